// Round 1
// baseline (13011.241 us; speedup 1.0000x reference)
//
#include <hip/hip_runtime.h>

#define NN 50000
#define NE 800000
#define NR 3
#define DD 128
#define DQ 64

#define FMA4(ACC, S, W_) \
  ACC.x = fmaf((S), (W_).x, ACC.x); ACC.y = fmaf((S), (W_).y, ACC.y); \
  ACC.z = fmaf((S), (W_).z, ACC.z); ACC.w = fmaf((S), (W_).w, ACC.w);

// Detect whether edges were pushed as int64 (little-endian: high dword == 0 for
// values in [0, 50000)) or int32. Writes 1 (int64) or 0 (int32) to *flag.
__global__ void detect_kernel(const int* __restrict__ e, int* __restrict__ flag) {
  if (threadIdx.x == 0 && blockIdx.x == 0) {
    int f = 1;
    for (int j = 0; j < 32; ++j)
      if (e[2 * j + 1] != 0) f = 0;   // random values: P(32 odd dwords all 0) ~ 0
    *flag = f;
  }
}

// deg counts via f32 atomics into rsqo/rsqi (pre-zeroed). grid=(NE/256, 3)
__global__ __launch_bounds__(256) void degree_kernel(
    const int* __restrict__ e, const int* __restrict__ flag,
    float* __restrict__ dego, float* __restrict__ degi) {
  int idx = blockIdx.x * 256 + threadIdx.x;  // exact: 3125*256 == NE
  int r = blockIdx.y;
  int f = *flag;
  long long b0 = ((long long)r * 2 * NE + idx) << f;
  long long b1 = b0 + ((long long)NE << f);
  int s = e[b0];
  int d = e[b1];
  atomicAdd(&dego[r * NN + s], 1.0f);
  atomicAdd(&degi[r * NN + d], 1.0f);
}

__global__ __launch_bounds__(256) void rsqrt_kernel(float* __restrict__ p, int n) {
  int i = blockIdx.x * 256 + threadIdx.x;
  if (i < n) p[i] = rsqrtf(fmaxf(p[i], 1.0f));
}

// C[n,j] = (TANH? tanh : id)( sum_k (SCALE? A[n,k]*scale[n] : A[n,k]) * W[k,j] )
// 16 rows per block-iter; thread = (rs 0..7 -> 2 rows, cg 0..31 -> 4 cols).
template <int TANH, int SCALE>
__global__ __launch_bounds__(256) void gemm128_kernel(
    const float* __restrict__ A, const float* __restrict__ W,
    const float* __restrict__ scale, float* __restrict__ C) {
  __shared__ float sW[DD * DD];    // 64 KiB
  __shared__ float sRow[16 * DD];  // 8 KiB
  const int tid = threadIdx.x;
  const int cg = tid & 31;
  const int rs = tid >> 5;
  for (int i = tid; i < DD * DD; i += 256) sW[i] = W[i];

  for (int base = blockIdx.x * 16; base < NN; base += gridDim.x * 16) {
    __syncthreads();
    const float4* A4 = (const float4*)(A + (size_t)base * DD);
    float4* R4 = (float4*)sRow;
#pragma unroll
    for (int i = 0; i < 2; ++i) {
      int u = tid + i * 256;  // 512 float4 = 16 rows
      float4 v = A4[u];
      if (SCALE) {
        float s = scale[base + (u >> 5)];
        v.x *= s; v.y *= s; v.z *= s; v.w *= s;
      }
      R4[u] = v;
    }
    __syncthreads();
    const float4* W4 = (const float4*)sW;
    const float4* row0 = (const float4*)(sRow + (rs * 2) * DD);
    const float4* row1 = (const float4*)(sRow + (rs * 2 + 1) * DD);
    float4 acc0 = make_float4(0, 0, 0, 0), acc1 = make_float4(0, 0, 0, 0);
#pragma unroll 8
    for (int k4 = 0; k4 < 32; ++k4) {
      float4 a0 = row0[k4];
      float4 a1 = row1[k4];
      float4 w;
      w = W4[(k4 * 4 + 0) * 32 + cg]; FMA4(acc0, a0.x, w) FMA4(acc1, a1.x, w)
      w = W4[(k4 * 4 + 1) * 32 + cg]; FMA4(acc0, a0.y, w) FMA4(acc1, a1.y, w)
      w = W4[(k4 * 4 + 2) * 32 + cg]; FMA4(acc0, a0.z, w) FMA4(acc1, a1.z, w)
      w = W4[(k4 * 4 + 3) * 32 + cg]; FMA4(acc0, a0.w, w) FMA4(acc1, a1.w, w)
    }
    if (TANH) {
      acc0.x = tanhf(acc0.x); acc0.y = tanhf(acc0.y); acc0.z = tanhf(acc0.z); acc0.w = tanhf(acc0.w);
      acc1.x = tanhf(acc1.x); acc1.y = tanhf(acc1.y); acc1.z = tanhf(acc1.z); acc1.w = tanhf(acc1.w);
    }
    ((float4*)(C + (size_t)(base + rs * 2) * DD))[cg] = acc0;
    ((float4*)(C + (size_t)(base + rs * 2 + 1) * DD))[cg] = acc1;
  }
}

// agg[dst,:] += m[src,:]  (32 threads x float4 per edge). grid = NE/8 blocks.
__global__ __launch_bounds__(256) void scatter_kernel(
    const float* __restrict__ m, const int* __restrict__ e,
    const int* __restrict__ flag, int r, float* __restrict__ agg) {
  long long gid = (long long)blockIdx.x * 256 + threadIdx.x;
  int idx = (int)(gid >> 5);
  int d4 = (int)(gid & 31) << 2;
  int f = *flag;
  long long b0 = ((long long)r * 2 * NE + idx) << f;
  int s = e[b0];
  int d = e[b0 + ((long long)NE << f)];
  float4 v = *(const float4*)(m + (size_t)s * DD + d4);
  float* o = agg + (size_t)d * DD + d4;
  atomicAdd(o + 0, v.x);
  atomicAdd(o + 1, v.y);
  atomicAdd(o + 2, v.z);
  atomicAdd(o + 3, v.w);
}

// val = agg * rsqi[n] + b + h   (in place on val). grid = NN*32/256.
__global__ __launch_bounds__(256) void fixup_kernel(
    float* __restrict__ val, const float* __restrict__ h,
    const float* __restrict__ rsqi, const float* __restrict__ b) {
  long long gid = (long long)blockIdx.x * 256 + threadIdx.x;
  int n = (int)(gid >> 5);
  int d4g = (int)(gid & 31);
  float s = rsqi[n];
  float4 a = ((const float4*)val)[gid];
  float4 hb = ((const float4*)h)[gid];
  float4 bb = ((const float4*)b)[d4g];
  float4 o;
  o.x = fmaf(a.x, s, bb.x + hb.x);
  o.y = fmaf(a.y, s, bb.y + hb.y);
  o.z = fmaf(a.z, s, bb.z + hb.z);
  o.w = fmaf(a.w, s, bb.w + hb.w);
  ((float4*)val)[gid] = o;
}

// sc[n] = sum_q tanh(V[n,:] @ AW[:,q]) * AQ[q]. 16 rows/iter, 16 threads/row.
__global__ __launch_bounds__(256) void scores_kernel(
    const float* __restrict__ V, const float* __restrict__ AW,
    const float* __restrict__ AQ, float* __restrict__ sc) {
  __shared__ float sW[DD * DQ];    // 32 KiB
  __shared__ float sRow[16 * DD];  // 8 KiB
  __shared__ float sQ[DQ];
  const int tid = threadIdx.x;
  const int cg = tid & 15;  // 16 groups x 4 = 64 query dims
  const int rs = tid >> 4;  // 16 rows
  for (int i = tid; i < DD * DQ; i += 256) sW[i] = AW[i];
  if (tid < DQ) sQ[tid] = AQ[tid];

  for (int base = blockIdx.x * 16; base < NN; base += gridDim.x * 16) {
    __syncthreads();
    const float4* A4 = (const float4*)(V + (size_t)base * DD);
    float4* R4 = (float4*)sRow;
#pragma unroll
    for (int i = 0; i < 2; ++i) R4[tid + i * 256] = A4[tid + i * 256];
    __syncthreads();
    const float4* W4 = (const float4*)sW;
    const float4* row = (const float4*)(sRow + rs * DD);
    float4 acc = make_float4(0, 0, 0, 0);
#pragma unroll 8
    for (int k4 = 0; k4 < 32; ++k4) {
      float4 a = row[k4];
      float4 w;
      w = W4[(k4 * 4 + 0) * 16 + cg]; FMA4(acc, a.x, w)
      w = W4[(k4 * 4 + 1) * 16 + cg]; FMA4(acc, a.y, w)
      w = W4[(k4 * 4 + 2) * 16 + cg]; FMA4(acc, a.z, w)
      w = W4[(k4 * 4 + 3) * 16 + cg]; FMA4(acc, a.w, w)
    }
    float4 q = ((const float4*)sQ)[cg];
    float p = tanhf(acc.x) * q.x + tanhf(acc.y) * q.y +
              tanhf(acc.z) * q.z + tanhf(acc.w) * q.w;
#pragma unroll
    for (int off = 8; off; off >>= 1) p += __shfl_xor(p, off);
    if (cg == 0) sc[base + rs] = p;
  }
}

// softmax over 3 relations + weighted combine. grid = NN*32/256.
__global__ __launch_bounds__(256) void combine_kernel(
    const float* __restrict__ vals, const float* __restrict__ sc,
    float* __restrict__ hout, float* __restrict__ attn_out) {
  long long gid = (long long)blockIdx.x * 256 + threadIdx.x;
  int n = (int)(gid >> 5);
  float s0 = sc[n], s1 = sc[NN + n], s2 = sc[2 * NN + n];
  float mx = fmaxf(s0, fmaxf(s1, s2));
  float e0 = __expf(s0 - mx), e1 = __expf(s1 - mx), e2 = __expf(s2 - mx);
  float inv = 1.0f / (e0 + e1 + e2);
  float a0 = e0 * inv, a1 = e1 * inv, a2 = e2 * inv;
  float4 v0 = ((const float4*)vals)[gid];
  float4 v1 = ((const float4*)vals)[(size_t)NN * 32 + gid];
  float4 v2 = ((const float4*)vals)[(size_t)NN * 64 + gid];
  float4 o;
  o.x = a0 * v0.x + a1 * v1.x + a2 * v2.x;
  o.y = a0 * v0.y + a1 * v1.y + a2 * v2.y;
  o.z = a0 * v0.z + a1 * v1.z + a2 * v2.z;
  o.w = a0 * v0.w + a1 * v1.w + a2 * v2.w;
  ((float4*)hout)[gid] = o;
  if (attn_out != nullptr && (gid & 31) == 0) {
    attn_out[(size_t)n * 3 + 0] = a0;
    attn_out[(size_t)n * 3 + 1] = a1;
    attn_out[(size_t)n * 3 + 2] = a2;
  }
}

// Y[n,j] = sum_part sum_k hp[part][n,k] * CW[j, part*128+k]
__global__ __launch_bounds__(256) void concat_kernel(
    const float* __restrict__ h0, const float* __restrict__ h1,
    const float* __restrict__ h2, const float* __restrict__ CW,
    float* __restrict__ Y) {
  __shared__ float sW[DD * 132];   // transposed, padded stride 132
  __shared__ float sRow[16 * DD];
  const int tid = threadIdx.x;
  const int cg = tid & 31;
  const int rs = tid >> 5;
  const float* hp[3] = {h0, h1, h2};
  for (int part = 0; part < 3; ++part) {
    __syncthreads();
    for (int u = tid; u < DD * DD; u += 256) {
      int j = u >> 7, k = u & 127;
      sW[k * 132 + j] = CW[(size_t)j * 384 + part * DD + k];  // coalesced read
    }
    __syncthreads();
    const float* H = hp[part];
    for (int base = blockIdx.x * 16; base < NN; base += gridDim.x * 16) {
      const float4* A4 = (const float4*)(H + (size_t)base * DD);
      float4* R4 = (float4*)sRow;
#pragma unroll
      for (int i = 0; i < 2; ++i) R4[tid + i * 256] = A4[tid + i * 256];
      __syncthreads();
      const float* row0 = sRow + (rs * 2) * DD;
      const float* row1 = row0 + DD;
      float4 acc0 = make_float4(0, 0, 0, 0), acc1 = make_float4(0, 0, 0, 0);
#pragma unroll 8
      for (int k = 0; k < DD; ++k) {
        float4 w = *(const float4*)(sW + k * 132 + cg * 4);
        FMA4(acc0, row0[k], w)
        FMA4(acc1, row1[k], w)
      }
      float4* Y0 = (float4*)(Y + (size_t)(base + rs * 2) * DD);
      float4* Y1 = (float4*)(Y + (size_t)(base + rs * 2 + 1) * DD);
      if (part == 0) {
        Y0[cg] = acc0;
        Y1[cg] = acc1;
      } else {
        float4 y0 = Y0[cg], y1 = Y1[cg];
        y0.x += acc0.x; y0.y += acc0.y; y0.z += acc0.z; y0.w += acc0.w;
        y1.x += acc1.x; y1.y += acc1.y; y1.z += acc1.z; y1.w += acc1.w;
        Y0[cg] = y0;
        Y1[cg] = y1;
      }
      __syncthreads();
    }
  }
}

extern "C" void kernel_launch(void* const* d_in, const int* in_sizes, int n_in,
                              void* d_out, int out_size, void* d_ws, size_t ws_size,
                              hipStream_t stream) {
  const float* x        = (const float*)d_in[0];
  const int*   edges    = (const int*)d_in[1];
  const float* feat_w   = (const float*)d_in[2];
  const float* conv_w   = (const float*)d_in[3];
  const float* conv_b   = (const float*)d_in[4];
  const float* attn_w   = (const float*)d_in[5];
  const float* attn_q   = (const float*)d_in[6];
  const float* concat_w = (const float*)d_in[7];
  float* out = (float*)d_out;

  float* ws = (float*)d_ws;
  float* rsqo = ws;                 // [3][NN]
  float* rsqi = rsqo + 3 * NN;      // [3][NN]
  float* scores = rsqi + 3 * NN;    // [3][NN]
  int* flag = (int*)(scores + 3 * NN);
  float* h0 = scores + 3 * NN + 16;
  float* h1 = h0 + (size_t)NN * DD;
  float* t2 = h1 + (size_t)NN * DD;
  float* vals = t2 + (size_t)NN * DD;  // 3 planes of [NN][DD]
  float* m = out;  // y-region of d_out is dead until the final concat GEMM

  const size_t ND = (size_t)NN * DD;

  hipMemsetAsync(rsqo, 0, sizeof(float) * 6 * NN, stream);
  detect_kernel<<<1, 64, 0, stream>>>(edges, flag);
  degree_kernel<<<dim3(NE / 256, 3), 256, 0, stream>>>(edges, flag, rsqo, rsqi);
  rsqrt_kernel<<<(6 * NN + 255) / 256, 256, 0, stream>>>(rsqo, 6 * NN);

  gemm128_kernel<1, 0><<<512, 256, 0, stream>>>(x, feat_w, nullptr, h0);

  auto het = [&](const float* h, int l, float* hout, float* attn_out) {
    hipMemsetAsync(vals, 0, sizeof(float) * 3 * ND, stream);
    for (int r = 0; r < 3; ++r) {
      gemm128_kernel<0, 1><<<512, 256, 0, stream>>>(
          h, conv_w + ((size_t)l * 3 + r) * DD * DD, rsqo + r * NN, m);
      scatter_kernel<<<NE / 8, 256, 0, stream>>>(m, edges, flag, r, vals + r * ND);
      fixup_kernel<<<NN * 32 / 256, 256, 0, stream>>>(
          vals + r * ND, h, rsqi + r * NN, conv_b + ((size_t)l * 3 + r) * DD);
    }
    for (int r = 0; r < 3; ++r)
      scores_kernel<<<512, 256, 0, stream>>>(
          vals + r * ND, attn_w + (size_t)l * DD * DQ, attn_q + (size_t)l * DQ,
          scores + r * NN);
    combine_kernel<<<NN * 32 / 256, 256, 0, stream>>>(vals, scores, hout, attn_out);
  };

  het(h0, 1, h1, nullptr);                    // h1 = het_layer(h0, l=1)
  het(h0, 0, t2, nullptr);                    // t  = het_layer(h0, l=0)
  het(t2, 1, t2, out + ND);                   // h2 = het_layer(t, l=1), attn -> out tail
  concat_kernel<<<512, 256, 0, stream>>>(h0, h1, t2, concat_w, out);
}

// Round 2
// 1878.203 us; speedup vs baseline: 6.9275x; 6.9275x over previous
//
#include <hip/hip_runtime.h>

#define NN 50000
#define NE 800000
#define NR 3
#define DD 128
#define DQ 64

#define FMA4(ACC, S, W_) \
  ACC.x = fmaf((S), (W_).x, ACC.x); ACC.y = fmaf((S), (W_).y, ACC.y); \
  ACC.z = fmaf((S), (W_).z, ACC.z); ACC.w = fmaf((S), (W_).w, ACC.w);

// Detect whether edges were pushed as int64 (little-endian: high dword == 0 for
// values in [0, 50000)) or int32. Writes 1 (int64) or 0 (int32) to *flag.
__global__ void detect_kernel(const int* __restrict__ e, int* __restrict__ flag) {
  if (threadIdx.x == 0 && blockIdx.x == 0) {
    int f = 1;
    for (int j = 0; j < 32; ++j)
      if (e[2 * j + 1] != 0) f = 0;   // random values: P(32 odd dwords all 0) ~ 0
    *flag = f;
  }
}

// degrees (float) for rsqrt-norm + int in-degree histogram for CSR.
// grid=(NE/256, 3). dego/degi/cnt pre-zeroed.
__global__ __launch_bounds__(256) void degree_kernel(
    const int* __restrict__ e, const int* __restrict__ flag,
    float* __restrict__ dego, float* __restrict__ degi, int* __restrict__ cnt) {
  int idx = blockIdx.x * 256 + threadIdx.x;  // exact: 3125*256 == NE
  int r = blockIdx.y;
  int f = *flag;
  long long b0 = ((long long)r * 2 * NE + idx) << f;
  long long b1 = b0 + ((long long)NE << f);
  int s = e[b0];
  int d = e[b1];
  atomicAdd(&dego[r * NN + s], 1.0f);
  atomicAdd(&degi[r * NN + d], 1.0f);
  atomicAdd(&cnt[r * NN + d], 1);
}

__global__ __launch_bounds__(256) void rsqrt_kernel(float* __restrict__ p, int n) {
  int i = blockIdx.x * 256 + threadIdx.x;
  if (i < n) p[i] = rsqrtf(fmaxf(p[i], 1.0f));
}

// Exclusive scan of cnt[r*NN..] -> rowptr[r*(NN+1)..] and cursor[r*NN..].
// grid = 3 blocks x 1024 threads; each thread owns a 49-element chunk.
__global__ __launch_bounds__(1024) void scan_kernel(
    const int* __restrict__ cnt, int* __restrict__ rowptr, int* __restrict__ cursor) {
  __shared__ int part[1024];
  const int r = blockIdx.x;
  const int* c = cnt + r * NN;
  int* rp = rowptr + r * (NN + 1);
  int* cur = cursor + r * NN;
  const int t = threadIdx.x;
  const int CH = 49;  // 1024*49 = 50176 >= NN
  int beg = t * CH, end = min(beg + CH, NN);
  int s = 0;
  for (int i = beg; i < end; ++i) s += c[i];
  part[t] = s;
  __syncthreads();
  for (int off = 1; off < 1024; off <<= 1) {
    int v = (t >= off) ? part[t - off] : 0;
    __syncthreads();
    if (t >= off) part[t] += v;
    __syncthreads();
  }
  int excl = (t == 0) ? 0 : part[t - 1];
  for (int i = beg; i < end; ++i) {
    rp[i] = excl;
    cur[i] = excl;
    excl += c[i];
  }
  if (t == 1023) rp[NN] = part[1023];
}

// Fill CSR column (src) arrays via atomic cursors. grid=(NE/256, 3).
__global__ __launch_bounds__(256) void fill_kernel(
    const int* __restrict__ e, const int* __restrict__ flag,
    int* __restrict__ cursor, int* __restrict__ col) {
  int idx = blockIdx.x * 256 + threadIdx.x;
  int r = blockIdx.y;
  int f = *flag;
  long long b0 = ((long long)r * 2 * NE + idx) << f;
  int s = e[b0];
  int d = e[b0 + ((long long)NE << f)];
  int pos = atomicAdd(&cursor[r * NN + d], 1);
  col[(size_t)r * NE + pos] = s;
}

// C[n,j] = (TANH? tanh : id)( sum_k (SCALE? A[n,k]*scale[n] : A[n,k]) * W[k,j] )
template <int TANH, int SCALE>
__global__ __launch_bounds__(256) void gemm128_kernel(
    const float* __restrict__ A, const float* __restrict__ W,
    const float* __restrict__ scale, float* __restrict__ C) {
  __shared__ float sW[DD * DD];    // 64 KiB
  __shared__ float sRow[16 * DD];  // 8 KiB
  const int tid = threadIdx.x;
  const int cg = tid & 31;
  const int rs = tid >> 5;
  for (int i = tid; i < DD * DD; i += 256) sW[i] = W[i];

  for (int base = blockIdx.x * 16; base < NN; base += gridDim.x * 16) {
    __syncthreads();
    const float4* A4 = (const float4*)(A + (size_t)base * DD);
    float4* R4 = (float4*)sRow;
#pragma unroll
    for (int i = 0; i < 2; ++i) {
      int u = tid + i * 256;  // 512 float4 = 16 rows
      float4 v = A4[u];
      if (SCALE) {
        float s = scale[base + (u >> 5)];
        v.x *= s; v.y *= s; v.z *= s; v.w *= s;
      }
      R4[u] = v;
    }
    __syncthreads();
    const float4* W4 = (const float4*)sW;
    const float4* row0 = (const float4*)(sRow + (rs * 2) * DD);
    const float4* row1 = (const float4*)(sRow + (rs * 2 + 1) * DD);
    float4 acc0 = make_float4(0, 0, 0, 0), acc1 = make_float4(0, 0, 0, 0);
#pragma unroll 8
    for (int k4 = 0; k4 < 32; ++k4) {
      float4 a0 = row0[k4];
      float4 a1 = row1[k4];
      float4 w;
      w = W4[(k4 * 4 + 0) * 32 + cg]; FMA4(acc0, a0.x, w) FMA4(acc1, a1.x, w)
      w = W4[(k4 * 4 + 1) * 32 + cg]; FMA4(acc0, a0.y, w) FMA4(acc1, a1.y, w)
      w = W4[(k4 * 4 + 2) * 32 + cg]; FMA4(acc0, a0.z, w) FMA4(acc1, a1.z, w)
      w = W4[(k4 * 4 + 3) * 32 + cg]; FMA4(acc0, a0.w, w) FMA4(acc1, a1.w, w)
    }
    if (TANH) {
      acc0.x = tanhf(acc0.x); acc0.y = tanhf(acc0.y); acc0.z = tanhf(acc0.z); acc0.w = tanhf(acc0.w);
      acc1.x = tanhf(acc1.x); acc1.y = tanhf(acc1.y); acc1.z = tanhf(acc1.z); acc1.w = tanhf(acc1.w);
    }
    ((float4*)(C + (size_t)(base + rs * 2) * DD))[cg] = acc0;
    ((float4*)(C + (size_t)(base + rs * 2 + 1) * DD))[cg] = acc1;
  }
}

// CSR gather-aggregate + fused fixup: val[n,:] = (sum_{e in in(n)} m[col[e],:]) * rsqi[n] + b + h[n,:]
// 32 lanes per node, float4 per lane. grid = NN*32/256 = 6250 blocks exactly.
__global__ __launch_bounds__(256) void gather_kernel(
    const float* __restrict__ m, const int* __restrict__ rowptr,
    const int* __restrict__ col, const float* __restrict__ h,
    const float* __restrict__ rsqi, const float* __restrict__ b,
    float* __restrict__ val) {
  int gid = blockIdx.x * 256 + threadIdx.x;
  int n = gid >> 5;
  int lane = gid & 31;
  int e0 = rowptr[n], e1 = rowptr[n + 1];
  const float4* m4 = (const float4*)m;
  float4 a0 = make_float4(0, 0, 0, 0), a1 = make_float4(0, 0, 0, 0);
  int e = e0;
  for (; e + 1 < e1; e += 2) {
    int s0 = col[e], s1 = col[e + 1];
    float4 v0 = m4[(size_t)s0 * 32 + lane];
    float4 v1 = m4[(size_t)s1 * 32 + lane];
    a0.x += v0.x; a0.y += v0.y; a0.z += v0.z; a0.w += v0.w;
    a1.x += v1.x; a1.y += v1.y; a1.z += v1.z; a1.w += v1.w;
  }
  if (e < e1) {
    int s0 = col[e];
    float4 v0 = m4[(size_t)s0 * 32 + lane];
    a0.x += v0.x; a0.y += v0.y; a0.z += v0.z; a0.w += v0.w;
  }
  float sc = rsqi[n];
  float4 hb = ((const float4*)h)[gid];
  float4 bb = ((const float4*)b)[lane];
  float4 o;
  o.x = fmaf(a0.x + a1.x, sc, bb.x + hb.x);
  o.y = fmaf(a0.y + a1.y, sc, bb.y + hb.y);
  o.z = fmaf(a0.z + a1.z, sc, bb.z + hb.z);
  o.w = fmaf(a0.w + a1.w, sc, bb.w + hb.w);
  ((float4*)val)[gid] = o;
}

// sc[n] = sum_q tanh(V[n,:] @ AW[:,q]) * AQ[q]. 16 rows/iter, 16 threads/row.
__global__ __launch_bounds__(256) void scores_kernel(
    const float* __restrict__ V, const float* __restrict__ AW,
    const float* __restrict__ AQ, float* __restrict__ sc) {
  __shared__ float sW[DD * DQ];    // 32 KiB
  __shared__ float sRow[16 * DD];  // 8 KiB
  __shared__ float sQ[DQ];
  const int tid = threadIdx.x;
  const int cg = tid & 15;
  const int rs = tid >> 4;
  for (int i = tid; i < DD * DQ; i += 256) sW[i] = AW[i];
  if (tid < DQ) sQ[tid] = AQ[tid];

  for (int base = blockIdx.x * 16; base < NN; base += gridDim.x * 16) {
    __syncthreads();
    const float4* A4 = (const float4*)(V + (size_t)base * DD);
    float4* R4 = (float4*)sRow;
#pragma unroll
    for (int i = 0; i < 2; ++i) R4[tid + i * 256] = A4[tid + i * 256];
    __syncthreads();
    const float4* W4 = (const float4*)sW;
    const float4* row = (const float4*)(sRow + rs * DD);
    float4 acc = make_float4(0, 0, 0, 0);
#pragma unroll 8
    for (int k4 = 0; k4 < 32; ++k4) {
      float4 a = row[k4];
      float4 w;
      w = W4[(k4 * 4 + 0) * 16 + cg]; FMA4(acc, a.x, w)
      w = W4[(k4 * 4 + 1) * 16 + cg]; FMA4(acc, a.y, w)
      w = W4[(k4 * 4 + 2) * 16 + cg]; FMA4(acc, a.z, w)
      w = W4[(k4 * 4 + 3) * 16 + cg]; FMA4(acc, a.w, w)
    }
    float4 q = ((const float4*)sQ)[cg];
    float p = tanhf(acc.x) * q.x + tanhf(acc.y) * q.y +
              tanhf(acc.z) * q.z + tanhf(acc.w) * q.w;
#pragma unroll
    for (int off = 8; off; off >>= 1) p += __shfl_xor(p, off);
    if (cg == 0) sc[base + rs] = p;
  }
}

// softmax over 3 relations + weighted combine. grid = NN*32/256.
__global__ __launch_bounds__(256) void combine_kernel(
    const float* __restrict__ vals, const float* __restrict__ sc,
    float* __restrict__ hout, float* __restrict__ attn_out) {
  long long gid = (long long)blockIdx.x * 256 + threadIdx.x;
  int n = (int)(gid >> 5);
  float s0 = sc[n], s1 = sc[NN + n], s2 = sc[2 * NN + n];
  float mx = fmaxf(s0, fmaxf(s1, s2));
  float e0 = __expf(s0 - mx), e1 = __expf(s1 - mx), e2 = __expf(s2 - mx);
  float inv = 1.0f / (e0 + e1 + e2);
  float a0 = e0 * inv, a1 = e1 * inv, a2 = e2 * inv;
  float4 v0 = ((const float4*)vals)[gid];
  float4 v1 = ((const float4*)vals)[(size_t)NN * 32 + gid];
  float4 v2 = ((const float4*)vals)[(size_t)NN * 64 + gid];
  float4 o;
  o.x = a0 * v0.x + a1 * v1.x + a2 * v2.x;
  o.y = a0 * v0.y + a1 * v1.y + a2 * v2.y;
  o.z = a0 * v0.z + a1 * v1.z + a2 * v2.z;
  o.w = a0 * v0.w + a1 * v1.w + a2 * v2.w;
  ((float4*)hout)[gid] = o;
  if (attn_out != nullptr && (gid & 31) == 0) {
    attn_out[(size_t)n * 3 + 0] = a0;
    attn_out[(size_t)n * 3 + 1] = a1;
    attn_out[(size_t)n * 3 + 2] = a2;
  }
}

// Y[n,j] = sum_part sum_k hp[part][n,k] * CW[j, part*128+k]
__global__ __launch_bounds__(256) void concat_kernel(
    const float* __restrict__ h0, const float* __restrict__ h1,
    const float* __restrict__ h2, const float* __restrict__ CW,
    float* __restrict__ Y) {
  __shared__ float sW[DD * 132];   // transposed, padded stride 132
  __shared__ float sRow[16 * DD];
  const int tid = threadIdx.x;
  const int cg = tid & 31;
  const int rs = tid >> 5;
  const float* hp[3] = {h0, h1, h2};
  for (int part = 0; part < 3; ++part) {
    __syncthreads();
    for (int u = tid; u < DD * DD; u += 256) {
      int j = u >> 7, k = u & 127;
      sW[k * 132 + j] = CW[(size_t)j * 384 + part * DD + k];
    }
    __syncthreads();
    const float* H = hp[part];
    for (int base = blockIdx.x * 16; base < NN; base += gridDim.x * 16) {
      const float4* A4 = (const float4*)(H + (size_t)base * DD);
      float4* R4 = (float4*)sRow;
#pragma unroll
      for (int i = 0; i < 2; ++i) R4[tid + i * 256] = A4[tid + i * 256];
      __syncthreads();
      const float* row0 = sRow + (rs * 2) * DD;
      const float* row1 = row0 + DD;
      float4 acc0 = make_float4(0, 0, 0, 0), acc1 = make_float4(0, 0, 0, 0);
#pragma unroll 8
      for (int k = 0; k < DD; ++k) {
        float4 w = *(const float4*)(sW + k * 132 + cg * 4);
        FMA4(acc0, row0[k], w)
        FMA4(acc1, row1[k], w)
      }
      float4* Y0 = (float4*)(Y + (size_t)(base + rs * 2) * DD);
      float4* Y1 = (float4*)(Y + (size_t)(base + rs * 2 + 1) * DD);
      if (part == 0) {
        Y0[cg] = acc0;
        Y1[cg] = acc1;
      } else {
        float4 y0 = Y0[cg], y1 = Y1[cg];
        y0.x += acc0.x; y0.y += acc0.y; y0.z += acc0.z; y0.w += acc0.w;
        y1.x += acc1.x; y1.y += acc1.y; y1.z += acc1.z; y1.w += acc1.w;
        Y0[cg] = y0;
        Y1[cg] = y1;
      }
      __syncthreads();
    }
  }
}

extern "C" void kernel_launch(void* const* d_in, const int* in_sizes, int n_in,
                              void* d_out, int out_size, void* d_ws, size_t ws_size,
                              hipStream_t stream) {
  const float* x        = (const float*)d_in[0];
  const int*   edges    = (const int*)d_in[1];
  const float* feat_w   = (const float*)d_in[2];
  const float* conv_w   = (const float*)d_in[3];
  const float* conv_b   = (const float*)d_in[4];
  const float* attn_w   = (const float*)d_in[5];
  const float* attn_q   = (const float*)d_in[6];
  const float* concat_w = (const float*)d_in[7];
  float* out = (float*)d_out;

  float* ws = (float*)d_ws;
  float* rsqo = ws;                  // [3][NN]
  float* rsqi = rsqo + 3 * NN;       // [3][NN]
  float* scores = rsqi + 3 * NN;     // [3][NN]
  int* flag = (int*)(scores + 3 * NN);
  int* cnt = flag + 16;              // [3][NN]
  int* cursor = cnt + 3 * NN;        // [3][NN]
  int* rowptr = cursor + 3 * NN;     // [3][NN+1] (+pad)
  int* col = rowptr + 3 * (NN + 1) + 13;  // [3][NE], 16B-aligned
  float* h0 = (float*)(col + 3 * (size_t)NE);
  float* h1 = h0 + (size_t)NN * DD;
  float* t2 = h1 + (size_t)NN * DD;
  float* vals = t2 + (size_t)NN * DD;  // 3 planes of [NN][DD]
  float* m = out;  // y-region of d_out is dead until the final concat GEMM

  const size_t ND = (size_t)NN * DD;

  hipMemsetAsync(rsqo, 0, sizeof(float) * 6 * NN, stream);
  hipMemsetAsync(cnt, 0, sizeof(int) * 3 * NN, stream);
  detect_kernel<<<1, 64, 0, stream>>>(edges, flag);
  degree_kernel<<<dim3(NE / 256, 3), 256, 0, stream>>>(edges, flag, rsqo, rsqi, cnt);
  rsqrt_kernel<<<(6 * NN + 255) / 256, 256, 0, stream>>>(rsqo, 6 * NN);
  scan_kernel<<<3, 1024, 0, stream>>>(cnt, rowptr, cursor);
  fill_kernel<<<dim3(NE / 256, 3), 256, 0, stream>>>(edges, flag, cursor, col);

  gemm128_kernel<1, 0><<<512, 256, 0, stream>>>(x, feat_w, nullptr, h0);

  auto het = [&](const float* h, int l, float* hout, float* attn_out) {
    for (int r = 0; r < 3; ++r) {
      gemm128_kernel<0, 1><<<512, 256, 0, stream>>>(
          h, conv_w + ((size_t)l * 3 + r) * DD * DD, rsqo + r * NN, m);
      gather_kernel<<<NN * 32 / 256, 256, 0, stream>>>(
          m, rowptr + r * (NN + 1), col + (size_t)r * NE, h, rsqi + r * NN,
          conv_b + ((size_t)l * 3 + r) * DD, vals + r * ND);
    }
    for (int r = 0; r < 3; ++r)
      scores_kernel<<<512, 256, 0, stream>>>(
          vals + r * ND, attn_w + (size_t)l * DD * DQ, attn_q + (size_t)l * DQ,
          scores + r * NN);
    combine_kernel<<<NN * 32 / 256, 256, 0, stream>>>(vals, scores, hout, attn_out);
  };

  het(h0, 1, h1, nullptr);                    // h1 = het_layer(h0, l=1)
  het(h0, 0, t2, nullptr);                    // t  = het_layer(h0, l=0)
  het(t2, 1, t2, out + ND);                   // h2 = het_layer(t, l=1), attn -> out tail
  concat_kernel<<<512, 256, 0, stream>>>(h0, h1, t2, concat_w, out);
}

// Round 5
// 1525.188 us; speedup vs baseline: 8.5309x; 1.2315x over previous
//
#include <hip/hip_runtime.h>

#define NN 50000
#define NE 800000
#define NR 3
#define DD 128
#define DQ 64

#define FMA4(ACC, S, W_) \
  ACC.x = fmaf((S), (W_).x, ACC.x); ACC.y = fmaf((S), (W_).y, ACC.y); \
  ACC.z = fmaf((S), (W_).z, ACC.z); ACC.w = fmaf((S), (W_).w, ACC.w);

__device__ __forceinline__ int clampi(int v, int lo, int hi) {
  return v < lo ? lo : (v > hi ? hi : v);
}

// Detect int64-pushed edges (harness doc says int32; insurance only).
__global__ void detect_kernel(const int* __restrict__ e, int* __restrict__ flag) {
  if (threadIdx.x == 0 && blockIdx.x == 0) {
    int f = 1;
    for (int j = 0; j < 32; ++j)
      if (e[2 * j + 1] != 0) f = 0;
    *flag = f;
  }
}

// Raw degree counts (float) into dego/degi (pre-zeroed). 2 atomics/edge.
__global__ __launch_bounds__(256) void degree_kernel(
    const int* __restrict__ e, const int* __restrict__ flag,
    float* __restrict__ dego, float* __restrict__ degi) {
  int idx = blockIdx.x * 256 + threadIdx.x;  // exact: 3125*256 == NE
  int r = blockIdx.y;
  int f = *flag;
  long long b0 = ((long long)r * 2 * NE + idx) << f;
  long long b1 = b0 + ((long long)NE << f);
  int s = clampi(e[b0], 0, NN - 1);
  int d = clampi(e[b1], 0, NN - 1);
  atomicAdd(&dego[r * NN + s], 1.0f);
  atomicAdd(&degi[r * NN + d], 1.0f);
}

__global__ __launch_bounds__(256) void rsqrt_kernel(float* __restrict__ p, int n) {
  int i = blockIdx.x * 256 + threadIdx.x;
  if (i < n) p[i] = rsqrtf(fmaxf(p[i], 1.0f));
}

// Exclusive scan of (int)degi_raw -> rowptr, cursor. Runs BEFORE rsqrt clamps.
__global__ __launch_bounds__(1024) void scan_kernel(
    const float* __restrict__ degi, int* __restrict__ rowptr, int* __restrict__ cursor) {
  __shared__ int part[1024];
  const int r = blockIdx.x;
  const float* c = degi + r * NN;
  int* rp = rowptr + r * (NN + 1);
  int* cur = cursor + r * NN;
  const int t = threadIdx.x;
  const int CH = 49;  // 1024*49 = 50176 >= NN
  int beg = t * CH, end = min(beg + CH, NN);
  int s = 0;
  for (int i = beg; i < end; ++i) s += (int)c[i];
  part[t] = s;
  __syncthreads();
  for (int off = 1; off < 1024; off <<= 1) {
    int v = (t >= off) ? part[t - off] : 0;
    __syncthreads();
    if (t >= off) part[t] += v;
    __syncthreads();
  }
  int excl = (t == 0) ? 0 : part[t - 1];
  for (int i = beg; i < end; ++i) {
    rp[i] = excl;
    cur[i] = excl;
    excl += (int)c[i];
  }
  if (t == 1023) rp[NN] = part[1023];
}

// Fill CSR column (src) arrays via atomic cursors. grid=(NE/256, 3).
__global__ __launch_bounds__(256) void fill_kernel(
    const int* __restrict__ e, const int* __restrict__ flag,
    int* __restrict__ cursor, int* __restrict__ col) {
  int idx = blockIdx.x * 256 + threadIdx.x;
  int r = blockIdx.y;
  int f = *flag;
  long long b0 = ((long long)r * 2 * NE + idx) << f;
  int s = clampi(e[b0], 0, NN - 1);
  int d = clampi(e[b0 + ((long long)NE << f)], 0, NN - 1);
  int pos = atomicAdd(&cursor[r * NN + d], 1);
  pos = clampi(pos, 0, NE - 1);
  col[(size_t)r * NE + pos] = s;
}

// C = [tanh]( A @ W )  [EPI: * rsqi[n] + bias[j] + resid[n,j]]
// A and C may ALIAS (in-place): each block stages its 16 rows in LDS before
// writing the same 16 rows; row-sets disjoint across blocks. No __restrict__
// on A/C.
template <int TANH, int EPI>
__global__ __launch_bounds__(256) void gemm128_kernel(
    const float* A, const float* __restrict__ W,
    const float* __restrict__ rsqi, const float* __restrict__ bias,
    const float* __restrict__ resid, float* C) {
  __shared__ float sW[DD * DD];    // 64 KiB
  __shared__ float sRow[16 * DD];  // 8 KiB
  const int tid = threadIdx.x;
  const int cg = tid & 31;
  const int rs = tid >> 5;
  for (int i = tid; i < DD * DD; i += 256) sW[i] = W[i];

  for (int base = blockIdx.x * 16; base < NN; base += gridDim.x * 16) {
    __syncthreads();
    const float4* A4 = (const float4*)(A + (size_t)base * DD);
    float4* R4 = (float4*)sRow;
#pragma unroll
    for (int i = 0; i < 2; ++i) R4[tid + i * 256] = A4[tid + i * 256];
    __syncthreads();
    const float4* W4 = (const float4*)sW;
    const float4* row0 = (const float4*)(sRow + (rs * 2) * DD);
    const float4* row1 = (const float4*)(sRow + (rs * 2 + 1) * DD);
    float4 acc0 = make_float4(0, 0, 0, 0), acc1 = make_float4(0, 0, 0, 0);
#pragma unroll 8
    for (int k4 = 0; k4 < 32; ++k4) {
      float4 a0 = row0[k4];
      float4 a1 = row1[k4];
      float4 w;
      w = W4[(k4 * 4 + 0) * 32 + cg]; FMA4(acc0, a0.x, w) FMA4(acc1, a1.x, w)
      w = W4[(k4 * 4 + 1) * 32 + cg]; FMA4(acc0, a0.y, w) FMA4(acc1, a1.y, w)
      w = W4[(k4 * 4 + 2) * 32 + cg]; FMA4(acc0, a0.z, w) FMA4(acc1, a1.z, w)
      w = W4[(k4 * 4 + 3) * 32 + cg]; FMA4(acc0, a0.w, w) FMA4(acc1, a1.w, w)
    }
    if (TANH) {
      acc0.x = tanhf(acc0.x); acc0.y = tanhf(acc0.y); acc0.z = tanhf(acc0.z); acc0.w = tanhf(acc0.w);
      acc1.x = tanhf(acc1.x); acc1.y = tanhf(acc1.y); acc1.z = tanhf(acc1.z); acc1.w = tanhf(acc1.w);
    }
    if (EPI) {
      int n0 = base + rs * 2;
      float s0 = rsqi[n0], s1 = rsqi[n0 + 1];
      float4 bb = ((const float4*)bias)[cg];
      float4 r0 = ((const float4*)(resid + (size_t)n0 * DD))[cg];
      float4 r1 = ((const float4*)(resid + (size_t)(n0 + 1) * DD))[cg];
      acc0.x = fmaf(acc0.x, s0, bb.x + r0.x); acc0.y = fmaf(acc0.y, s0, bb.y + r0.y);
      acc0.z = fmaf(acc0.z, s0, bb.z + r0.z); acc0.w = fmaf(acc0.w, s0, bb.w + r0.w);
      acc1.x = fmaf(acc1.x, s1, bb.x + r1.x); acc1.y = fmaf(acc1.y, s1, bb.y + r1.y);
      acc1.z = fmaf(acc1.z, s1, bb.z + r1.z); acc1.w = fmaf(acc1.w, s1, bb.w + r1.w);
    }
    ((float4*)(C + (size_t)(base + rs * 2) * DD))[cg] = acc0;
    ((float4*)(C + (size_t)(base + rs * 2 + 1) * DD))[cg] = acc1;
  }
}

// CSR gather: u[n,:] = sum_{e in in(n)} h[col[e],:] * rsqo[col[e]]
// u must NOT alias h (it never does here). grid = NN*32/256.
__global__ __launch_bounds__(256) void gather_kernel(
    const float* __restrict__ h, const int* __restrict__ rowptr,
    const int* __restrict__ col, const float* __restrict__ rsqo,
    float* __restrict__ u) {
  int gid = blockIdx.x * 256 + threadIdx.x;
  int n = gid >> 5;
  int lane = gid & 31;
  int e0 = clampi(rowptr[n], 0, NE);
  int e1 = clampi(rowptr[n + 1], e0, NE);
  const float4* h4 = (const float4*)h;
  float4 a0 = make_float4(0, 0, 0, 0), a1 = make_float4(0, 0, 0, 0);
  int e = e0;
  for (; e + 1 < e1; e += 2) {
    int s0 = clampi(col[e], 0, NN - 1), s1 = clampi(col[e + 1], 0, NN - 1);
    float c0 = rsqo[s0], c1 = rsqo[s1];
    float4 v0 = h4[(size_t)s0 * 32 + lane];
    float4 v1 = h4[(size_t)s1 * 32 + lane];
    a0.x = fmaf(v0.x, c0, a0.x); a0.y = fmaf(v0.y, c0, a0.y);
    a0.z = fmaf(v0.z, c0, a0.z); a0.w = fmaf(v0.w, c0, a0.w);
    a1.x = fmaf(v1.x, c1, a1.x); a1.y = fmaf(v1.y, c1, a1.y);
    a1.z = fmaf(v1.z, c1, a1.z); a1.w = fmaf(v1.w, c1, a1.w);
  }
  if (e < e1) {
    int s0 = clampi(col[e], 0, NN - 1);
    float c0 = rsqo[s0];
    float4 v0 = h4[(size_t)s0 * 32 + lane];
    a0.x = fmaf(v0.x, c0, a0.x); a0.y = fmaf(v0.y, c0, a0.y);
    a0.z = fmaf(v0.z, c0, a0.z); a0.w = fmaf(v0.w, c0, a0.w);
  }
  float4 o;
  o.x = a0.x + a1.x; o.y = a0.y + a1.y; o.z = a0.z + a1.z; o.w = a0.w + a1.w;
  ((float4*)u)[gid] = o;
}

// Fused scores + softmax + combine over 3 relation planes (separate ptrs).
// hout MAY alias v0p (in-place): rows staged in LDS before write, row-sets
// disjoint across blocks. No __restrict__ on v*/hout.
__global__ __launch_bounds__(256) void scorecombine_kernel(
    const float* v0p, const float* v1p, const float* v2p,
    const float* __restrict__ AW, const float* __restrict__ AQ,
    float* hout, float* __restrict__ attn_out) {
  __shared__ float sW[DD * DQ];       // 32 KiB
  __shared__ float sRow[3][16 * DD];  // 24 KiB
  __shared__ float sS[3][16];
  __shared__ float sQ[DQ];
  const int tid = threadIdx.x;
  const int cg = tid & 15;
  const int rs = tid >> 4;
  for (int i = tid; i < DD * DQ; i += 256) sW[i] = AW[i];
  if (tid < DQ) sQ[tid] = AQ[tid];
  const float* vp[3] = {v0p, v1p, v2p};

  for (int base = blockIdx.x * 16; base < NN; base += gridDim.x * 16) {
    __syncthreads();
#pragma unroll
    for (int r = 0; r < 3; ++r) {
      const float4* V4 = (const float4*)vp[r];
      float4* R4 = (float4*)sRow[r];
#pragma unroll
      for (int i = 0; i < 2; ++i)
        R4[tid + i * 256] = V4[(size_t)base * 32 + tid + i * 256];
    }
    __syncthreads();
    const float4* W4 = (const float4*)sW;
#pragma unroll
    for (int r = 0; r < 3; ++r) {
      const float4* row = (const float4*)(sRow[r] + rs * DD);
      float4 acc = make_float4(0, 0, 0, 0);
#pragma unroll 8
      for (int k4 = 0; k4 < 32; ++k4) {
        float4 a = row[k4];
        float4 w;
        w = W4[(k4 * 4 + 0) * 16 + cg]; FMA4(acc, a.x, w)
        w = W4[(k4 * 4 + 1) * 16 + cg]; FMA4(acc, a.y, w)
        w = W4[(k4 * 4 + 2) * 16 + cg]; FMA4(acc, a.z, w)
        w = W4[(k4 * 4 + 3) * 16 + cg]; FMA4(acc, a.w, w)
      }
      float4 q = ((const float4*)sQ)[cg];
      float p = tanhf(acc.x) * q.x + tanhf(acc.y) * q.y +
                tanhf(acc.z) * q.z + tanhf(acc.w) * q.w;
#pragma unroll
      for (int off = 8; off; off >>= 1) p += __shfl_xor(p, off);
      if (cg == 0) sS[r][rs] = p;
    }
    __syncthreads();
    float s0 = sS[0][rs], s1 = sS[1][rs], s2 = sS[2][rs];
    float mx = fmaxf(s0, fmaxf(s1, s2));
    float e0 = __expf(s0 - mx), e1 = __expf(s1 - mx), e2 = __expf(s2 - mx);
    float inv = 1.0f / (e0 + e1 + e2);
    float a0 = e0 * inv, a1 = e1 * inv, a2 = e2 * inv;
    const float4* P0 = (const float4*)sRow[0];
    const float4* P1 = (const float4*)sRow[1];
    const float4* P2 = (const float4*)sRow[2];
#pragma unroll
    for (int j = 0; j < 2; ++j) {
      int col4 = cg * 2 + j;
      float4 v0 = P0[rs * 32 + col4];
      float4 v1 = P1[rs * 32 + col4];
      float4 v2 = P2[rs * 32 + col4];
      float4 o;
      o.x = a0 * v0.x + a1 * v1.x + a2 * v2.x;
      o.y = a0 * v0.y + a1 * v1.y + a2 * v2.y;
      o.z = a0 * v0.z + a1 * v1.z + a2 * v2.z;
      o.w = a0 * v0.w + a1 * v1.w + a2 * v2.w;
      ((float4*)hout)[(size_t)(base + rs) * 32 + col4] = o;
    }
    if (attn_out != nullptr && cg == 0) {
      int n = base + rs;
      attn_out[(size_t)n * 3 + 0] = a0;
      attn_out[(size_t)n * 3 + 1] = a1;
      attn_out[(size_t)n * 3 + 2] = a2;
    }
  }
}

// Y[n,j] = sum_part sum_k hp[part][n,k] * CW[j, part*128+k]; Y is [NN,128].
__global__ __launch_bounds__(256) void concat_kernel(
    const float* __restrict__ h0, const float* __restrict__ h1,
    const float* __restrict__ h2, const float* __restrict__ CW,
    float* __restrict__ Y) {
  __shared__ float sW[DD * 132];   // transposed, padded stride 132
  __shared__ float sRow[16 * DD];
  const int tid = threadIdx.x;
  const int cg = tid & 31;
  const int rs = tid >> 5;
  const float* hp[3] = {h0, h1, h2};
  for (int part = 0; part < 3; ++part) {
    __syncthreads();
    for (int u = tid; u < DD * DD; u += 256) {
      int j = u >> 7, k = u & 127;
      sW[k * 132 + j] = CW[(size_t)j * 384 + part * DD + k];
    }
    __syncthreads();
    const float* H = hp[part];
    for (int base = blockIdx.x * 16; base < NN; base += gridDim.x * 16) {
      const float4* A4 = (const float4*)(H + (size_t)base * DD);
      float4* R4 = (float4*)sRow;
#pragma unroll
      for (int i = 0; i < 2; ++i) R4[tid + i * 256] = A4[tid + i * 256];
      __syncthreads();
      const float* row0 = sRow + (rs * 2) * DD;
      const float* row1 = row0 + DD;
      float4 acc0 = make_float4(0, 0, 0, 0), acc1 = make_float4(0, 0, 0, 0);
#pragma unroll 8
      for (int k = 0; k < DD; ++k) {
        float4 w = *(const float4*)(sW + k * 132 + cg * 4);
        FMA4(acc0, row0[k], w)
        FMA4(acc1, row1[k], w)
      }
      float4* Y0 = (float4*)(Y + (size_t)(base + rs * 2) * DD);
      float4* Y1 = (float4*)(Y + (size_t)(base + rs * 2 + 1) * DD);
      if (part == 0) {
        Y0[cg] = acc0;
        Y1[cg] = acc1;
      } else {
        float4 y0 = Y0[cg], y1 = Y1[cg];
        y0.x += acc0.x; y0.y += acc0.y; y0.z += acc0.z; y0.w += acc0.w;
        y1.x += acc1.x; y1.y += acc1.y; y1.z += acc1.z; y1.w += acc1.w;
        Y0[cg] = y0;
        Y1[cg] = y1;
      }
      __syncthreads();
    }
  }
}

extern "C" void kernel_launch(void* const* d_in, const int* in_sizes, int n_in,
                              void* d_out, int out_size, void* d_ws, size_t ws_size,
                              hipStream_t stream) {
  const float* x        = (const float*)d_in[0];
  const int*   edges    = (const int*)d_in[1];
  const float* feat_w   = (const float*)d_in[2];
  const float* conv_w   = (const float*)d_in[3];
  const float* conv_b   = (const float*)d_in[4];
  const float* attn_w   = (const float*)d_in[5];
  const float* attn_q   = (const float*)d_in[6];
  const float* concat_w = (const float*)d_in[7];
  float* out = (float*)d_out;   // [NN*128 y][NN*3 attn] = 6.55M floats total

  float* ws = (float*)d_ws;
  float* rsqo = ws;                  // [3][NN]  (raw counts, then rsqrt)
  float* rsqi = rsqo + 3 * NN;       // [3][NN]
  int* flag = (int*)(rsqi + 3 * NN);
  int* cursor = flag + 16;           // [3][NN]
  int* rowptr = cursor + 3 * NN;     // [3][NN+1] (+pad to 16B)
  int* col = rowptr + 3 * (NN + 1) + 13;  // [3][NE]
  float* P1 = (float*)(col + 3 * (size_t)NE);   // h0
  const size_t ND = (size_t)NN * DD;
  float* P2 = P1 + ND;   // u[0] / vals0[0] / u2[0] / vals2[0] / h2
  float* P3 = P2 + ND;   // u[1] / vals0[1] / u2[1] / vals2[1]
  float* P4 = P3 + ND;   // u[2] / vals0[2] / u2[2] / vals2[2]
  float* P5 = P4 + ND;   // vals1[0] / h1
  float* P6 = P5 + ND;   // vals1[1] / t2
  float* O  = out;       // vals1[2] scratch in d_out's y region (dead until concat)

  const float* W1 = conv_w + (size_t)1 * 3 * DD * DD;  // conv_w[1, r]
  const float* W0 = conv_w;                            // conv_w[0, r]
  const float* B1 = conv_b + (size_t)1 * 3 * DD;
  const float* B0 = conv_b;

  hipMemsetAsync(rsqo, 0, sizeof(float) * 6 * NN, stream);
  detect_kernel<<<1, 64, 0, stream>>>(edges, flag);
  degree_kernel<<<dim3(NE / 256, 3), 256, 0, stream>>>(edges, flag, rsqo, rsqi);
  scan_kernel<<<3, 1024, 0, stream>>>(rsqi, rowptr, cursor);   // before rsqrt clamps
  rsqrt_kernel<<<(6 * NN + 255) / 256, 256, 0, stream>>>(rsqo, 6 * NN);
  fill_kernel<<<dim3(NE / 256, 3), 256, 0, stream>>>(edges, flag, cursor, col);

  // h0 = tanh(x @ feat_w) -> P1
  gemm128_kernel<1, 0><<<512, 256, 0, stream>>>(x, feat_w, nullptr, nullptr, nullptr, P1);

  // Shared aggregation u[r] = A_r^T (h0 * rsqo_r) -> P2,P3,P4
  float* U[3] = {P2, P3, P4};
  for (int r = 0; r < 3; ++r)
    gather_kernel<<<NN * 32 / 256, 256, 0, stream>>>(
        P1, rowptr + r * (NN + 1), col + (size_t)r * NE, rsqo + r * NN, U[r]);

  // layer l=1 on h0: vals1[r] = u[r]@W1r * rsqi + b + h0 -> P5,P6,O
  float* V1[3] = {P5, P6, O};
  for (int r = 0; r < 3; ++r)
    gemm128_kernel<0, 1><<<512, 256, 0, stream>>>(
        U[r], W1 + (size_t)r * DD * DD, rsqi + r * NN, B1 + (size_t)r * DD, P1, V1[r]);
  // h1 = scorecombine(vals1) -> P5 (in-place over vals1[0])
  scorecombine_kernel<<<512, 256, 0, stream>>>(
      P5, P6, O, attn_w + (size_t)1 * DD * DQ, attn_q + (size_t)1 * DQ, P5, nullptr);

  // layer l=0 on h0: vals0[r] = u[r]@W0r ... IN-PLACE on P2,P3,P4
  for (int r = 0; r < 3; ++r)
    gemm128_kernel<0, 1><<<512, 256, 0, stream>>>(
        U[r], W0 + (size_t)r * DD * DD, rsqi + r * NN, B0 + (size_t)r * DD, P1, U[r]);
  // t = scorecombine(vals0) -> P6 (vals1[1] dead)
  scorecombine_kernel<<<512, 256, 0, stream>>>(
      P2, P3, P4, attn_w, attn_q, P6, nullptr);

  // layer l=1 on t: u2[r] = gather(t) -> P2,P3,P4 (vals0 dead)
  for (int r = 0; r < 3; ++r)
    gather_kernel<<<NN * 32 / 256, 256, 0, stream>>>(
        P6, rowptr + r * (NN + 1), col + (size_t)r * NE, rsqo + r * NN, U[r]);
  // vals2[r] = u2[r]@W1r ... IN-PLACE on P2,P3,P4 (resid = t = P6)
  for (int r = 0; r < 3; ++r)
    gemm128_kernel<0, 1><<<512, 256, 0, stream>>>(
        U[r], W1 + (size_t)r * DD * DD, rsqi + r * NN, B1 + (size_t)r * DD, P6, U[r]);
  // h2 = scorecombine(vals2) -> P2 (in-place), attn -> out + ND
  scorecombine_kernel<<<512, 256, 0, stream>>>(
      P2, P3, P4, attn_w + (size_t)1 * DD * DQ, attn_q + (size_t)1 * DQ, P2, out + ND);

  // y = concat(h0=P1, h1=P5, h2=P2) @ CW^T -> out[0..NN*128)
  concat_kernel<<<512, 256, 0, stream>>>(P1, P5, P2, concat_w, out);
}

// Round 6
// 1171.503 us; speedup vs baseline: 11.1065x; 1.3019x over previous
//
#include <hip/hip_runtime.h>

#define NN 50000
#define NE 800000
#define NR 3
#define DD 128
#define DQ 64
#define NB 42          // histogram/fill blocks per (relation, array)
#define SL 19048       // edge slice per block: 42*19048 = 800016 >= NE
#define NW 25000       // packed uint16 words covering NN counters

#define FMA4(ACC, S, W_) \
  ACC.x = fmaf((S), (W_).x, ACC.x); ACC.y = fmaf((S), (W_).y, ACC.y); \
  ACC.z = fmaf((S), (W_).z, ACC.z); ACC.w = fmaf((S), (W_).w, ACC.w);

__device__ __forceinline__ int clampi(int v, int lo, int hi) {
  return v < lo ? lo : (v > hi ? hi : v);
}

// Detect int64-pushed edges (harness doc says int32; insurance only).
__global__ void detect_kernel(const int* __restrict__ e, int* __restrict__ flag) {
  if (threadIdx.x == 0 && blockIdx.x == 0) {
    int f = 1;
    for (int j = 0; j < 32; ++j)
      if (e[2 * j + 1] != 0) f = 0;
    *flag = f;
  }
}

// PhaseA: per-block LDS histograms, packed 2x uint16 per uint32 word.
// grid = (NB, 6); combo c = r*2 + a, a=0 -> dst array, a=1 -> src array.
// hist[c][b][w] written streaming (no global atomics).
__global__ __launch_bounds__(512) void hist6_kernel(
    const int* __restrict__ e, const int* __restrict__ flag,
    unsigned int* __restrict__ hist) {
  __shared__ unsigned int lds[NW];  // 100 KB
  const int b = blockIdx.x;
  const int c = blockIdx.y;
  const int r = c >> 1;
  const int a = c & 1;  // 0: dst, 1: src
  const int tid = threadIdx.x;
  const int f = *flag;
  for (int i = tid; i < NW; i += 512) lds[i] = 0u;
  __syncthreads();
  const long long abase = (long long)r * 2 * NE + (a ? 0 : NE);
  const int beg = b * SL, end = min(beg + SL, NE);
  for (int i = beg + tid; i < end; i += 512) {
    int v = clampi(e[(abase + i) << f], 0, NN - 1);
    atomicAdd(&lds[v >> 1], 1u << ((v & 1) * 16));
  }
  __syncthreads();
  unsigned int* out = hist + ((size_t)c * NB + b) * NW;
  for (int i = tid; i < NW; i += 512) out[i] = lds[i];
}

// PhaseB: sum the NB per-block histograms (unpack before summing),
// emit cnt (int, for scan) and rsqi/rsqo (rsqrt fused).
// grid = (25, 6); 1000 words per block.
__global__ __launch_bounds__(256) void sumhist_kernel(
    const unsigned int* __restrict__ hist, int* __restrict__ cnt,
    float* __restrict__ rsqi, float* __restrict__ rsqo) {
  const int c = blockIdx.y;
  const int r = c >> 1;
  const int a = c & 1;
  for (int wl = threadIdx.x; wl < 1000; wl += 256) {
    int w = blockIdx.x * 1000 + wl;  // < 25000 exact
    unsigned int lo = 0, hi = 0;
    const unsigned int* hp = hist + (size_t)c * NB * NW + w;
#pragma unroll 7
    for (int b = 0; b < NB; ++b) {
      unsigned int v = hp[(size_t)b * NW];
      lo += v & 0xFFFFu;
      hi += v >> 16;
    }
    int n0 = 2 * w, n1 = 2 * w + 1;
    if (a == 0) {
      cnt[r * NN + n0] = (int)lo;
      cnt[r * NN + n1] = (int)hi;
      rsqi[r * NN + n0] = rsqrtf(fmaxf((float)lo, 1.0f));
      rsqi[r * NN + n1] = rsqrtf(fmaxf((float)hi, 1.0f));
    } else {
      rsqo[r * NN + n0] = rsqrtf(fmaxf((float)lo, 1.0f));
      rsqo[r * NN + n1] = rsqrtf(fmaxf((float)hi, 1.0f));
    }
  }
}

// Exclusive scan of cnt -> rowptr. grid = 3 x 1024.
__global__ __launch_bounds__(1024) void scan_kernel(
    const int* __restrict__ cnt, int* __restrict__ rowptr) {
  __shared__ int part[1024];
  const int r = blockIdx.x;
  const int* c = cnt + r * NN;
  int* rp = rowptr + r * (NN + 1);
  const int t = threadIdx.x;
  const int CH = 49;  // 1024*49 = 50176 >= NN
  int beg = t * CH, end = min(beg + CH, NN);
  int s = 0;
  for (int i = beg; i < end; ++i) s += c[i];
  part[t] = s;
  __syncthreads();
  for (int off = 1; off < 1024; off <<= 1) {
    int v = (t >= off) ? part[t - off] : 0;
    __syncthreads();
    if (t >= off) part[t] += v;
    __syncthreads();
  }
  int excl = (t == 0) ? 0 : part[t - 1];
  for (int i = beg; i < end; ++i) {
    rp[i] = excl;
    excl += c[i];
  }
  if (t == 1023) rp[NN] = part[1023];
}

// PhaseC: per-block fill bases. bases[r][b][n] = rowptr[n] + sum_{b'<b} hist_dst[b'][n].
// grid = (25, 3); word w covers nodes 2w, 2w+1.
__global__ __launch_bounds__(256) void bases_kernel(
    const unsigned int* __restrict__ hist, const int* __restrict__ rowptr,
    int* __restrict__ bases) {
  const int r = blockIdx.y;
  for (int wl = threadIdx.x; wl < 1000; wl += 256) {
    int w = blockIdx.x * 1000 + wl;
    int n0 = 2 * w, n1 = 2 * w + 1;
    int run0 = rowptr[r * (NN + 1) + n0];
    int run1 = rowptr[r * (NN + 1) + n1];
    const unsigned int* hp = hist + (size_t)(r * 2) * NB * NW + w;
    int* bp = bases + (size_t)r * NB * NN;
#pragma unroll 7
    for (int b = 0; b < NB; ++b) {
      unsigned int v = hp[(size_t)b * NW];
      bp[(size_t)b * NN + n0] = run0;
      bp[(size_t)b * NN + n1] = run1;
      run0 += (int)(v & 0xFFFFu);
      run1 += (int)(v >> 16);
    }
  }
}

// Atomic-free-global fill: in-block rank via LDS packed cursor + precomputed base.
// grid = (NB, 3).
__global__ __launch_bounds__(512) void fill2_kernel(
    const int* __restrict__ e, const int* __restrict__ flag,
    const int* __restrict__ bases, int* __restrict__ col) {
  __shared__ unsigned int cur[NW];  // 100 KB
  const int b = blockIdx.x;
  const int r = blockIdx.y;
  const int tid = threadIdx.x;
  const int f = *flag;
  for (int i = tid; i < NW; i += 512) cur[i] = 0u;
  __syncthreads();
  const long long sbase = (long long)r * 2 * NE;
  const int beg = b * SL, end = min(beg + SL, NE);
  const int* bp = bases + ((size_t)r * NB + b) * NN;
  for (int i = beg + tid; i < end; i += 512) {
    int s = clampi(e[(sbase + i) << f], 0, NN - 1);
    int d = clampi(e[(sbase + NE + i) << f], 0, NN - 1);
    unsigned int packed = atomicAdd(&cur[d >> 1], 1u << ((d & 1) * 16));
    int local = (int)((packed >> ((d & 1) * 16)) & 0xFFFFu);
    int pos = clampi(bp[d] + local, 0, NE - 1);
    col[(size_t)r * NE + pos] = s;
  }
}

// C = [tanh]( A @ W )  [EPI: * rsqi[n] + bias[j] + resid[n,j]]
// A and C may ALIAS (in-place): rows staged in LDS before the same rows are
// written; row-sets disjoint across blocks. No __restrict__ on A/C.
template <int TANH, int EPI>
__global__ __launch_bounds__(256) void gemm128_kernel(
    const float* A, const float* __restrict__ W,
    const float* __restrict__ rsqi, const float* __restrict__ bias,
    const float* __restrict__ resid, float* C) {
  __shared__ float sW[DD * DD];    // 64 KiB
  __shared__ float sRow[16 * DD];  // 8 KiB
  const int tid = threadIdx.x;
  const int cg = tid & 31;
  const int rs = tid >> 5;
  for (int i = tid; i < DD * DD; i += 256) sW[i] = W[i];

  for (int base = blockIdx.x * 16; base < NN; base += gridDim.x * 16) {
    __syncthreads();
    const float4* A4 = (const float4*)(A + (size_t)base * DD);
    float4* R4 = (float4*)sRow;
#pragma unroll
    for (int i = 0; i < 2; ++i) R4[tid + i * 256] = A4[tid + i * 256];
    __syncthreads();
    const float4* W4 = (const float4*)sW;
    const float4* row0 = (const float4*)(sRow + (rs * 2) * DD);
    const float4* row1 = (const float4*)(sRow + (rs * 2 + 1) * DD);
    float4 acc0 = make_float4(0, 0, 0, 0), acc1 = make_float4(0, 0, 0, 0);
#pragma unroll 8
    for (int k4 = 0; k4 < 32; ++k4) {
      float4 a0 = row0[k4];
      float4 a1 = row1[k4];
      float4 w;
      w = W4[(k4 * 4 + 0) * 32 + cg]; FMA4(acc0, a0.x, w) FMA4(acc1, a1.x, w)
      w = W4[(k4 * 4 + 1) * 32 + cg]; FMA4(acc0, a0.y, w) FMA4(acc1, a1.y, w)
      w = W4[(k4 * 4 + 2) * 32 + cg]; FMA4(acc0, a0.z, w) FMA4(acc1, a1.z, w)
      w = W4[(k4 * 4 + 3) * 32 + cg]; FMA4(acc0, a0.w, w) FMA4(acc1, a1.w, w)
    }
    if (TANH) {
      acc0.x = tanhf(acc0.x); acc0.y = tanhf(acc0.y); acc0.z = tanhf(acc0.z); acc0.w = tanhf(acc0.w);
      acc1.x = tanhf(acc1.x); acc1.y = tanhf(acc1.y); acc1.z = tanhf(acc1.z); acc1.w = tanhf(acc1.w);
    }
    if (EPI) {
      int n0 = base + rs * 2;
      float s0 = rsqi[n0], s1 = rsqi[n0 + 1];
      float4 bb = ((const float4*)bias)[cg];
      float4 r0 = ((const float4*)(resid + (size_t)n0 * DD))[cg];
      float4 r1 = ((const float4*)(resid + (size_t)(n0 + 1) * DD))[cg];
      acc0.x = fmaf(acc0.x, s0, bb.x + r0.x); acc0.y = fmaf(acc0.y, s0, bb.y + r0.y);
      acc0.z = fmaf(acc0.z, s0, bb.z + r0.z); acc0.w = fmaf(acc0.w, s0, bb.w + r0.w);
      acc1.x = fmaf(acc1.x, s1, bb.x + r1.x); acc1.y = fmaf(acc1.y, s1, bb.y + r1.y);
      acc1.z = fmaf(acc1.z, s1, bb.z + r1.z); acc1.w = fmaf(acc1.w, s1, bb.w + r1.w);
    }
    ((float4*)(C + (size_t)(base + rs * 2) * DD))[cg] = acc0;
    ((float4*)(C + (size_t)(base + rs * 2 + 1) * DD))[cg] = acc1;
  }
}

// CSR gather: u[n,:] = sum_{e in in(n)} h[col[e],:] * rsqo[col[e]]
__global__ __launch_bounds__(256) void gather_kernel(
    const float* __restrict__ h, const int* __restrict__ rowptr,
    const int* __restrict__ col, const float* __restrict__ rsqo,
    float* __restrict__ u) {
  int gid = blockIdx.x * 256 + threadIdx.x;
  int n = gid >> 5;
  int lane = gid & 31;
  int e0 = clampi(rowptr[n], 0, NE);
  int e1 = clampi(rowptr[n + 1], e0, NE);
  const float4* h4 = (const float4*)h;
  float4 a0 = make_float4(0, 0, 0, 0), a1 = make_float4(0, 0, 0, 0);
  int e = e0;
  for (; e + 1 < e1; e += 2) {
    int s0 = clampi(col[e], 0, NN - 1), s1 = clampi(col[e + 1], 0, NN - 1);
    float c0 = rsqo[s0], c1 = rsqo[s1];
    float4 v0 = h4[(size_t)s0 * 32 + lane];
    float4 v1 = h4[(size_t)s1 * 32 + lane];
    a0.x = fmaf(v0.x, c0, a0.x); a0.y = fmaf(v0.y, c0, a0.y);
    a0.z = fmaf(v0.z, c0, a0.z); a0.w = fmaf(v0.w, c0, a0.w);
    a1.x = fmaf(v1.x, c1, a1.x); a1.y = fmaf(v1.y, c1, a1.y);
    a1.z = fmaf(v1.z, c1, a1.z); a1.w = fmaf(v1.w, c1, a1.w);
  }
  if (e < e1) {
    int s0 = clampi(col[e], 0, NN - 1);
    float c0 = rsqo[s0];
    float4 v0 = h4[(size_t)s0 * 32 + lane];
    a0.x = fmaf(v0.x, c0, a0.x); a0.y = fmaf(v0.y, c0, a0.y);
    a0.z = fmaf(v0.z, c0, a0.z); a0.w = fmaf(v0.w, c0, a0.w);
  }
  float4 o;
  o.x = a0.x + a1.x; o.y = a0.y + a1.y; o.z = a0.z + a1.z; o.w = a0.w + a1.w;
  ((float4*)u)[gid] = o;
}

// Fused scores + softmax + combine. hout MAY alias v0p (LDS-staged rows).
__global__ __launch_bounds__(256) void scorecombine_kernel(
    const float* v0p, const float* v1p, const float* v2p,
    const float* __restrict__ AW, const float* __restrict__ AQ,
    float* hout, float* __restrict__ attn_out) {
  __shared__ float sW[DD * DQ];       // 32 KiB
  __shared__ float sRow[3][16 * DD];  // 24 KiB
  __shared__ float sS[3][16];
  __shared__ float sQ[DQ];
  const int tid = threadIdx.x;
  const int cg = tid & 15;
  const int rs = tid >> 4;
  for (int i = tid; i < DD * DQ; i += 256) sW[i] = AW[i];
  if (tid < DQ) sQ[tid] = AQ[tid];
  const float* vp[3] = {v0p, v1p, v2p};

  for (int base = blockIdx.x * 16; base < NN; base += gridDim.x * 16) {
    __syncthreads();
#pragma unroll
    for (int r = 0; r < 3; ++r) {
      const float4* V4 = (const float4*)vp[r];
      float4* R4 = (float4*)sRow[r];
#pragma unroll
      for (int i = 0; i < 2; ++i)
        R4[tid + i * 256] = V4[(size_t)base * 32 + tid + i * 256];
    }
    __syncthreads();
    const float4* W4 = (const float4*)sW;
#pragma unroll
    for (int r = 0; r < 3; ++r) {
      const float4* row = (const float4*)(sRow[r] + rs * DD);
      float4 acc = make_float4(0, 0, 0, 0);
#pragma unroll 8
      for (int k4 = 0; k4 < 32; ++k4) {
        float4 a = row[k4];
        float4 w;
        w = W4[(k4 * 4 + 0) * 16 + cg]; FMA4(acc, a.x, w)
        w = W4[(k4 * 4 + 1) * 16 + cg]; FMA4(acc, a.y, w)
        w = W4[(k4 * 4 + 2) * 16 + cg]; FMA4(acc, a.z, w)
        w = W4[(k4 * 4 + 3) * 16 + cg]; FMA4(acc, a.w, w)
      }
      float4 q = ((const float4*)sQ)[cg];
      float p = tanhf(acc.x) * q.x + tanhf(acc.y) * q.y +
                tanhf(acc.z) * q.z + tanhf(acc.w) * q.w;
#pragma unroll
      for (int off = 8; off; off >>= 1) p += __shfl_xor(p, off);
      if (cg == 0) sS[r][rs] = p;
    }
    __syncthreads();
    float s0 = sS[0][rs], s1 = sS[1][rs], s2 = sS[2][rs];
    float mx = fmaxf(s0, fmaxf(s1, s2));
    float e0 = __expf(s0 - mx), e1 = __expf(s1 - mx), e2 = __expf(s2 - mx);
    float inv = 1.0f / (e0 + e1 + e2);
    float a0 = e0 * inv, a1 = e1 * inv, a2 = e2 * inv;
    const float4* P0 = (const float4*)sRow[0];
    const float4* P1 = (const float4*)sRow[1];
    const float4* P2 = (const float4*)sRow[2];
#pragma unroll
    for (int j = 0; j < 2; ++j) {
      int col4 = cg * 2 + j;
      float4 v0 = P0[rs * 32 + col4];
      float4 v1 = P1[rs * 32 + col4];
      float4 v2 = P2[rs * 32 + col4];
      float4 o;
      o.x = a0 * v0.x + a1 * v1.x + a2 * v2.x;
      o.y = a0 * v0.y + a1 * v1.y + a2 * v2.y;
      o.z = a0 * v0.z + a1 * v1.z + a2 * v2.z;
      o.w = a0 * v0.w + a1 * v1.w + a2 * v2.w;
      ((float4*)hout)[(size_t)(base + rs) * 32 + col4] = o;
    }
    if (attn_out != nullptr && cg == 0) {
      int n = base + rs;
      attn_out[(size_t)n * 3 + 0] = a0;
      attn_out[(size_t)n * 3 + 1] = a1;
      attn_out[(size_t)n * 3 + 2] = a2;
    }
  }
}

// Y[n,j] = sum_part sum_k hp[part][n,k] * CW[j, part*128+k]; Y is [NN,128].
__global__ __launch_bounds__(256) void concat_kernel(
    const float* __restrict__ h0, const float* __restrict__ h1,
    const float* __restrict__ h2, const float* __restrict__ CW,
    float* __restrict__ Y) {
  __shared__ float sW[DD * 132];   // transposed, padded stride 132
  __shared__ float sRow[16 * DD];
  const int tid = threadIdx.x;
  const int cg = tid & 31;
  const int rs = tid >> 5;
  const float* hp[3] = {h0, h1, h2};
  for (int part = 0; part < 3; ++part) {
    __syncthreads();
    for (int u = tid; u < DD * DD; u += 256) {
      int j = u >> 7, k = u & 127;
      sW[k * 132 + j] = CW[(size_t)j * 384 + part * DD + k];
    }
    __syncthreads();
    const float* H = hp[part];
    for (int base = blockIdx.x * 16; base < NN; base += gridDim.x * 16) {
      const float4* A4 = (const float4*)(H + (size_t)base * DD);
      float4* R4 = (float4*)sRow;
#pragma unroll
      for (int i = 0; i < 2; ++i) R4[tid + i * 256] = A4[tid + i * 256];
      __syncthreads();
      const float* row0 = sRow + (rs * 2) * DD;
      const float* row1 = row0 + DD;
      float4 acc0 = make_float4(0, 0, 0, 0), acc1 = make_float4(0, 0, 0, 0);
#pragma unroll 8
      for (int k = 0; k < DD; ++k) {
        float4 w = *(const float4*)(sW + k * 132 + cg * 4);
        FMA4(acc0, row0[k], w)
        FMA4(acc1, row1[k], w)
      }
      float4* Y0 = (float4*)(Y + (size_t)(base + rs * 2) * DD);
      float4* Y1 = (float4*)(Y + (size_t)(base + rs * 2 + 1) * DD);
      if (part == 0) {
        Y0[cg] = acc0;
        Y1[cg] = acc1;
      } else {
        float4 y0 = Y0[cg], y1 = Y1[cg];
        y0.x += acc0.x; y0.y += acc0.y; y0.z += acc0.z; y0.w += acc0.w;
        y1.x += acc1.x; y1.y += acc1.y; y1.z += acc1.z; y1.w += acc1.w;
        Y0[cg] = y0;
        Y1[cg] = y1;
      }
      __syncthreads();
    }
  }
}

extern "C" void kernel_launch(void* const* d_in, const int* in_sizes, int n_in,
                              void* d_out, int out_size, void* d_ws, size_t ws_size,
                              hipStream_t stream) {
  const float* x        = (const float*)d_in[0];
  const int*   edges    = (const int*)d_in[1];
  const float* feat_w   = (const float*)d_in[2];
  const float* conv_w   = (const float*)d_in[3];
  const float* conv_b   = (const float*)d_in[4];
  const float* attn_w   = (const float*)d_in[5];
  const float* attn_q   = (const float*)d_in[6];
  const float* concat_w = (const float*)d_in[7];
  float* out = (float*)d_out;   // [NN*128 y][NN*3 attn]

  float* ws = (float*)d_ws;
  float* rsqo = ws;                  // [3][NN]
  float* rsqi = rsqo + 3 * NN;       // [3][NN]
  int* flag = (int*)(rsqi + 3 * NN);
  int* cnt = flag + 16;              // [3][NN]
  int* rowptr = cnt + 3 * NN;        // [3][NN+1] (+pad to 16B)
  int* col = rowptr + 3 * (NN + 1) + 13;  // [3][NE]
  float* P1 = (float*)(col + 3 * (size_t)NE);   // h0
  const size_t ND = (size_t)NN * DD;
  float* P2 = P1 + ND;   // overlay: hist (25.2MB) | later u[0]/vals/h2
  float* P3 = P2 + ND;   // overlay: bases (25.2MB) | later u[1]/vals
  float* P4 = P3 + ND;   // u[2]/vals
  float* P5 = P4 + ND;   // vals1[0] / h1
  float* P6 = P5 + ND;   // vals1[1] / t2
  float* O  = out;       // vals1[2] scratch (y region dead until concat)

  unsigned int* hist = (unsigned int*)P2;  // [6][NB][NW] = 25.2 MB <= plane
  int* bases = (int*)P3;                   // [3][NB][NN] = 25.2 MB <= plane

  const float* W1 = conv_w + (size_t)1 * 3 * DD * DD;
  const float* W0 = conv_w;
  const float* B1 = conv_b + (size_t)1 * 3 * DD;
  const float* B0 = conv_b;

  // CSR + degree prologue (no global atomics)
  detect_kernel<<<1, 64, 0, stream>>>(edges, flag);
  hist6_kernel<<<dim3(NB, 6), 512, 0, stream>>>(edges, flag, hist);
  sumhist_kernel<<<dim3(25, 6), 256, 0, stream>>>(hist, cnt, rsqi, rsqo);
  scan_kernel<<<3, 1024, 0, stream>>>(cnt, rowptr);
  bases_kernel<<<dim3(25, 3), 256, 0, stream>>>(hist, rowptr, bases);
  fill2_kernel<<<dim3(NB, 3), 512, 0, stream>>>(edges, flag, bases, col);

  // h0 = tanh(x @ feat_w) -> P1
  gemm128_kernel<1, 0><<<512, 256, 0, stream>>>(x, feat_w, nullptr, nullptr, nullptr, P1);

  // Shared aggregation u[r] = A_r^T (h0 * rsqo_r) -> P2,P3,P4 (hist/bases dead)
  float* U[3] = {P2, P3, P4};
  for (int r = 0; r < 3; ++r)
    gather_kernel<<<NN * 32 / 256, 256, 0, stream>>>(
        P1, rowptr + r * (NN + 1), col + (size_t)r * NE, rsqo + r * NN, U[r]);

  // layer l=1 on h0 -> vals1 in P5,P6,O
  float* V1[3] = {P5, P6, O};
  for (int r = 0; r < 3; ++r)
    gemm128_kernel<0, 1><<<512, 256, 0, stream>>>(
        U[r], W1 + (size_t)r * DD * DD, rsqi + r * NN, B1 + (size_t)r * DD, P1, V1[r]);
  scorecombine_kernel<<<512, 256, 0, stream>>>(
      P5, P6, O, attn_w + (size_t)1 * DD * DQ, attn_q + (size_t)1 * DQ, P5, nullptr);

  // layer l=0 on h0 -> vals0 IN-PLACE on P2,P3,P4; t -> P6
  for (int r = 0; r < 3; ++r)
    gemm128_kernel<0, 1><<<512, 256, 0, stream>>>(
        U[r], W0 + (size_t)r * DD * DD, rsqi + r * NN, B0 + (size_t)r * DD, P1, U[r]);
  scorecombine_kernel<<<512, 256, 0, stream>>>(
      P2, P3, P4, attn_w, attn_q, P6, nullptr);

  // layer l=1 on t: gathers -> P2,P3,P4; gemms in-place; h2 -> P2, attn -> out+ND
  for (int r = 0; r < 3; ++r)
    gather_kernel<<<NN * 32 / 256, 256, 0, stream>>>(
        P6, rowptr + r * (NN + 1), col + (size_t)r * NE, rsqo + r * NN, U[r]);
  for (int r = 0; r < 3; ++r)
    gemm128_kernel<0, 1><<<512, 256, 0, stream>>>(
        U[r], W1 + (size_t)r * DD * DD, rsqi + r * NN, B1 + (size_t)r * DD, P6, U[r]);
  scorecombine_kernel<<<512, 256, 0, stream>>>(
      P2, P3, P4, attn_w + (size_t)1 * DD * DQ, attn_q + (size_t)1 * DQ, P2, out + ND);

  // y = concat(h0=P1, h1=P5, h2=P2) @ CW^T -> out
  concat_kernel<<<512, 256, 0, stream>>>(P1, P5, P2, concat_w, out);
}

// Round 7
// 808.828 us; speedup vs baseline: 16.0865x; 1.4484x over previous
//
#include <hip/hip_runtime.h>

#define NN 50000
#define NE 800000
#define DD 128
#define DQ 64
#define NB 42          // histogram/fill blocks per (relation, array)
#define SL 19048       // edge slice per block: 42*19048 >= NE
#define NW 25000       // packed uint16 words covering NN counters

typedef __attribute__((ext_vector_type(8))) short short8_t;  // 8 bf16 (4 VGPR)
typedef __attribute__((ext_vector_type(4))) float f32x4;     // MFMA acc

#define FMA4(ACC, S, W_) \
  ACC.x = fmaf((S), (W_).x, ACC.x); ACC.y = fmaf((S), (W_).y, ACC.y); \
  ACC.z = fmaf((S), (W_).z, ACC.z); ACC.w = fmaf((S), (W_).w, ACC.w);

__device__ __forceinline__ int clampi(int v, int lo, int hi) {
  return v < lo ? lo : (v > hi ? hi : v);
}
__device__ __forceinline__ unsigned short f2bf(float f) {  // RNE fp32->bf16
  unsigned int u = __float_as_uint(f);
  return (unsigned short)((u + 0x7FFFu + ((u >> 16) & 1u)) >> 16);
}
__device__ __forceinline__ float bfl(unsigned int u) { return __uint_as_float(u << 16); }
__device__ __forceinline__ float bfh(unsigned int u) { return __uint_as_float(u & 0xFFFF0000u); }

// ---------------- prologue (unchanged from R6) ----------------
__global__ void detect_kernel(const int* __restrict__ e, int* __restrict__ flag) {
  if (threadIdx.x == 0 && blockIdx.x == 0) {
    int f = 1;
    for (int j = 0; j < 32; ++j)
      if (e[2 * j + 1] != 0) f = 0;
    *flag = f;
  }
}

__global__ __launch_bounds__(512) void hist6_kernel(
    const int* __restrict__ e, const int* __restrict__ flag,
    unsigned int* __restrict__ hist) {
  __shared__ unsigned int lds[NW];  // 100 KB
  const int b = blockIdx.x;
  const int c = blockIdx.y;
  const int r = c >> 1;
  const int a = c & 1;  // 0: dst, 1: src
  const int tid = threadIdx.x;
  const int f = *flag;
  for (int i = tid; i < NW; i += 512) lds[i] = 0u;
  __syncthreads();
  const long long abase = (long long)r * 2 * NE + (a ? 0 : NE);
  const int beg = b * SL, end = min(beg + SL, NE);
  for (int i = beg + tid; i < end; i += 512) {
    int v = clampi(e[(abase + i) << f], 0, NN - 1);
    atomicAdd(&lds[v >> 1], 1u << ((v & 1) * 16));
  }
  __syncthreads();
  unsigned int* outp = hist + ((size_t)c * NB + b) * NW;
  for (int i = tid; i < NW; i += 512) outp[i] = lds[i];
}

__global__ __launch_bounds__(256) void sumhist_kernel(
    const unsigned int* __restrict__ hist, int* __restrict__ cnt,
    float* __restrict__ rsqi, float* __restrict__ rsqo) {
  const int c = blockIdx.y;
  const int r = c >> 1;
  const int a = c & 1;
  for (int wl = threadIdx.x; wl < 1000; wl += 256) {
    int w = blockIdx.x * 1000 + wl;
    unsigned int lo = 0, hi = 0;
    const unsigned int* hp = hist + (size_t)c * NB * NW + w;
#pragma unroll 7
    for (int b = 0; b < NB; ++b) {
      unsigned int v = hp[(size_t)b * NW];
      lo += v & 0xFFFFu;
      hi += v >> 16;
    }
    int n0 = 2 * w, n1 = 2 * w + 1;
    if (a == 0) {
      cnt[r * NN + n0] = (int)lo;
      cnt[r * NN + n1] = (int)hi;
      rsqi[r * NN + n0] = rsqrtf(fmaxf((float)lo, 1.0f));
      rsqi[r * NN + n1] = rsqrtf(fmaxf((float)hi, 1.0f));
    } else {
      rsqo[r * NN + n0] = rsqrtf(fmaxf((float)lo, 1.0f));
      rsqo[r * NN + n1] = rsqrtf(fmaxf((float)hi, 1.0f));
    }
  }
}

__global__ __launch_bounds__(1024) void scan_kernel(
    const int* __restrict__ cnt, int* __restrict__ rowptr) {
  __shared__ int part[1024];
  const int r = blockIdx.x;
  const int* c = cnt + r * NN;
  int* rp = rowptr + r * (NN + 1);
  const int t = threadIdx.x;
  const int CH = 49;
  int beg = t * CH, end = min(beg + CH, NN);
  int s = 0;
  for (int i = beg; i < end; ++i) s += c[i];
  part[t] = s;
  __syncthreads();
  for (int off = 1; off < 1024; off <<= 1) {
    int v = (t >= off) ? part[t - off] : 0;
    __syncthreads();
    if (t >= off) part[t] += v;
    __syncthreads();
  }
  int excl = (t == 0) ? 0 : part[t - 1];
  for (int i = beg; i < end; ++i) {
    rp[i] = excl;
    excl += c[i];
  }
  if (t == 1023) rp[NN] = part[1023];
}

__global__ __launch_bounds__(256) void bases_kernel(
    const unsigned int* __restrict__ hist, const int* __restrict__ rowptr,
    int* __restrict__ bases) {
  const int r = blockIdx.y;
  for (int wl = threadIdx.x; wl < 1000; wl += 256) {
    int w = blockIdx.x * 1000 + wl;
    int n0 = 2 * w, n1 = 2 * w + 1;
    int run0 = rowptr[r * (NN + 1) + n0];
    int run1 = rowptr[r * (NN + 1) + n1];
    const unsigned int* hp = hist + (size_t)(r * 2) * NB * NW + w;
    int* bp = bases + (size_t)r * NB * NN;
#pragma unroll 7
    for (int b = 0; b < NB; ++b) {
      unsigned int v = hp[(size_t)b * NW];
      bp[(size_t)b * NN + n0] = run0;
      bp[(size_t)b * NN + n1] = run1;
      run0 += (int)(v & 0xFFFFu);
      run1 += (int)(v >> 16);
    }
  }
}

__global__ __launch_bounds__(512) void fill2_kernel(
    const int* __restrict__ e, const int* __restrict__ flag,
    const int* __restrict__ bases, int* __restrict__ col) {
  __shared__ unsigned int cur[NW];  // 100 KB
  const int b = blockIdx.x;
  const int r = blockIdx.y;
  const int tid = threadIdx.x;
  const int f = *flag;
  for (int i = tid; i < NW; i += 512) cur[i] = 0u;
  __syncthreads();
  const long long sbase = (long long)r * 2 * NE;
  const int beg = b * SL, end = min(beg + SL, NE);
  const int* bp = bases + ((size_t)r * NB + b) * NN;
  for (int i = beg + tid; i < end; i += 512) {
    int s = clampi(e[(sbase + i) << f], 0, NN - 1);
    int d = clampi(e[(sbase + NE + i) << f], 0, NN - 1);
    unsigned int packed = atomicAdd(&cur[d >> 1], 1u << ((d & 1) * 16));
    int local = (int)((packed >> ((d & 1) * 16)) & 0xFFFFu);
    int pos = clampi(bp[d] + local, 0, NE - 1);
    col[(size_t)r * NE + pos] = s;
  }
}

// ---------------- weight fragment prep ----------------
// fw[i] (10 buffers x 16384 ushort): entry (nt,ks,lane,j) = bf16(B[k][n]),
// k = (lane>>4)*8 + j + 32*ks, n = (lane&15) + 16*nt.
// i in 0..5: conv_w[l*3+r] (B=W);  i==6: feat_w;  i>=7: concat part p=i-7,
// B_p[k][n] = concat_w[n][p*128+k]  (CW is [128][384], y = concat @ CW^T).
__global__ __launch_bounds__(256) void prepw_kernel(
    const float* __restrict__ conv_w, const float* __restrict__ feat_w,
    const float* __restrict__ concat_w, unsigned short* __restrict__ fw) {
  const int i = blockIdx.x;
  unsigned short* dst = fw + (size_t)i * 16384;
  for (int e = threadIdx.x; e < 2048; e += 256) {
    int nt = e >> 8, ks = (e >> 6) & 3, lane = e & 63;
    int n = (lane & 15) + nt * 16;
    int kb = (lane >> 4) * 8 + ks * 32;
    unsigned int w[4];
#pragma unroll
    for (int jj = 0; jj < 4; ++jj) {
      int k0 = kb + 2 * jj, k1 = k0 + 1;
      float f0, f1;
      if (i < 6) {
        f0 = conv_w[(size_t)i * 16384 + (size_t)k0 * DD + n];
        f1 = conv_w[(size_t)i * 16384 + (size_t)k1 * DD + n];
      } else if (i == 6) {
        f0 = feat_w[(size_t)k0 * DD + n];
        f1 = feat_w[(size_t)k1 * DD + n];
      } else {
        int p = i - 7;
        f0 = concat_w[(size_t)n * 384 + p * DD + k0];
        f1 = concat_w[(size_t)n * 384 + p * DD + k1];
      }
      w[jj] = (unsigned int)f2bf(f0) | ((unsigned int)f2bf(f1) << 16);
    }
    ((uint4*)dst)[e] = make_uint4(w[0], w[1], w[2], w[3]);
  }
}

// ---------------- MFMA GEMM: C = [tanh](A @ W) [EPI: *rsqi + bias + resid] ----------------
// A: bf16 [NN][128] (or fp32 if AFP32). W: fragment buffer (16384 ushort).
// Block 256 thr = 4 waves; wave = 32 rows (2 m-tiles) x 128 cols. grid = 391.
template <int AFP32, int TANH, int EPI, int WRITEB>
__global__ __launch_bounds__(256) void mgemm_kernel(
    const void* __restrict__ Ap, const unsigned short* __restrict__ fw,
    const float* __restrict__ rsqi, const float* __restrict__ bias,
    const float* __restrict__ resid, float* __restrict__ C,
    unsigned short* __restrict__ Cb) {
  __shared__ unsigned short sF[16384];  // 32 KB
  const int tid = threadIdx.x;
  {
    const float4* s = (const float4*)fw;
    float4* d = (float4*)sF;
#pragma unroll
    for (int i = 0; i < 8; ++i) d[tid + i * 256] = s[tid + i * 256];
  }
  __syncthreads();
  const int w = tid >> 6, l = tid & 63, la = l & 15, gr = l >> 4;
  const int row0 = blockIdx.x * 128 + w * 32;
  if (row0 >= NN) return;            // after barrier: safe
  const bool m1ok = (row0 + 32) <= NN;  // NN % 16 == 0, tiles 16-granular
  short8_t a[2][4];
#pragma unroll
  for (int m = 0; m < 2; ++m) {
    const int r = row0 + m * 16 + la;
    const bool ok = (m == 0) || m1ok;
    if (AFP32) {
      const float* ap = (const float*)Ap + (size_t)r * DD + gr * 8;
#pragma unroll
      for (int ks = 0; ks < 4; ++ks) {
        short8_t v = (short8_t)0;
        if (ok) {
          float4 x0 = *(const float4*)(ap + ks * 32);
          float4 x1 = *(const float4*)(ap + ks * 32 + 4);
          v[0] = (short)f2bf(x0.x); v[1] = (short)f2bf(x0.y);
          v[2] = (short)f2bf(x0.z); v[3] = (short)f2bf(x0.w);
          v[4] = (short)f2bf(x1.x); v[5] = (short)f2bf(x1.y);
          v[6] = (short)f2bf(x1.z); v[7] = (short)f2bf(x1.w);
        }
        a[m][ks] = v;
      }
    } else {
      const unsigned short* ap = (const unsigned short*)Ap + (size_t)r * DD + gr * 8;
#pragma unroll
      for (int ks = 0; ks < 4; ++ks)
        a[m][ks] = ok ? *(const short8_t*)(ap + ks * 32) : (short8_t)0;
    }
  }
  f32x4 zero = {0.f, 0.f, 0.f, 0.f};
  f32x4 acc[2][8];
#pragma unroll
  for (int m = 0; m < 2; ++m)
#pragma unroll
    for (int nt = 0; nt < 8; ++nt) acc[m][nt] = zero;
#pragma unroll
  for (int nt = 0; nt < 8; ++nt) {
#pragma unroll
    for (int ks = 0; ks < 4; ++ks) {
      short8_t b = *(const short8_t*)(sF + ((nt * 4 + ks) * 64 + l) * 8);
      acc[0][nt] = __builtin_amdgcn_mfma_f32_16x16x32_bf16(a[0][ks], b, acc[0][nt], 0, 0, 0);
      acc[1][nt] = __builtin_amdgcn_mfma_f32_16x16x32_bf16(a[1][ks], b, acc[1][nt], 0, 0, 0);
    }
  }
  // epilogue: D[row0 + m*16 + gr*4 + rr][nt*16 + la]
#pragma unroll
  for (int m = 0; m < 2; ++m) {
    if (m == 1 && !m1ok) break;
#pragma unroll
    for (int rr = 0; rr < 4; ++rr) {
      const int row = row0 + m * 16 + gr * 4 + rr;
      const float sc = EPI ? rsqi[row] : 0.0f;
#pragma unroll
      for (int nt = 0; nt < 8; ++nt) {
        const int c0 = nt * 16 + la;
        float v = acc[m][nt][rr];
        if (TANH) v = tanhf(v);
        if (EPI) v = fmaf(v, sc, bias[c0] + resid[(size_t)row * DD + c0]);
        C[(size_t)row * DD + c0] = v;
        if (WRITEB) Cb[(size_t)row * DD + c0] = f2bf(v);
      }
    }
  }
}

// ---------------- MFMA concat: y = sum_p hb[p] @ Bp (K=384) ----------------
// 512 thr = 8 waves; wave = 32 rows; block = 256 rows. grid = 196. LDS 96 KB.
__global__ __launch_bounds__(512) void mconcat_kernel(
    const unsigned short* __restrict__ h0b, const unsigned short* __restrict__ h1b,
    const unsigned short* __restrict__ h2b, const unsigned short* __restrict__ fwc,
    float* __restrict__ Y) {
  __shared__ unsigned short sF[3 * 16384];  // 96 KB
  const int tid = threadIdx.x;
  {
    const float4* s = (const float4*)fwc;
    float4* d = (float4*)sF;
#pragma unroll
    for (int i = 0; i < 12; ++i) d[tid + i * 512] = s[tid + i * 512];
  }
  __syncthreads();
  const int w = tid >> 6, l = tid & 63, la = l & 15, gr = l >> 4;
  const int row0 = blockIdx.x * 256 + w * 32;
  if (row0 >= NN) return;
  const bool m1ok = (row0 + 32) <= NN;
  const unsigned short* hb[3] = {h0b, h1b, h2b};
  f32x4 zero = {0.f, 0.f, 0.f, 0.f};
  f32x4 acc[2][8];
#pragma unroll
  for (int m = 0; m < 2; ++m)
#pragma unroll
    for (int nt = 0; nt < 8; ++nt) acc[m][nt] = zero;
#pragma unroll
  for (int p = 0; p < 3; ++p) {
    short8_t a[2][4];
#pragma unroll
    for (int m = 0; m < 2; ++m) {
      const int r = row0 + m * 16 + la;
      const bool ok = (m == 0) || m1ok;
      const unsigned short* ap = hb[p] + (size_t)r * DD + gr * 8;
#pragma unroll
      for (int ks = 0; ks < 4; ++ks)
        a[m][ks] = ok ? *(const short8_t*)(ap + ks * 32) : (short8_t)0;
    }
    const unsigned short* sfp = sF + p * 16384;
#pragma unroll
    for (int nt = 0; nt < 8; ++nt) {
#pragma unroll
      for (int ks = 0; ks < 4; ++ks) {
        short8_t b = *(const short8_t*)(sfp + ((nt * 4 + ks) * 64 + l) * 8);
        acc[0][nt] = __builtin_amdgcn_mfma_f32_16x16x32_bf16(a[0][ks], b, acc[0][nt], 0, 0, 0);
        acc[1][nt] = __builtin_amdgcn_mfma_f32_16x16x32_bf16(a[1][ks], b, acc[1][nt], 0, 0, 0);
      }
    }
  }
#pragma unroll
  for (int m = 0; m < 2; ++m) {
    if (m == 1 && !m1ok) break;
#pragma unroll
    for (int rr = 0; rr < 4; ++rr) {
      const int row = row0 + m * 16 + gr * 4 + rr;
#pragma unroll
      for (int nt = 0; nt < 8; ++nt)
        Y[(size_t)row * DD + nt * 16 + la] = acc[m][nt][rr];
    }
  }
}

// ---------------- bf16 CSR gather: u[n] = sum h[col[e]] * rsqo[col[e]] ----------------
// 32 lanes/node, 8B (4 bf16) per lane. grid = NN*32/256 = 6250.
__global__ __launch_bounds__(256) void gatherb_kernel(
    const unsigned short* __restrict__ hb, const int* __restrict__ rowptr,
    const int* __restrict__ col, const float* __restrict__ rsqo,
    unsigned short* __restrict__ ub) {
  int gid = blockIdx.x * 256 + threadIdx.x;
  int n = gid >> 5;
  int lane = gid & 31;
  int e0 = clampi(rowptr[n], 0, NE);
  int e1 = clampi(rowptr[n + 1], e0, NE);
  const uint2* h2 = (const uint2*)hb;  // row = 32 x uint2 (256B)
  float a0 = 0, a1 = 0, a2 = 0, a3 = 0, b0 = 0, b1 = 0, b2 = 0, b3 = 0;
  int e = e0;
  for (; e + 1 < e1; e += 2) {
    int s0 = clampi(col[e], 0, NN - 1), s1 = clampi(col[e + 1], 0, NN - 1);
    float c0 = rsqo[s0], c1 = rsqo[s1];
    uint2 v0 = h2[(size_t)s0 * 32 + lane];
    uint2 v1 = h2[(size_t)s1 * 32 + lane];
    a0 = fmaf(bfl(v0.x), c0, a0); a1 = fmaf(bfh(v0.x), c0, a1);
    a2 = fmaf(bfl(v0.y), c0, a2); a3 = fmaf(bfh(v0.y), c0, a3);
    b0 = fmaf(bfl(v1.x), c1, b0); b1 = fmaf(bfh(v1.x), c1, b1);
    b2 = fmaf(bfl(v1.y), c1, b2); b3 = fmaf(bfh(v1.y), c1, b3);
  }
  if (e < e1) {
    int s0 = clampi(col[e], 0, NN - 1);
    float c0 = rsqo[s0];
    uint2 v0 = h2[(size_t)s0 * 32 + lane];
    a0 = fmaf(bfl(v0.x), c0, a0); a1 = fmaf(bfh(v0.x), c0, a1);
    a2 = fmaf(bfl(v0.y), c0, a2); a3 = fmaf(bfh(v0.y), c0, a3);
  }
  a0 += b0; a1 += b1; a2 += b2; a3 += b3;
  uint2 o;
  o.x = (unsigned int)f2bf(a0) | ((unsigned int)f2bf(a1) << 16);
  o.y = (unsigned int)f2bf(a2) | ((unsigned int)f2bf(a3) << 16);
  ((uint2*)ub)[gid] = o;
}

// ---------------- fused scores + softmax + combine (+bf16 copy) ----------------
__global__ __launch_bounds__(256) void scorecombine_kernel(
    const float* v0p, const float* v1p, const float* v2p,
    const float* __restrict__ AW, const float* __restrict__ AQ,
    float* hout, unsigned short* __restrict__ houtb,
    float* __restrict__ attn_out) {
  __shared__ float sW[DD * DQ];       // 32 KB
  __shared__ float sRow[3][16 * DD];  // 24 KB
  __shared__ float sS[3][16];
  __shared__ float sQ[DQ];
  const int tid = threadIdx.x;
  const int cg = tid & 15;
  const int rs = tid >> 4;
  for (int i = tid; i < DD * DQ; i += 256) sW[i] = AW[i];
  if (tid < DQ) sQ[tid] = AQ[tid];
  const float* vp[3] = {v0p, v1p, v2p};

  for (int base = blockIdx.x * 16; base < NN; base += gridDim.x * 16) {
    __syncthreads();
#pragma unroll
    for (int r = 0; r < 3; ++r) {
      const float4* V4 = (const float4*)vp[r];
      float4* R4 = (float4*)sRow[r];
#pragma unroll
      for (int i = 0; i < 2; ++i)
        R4[tid + i * 256] = V4[(size_t)base * 32 + tid + i * 256];
    }
    __syncthreads();
    const float4* W4 = (const float4*)sW;
#pragma unroll
    for (int r = 0; r < 3; ++r) {
      const float4* row = (const float4*)(sRow[r] + rs * DD);
      float4 acc = make_float4(0, 0, 0, 0);
#pragma unroll 8
      for (int k4 = 0; k4 < 32; ++k4) {
        float4 a = row[k4];
        float4 wv;
        wv = W4[(k4 * 4 + 0) * 16 + cg]; FMA4(acc, a.x, wv)
        wv = W4[(k4 * 4 + 1) * 16 + cg]; FMA4(acc, a.y, wv)
        wv = W4[(k4 * 4 + 2) * 16 + cg]; FMA4(acc, a.z, wv)
        wv = W4[(k4 * 4 + 3) * 16 + cg]; FMA4(acc, a.w, wv)
      }
      float4 q = ((const float4*)sQ)[cg];
      float p = tanhf(acc.x) * q.x + tanhf(acc.y) * q.y +
                tanhf(acc.z) * q.z + tanhf(acc.w) * q.w;
#pragma unroll
      for (int off = 8; off; off >>= 1) p += __shfl_xor(p, off);
      if (cg == 0) sS[r][rs] = p;
    }
    __syncthreads();
    float s0 = sS[0][rs], s1 = sS[1][rs], s2 = sS[2][rs];
    float mx = fmaxf(s0, fmaxf(s1, s2));
    float e0 = __expf(s0 - mx), e1 = __expf(s1 - mx), e2 = __expf(s2 - mx);
    float inv = 1.0f / (e0 + e1 + e2);
    float a0 = e0 * inv, a1 = e1 * inv, a2 = e2 * inv;
    const float4* P0 = (const float4*)sRow[0];
    const float4* P1 = (const float4*)sRow[1];
    const float4* P2 = (const float4*)sRow[2];
#pragma unroll
    for (int j = 0; j < 2; ++j) {
      int col4 = cg * 2 + j;
      float4 v0 = P0[rs * 32 + col4];
      float4 v1 = P1[rs * 32 + col4];
      float4 v2 = P2[rs * 32 + col4];
      float4 o;
      o.x = a0 * v0.x + a1 * v1.x + a2 * v2.x;
      o.y = a0 * v0.y + a1 * v1.y + a2 * v2.y;
      o.z = a0 * v0.z + a1 * v1.z + a2 * v2.z;
      o.w = a0 * v0.w + a1 * v1.w + a2 * v2.w;
      ((float4*)hout)[(size_t)(base + rs) * 32 + col4] = o;
      uint2 ob;
      ob.x = (unsigned int)f2bf(o.x) | ((unsigned int)f2bf(o.y) << 16);
      ob.y = (unsigned int)f2bf(o.z) | ((unsigned int)f2bf(o.w) << 16);
      ((uint2*)houtb)[(size_t)(base + rs) * 32 + col4] = ob;
    }
    if (attn_out != nullptr && cg == 0) {
      int n = base + rs;
      attn_out[(size_t)n * 3 + 0] = a0;
      attn_out[(size_t)n * 3 + 1] = a1;
      attn_out[(size_t)n * 3 + 2] = a2;
    }
  }
}

extern "C" void kernel_launch(void* const* d_in, const int* in_sizes, int n_in,
                              void* d_out, int out_size, void* d_ws, size_t ws_size,
                              hipStream_t stream) {
  const float* x        = (const float*)d_in[0];
  const int*   edges    = (const int*)d_in[1];
  const float* feat_w   = (const float*)d_in[2];
  const float* conv_w   = (const float*)d_in[3];
  const float* conv_b   = (const float*)d_in[4];
  const float* attn_w   = (const float*)d_in[5];
  const float* attn_q   = (const float*)d_in[6];
  const float* concat_w = (const float*)d_in[7];
  float* out = (float*)d_out;   // [NN*128 y][NN*3 attn]

  float* ws = (float*)d_ws;
  float* rsqo = ws;                   // [3][NN]
  float* rsqi = rsqo + 3 * NN;        // [3][NN]
  int* flag = (int*)(rsqi + 3 * NN);
  int* cnt = flag + 16;               // [3][NN]; fw overlays after scan
  int* rowptr = cnt + 3 * NN;         // [3][NN+1] (+pad)
  int* col = rowptr + 3 * (NN + 1) + 13;  // [3][NE]
  const size_t ND = (size_t)NN * DD;
  float* P1 = (float*)(col + 3 * (size_t)NE);  // h0 fp32, later t2 fp32
  float* PA = P1 + ND;   // vals plane (hist overlay in prologue)
  float* PB = PA + ND;   // vals plane (bases overlay in prologue)
  unsigned short* U0 = (unsigned short*)(PB + ND);  // u bf16; later h2b
  unsigned short* U1 = U0 + ND;
  unsigned short* U2 = U1 + ND;
  unsigned short* B0 = U2 + ND;   // h0b
  unsigned short* B1 = B0 + ND;   // h1b
  unsigned short* B2 = B1 + ND;   // t2b
  unsigned short* fw = (unsigned short*)cnt;   // 10 x 16384 ushort (<= cnt size)
  unsigned int* hist = (unsigned int*)PA;      // 6*NB*NW <= ND
  int* bases = (int*)PB;                       // 3*NB*NN <= ND
  float* O = out;                              // vals plane in y region

  // prologue: degrees + CSR (no global atomics) + weight fragments
  detect_kernel<<<1, 64, 0, stream>>>(edges, flag);
  hist6_kernel<<<dim3(NB, 6), 512, 0, stream>>>(edges, flag, hist);
  sumhist_kernel<<<dim3(25, 6), 256, 0, stream>>>(hist, cnt, rsqi, rsqo);
  scan_kernel<<<3, 1024, 0, stream>>>(cnt, rowptr);
  prepw_kernel<<<10, 256, 0, stream>>>(conv_w, feat_w, concat_w, fw);  // cnt dead
  bases_kernel<<<dim3(25, 3), 256, 0, stream>>>(hist, rowptr, bases);
  fill2_kernel<<<dim3(NB, 3), 512, 0, stream>>>(edges, flag, bases, col);

  // h0 = tanh(x @ feat_w) -> P1 (fp32) + B0 (bf16)
  mgemm_kernel<1, 1, 0, 1><<<391, 256, 0, stream>>>(
      x, fw + (size_t)6 * 16384, nullptr, nullptr, nullptr, P1, B0);

  unsigned short* U[3] = {U0, U1, U2};
  float* V[3] = {PA, PB, O};

  // shared u[r] = A_r^T (h0 * rsqo_r), bf16
  for (int r = 0; r < 3; ++r)
    gatherb_kernel<<<NN * 32 / 256, 256, 0, stream>>>(
        B0, rowptr + r * (NN + 1), col + (size_t)r * NE, rsqo + r * NN, U[r]);

  // layer l=1 on h0 -> vals1 (PA,PB,O); h1 -> B1 (fp32 dump to PA in-place)
  for (int r = 0; r < 3; ++r)
    mgemm_kernel<0, 0, 1, 0><<<391, 256, 0, stream>>>(
        U[r], fw + (size_t)(3 + r) * 16384, rsqi + r * NN,
        conv_b + (size_t)(3 + r) * DD, P1, V[r], nullptr);
  scorecombine_kernel<<<512, 256, 0, stream>>>(
      PA, PB, O, attn_w + (size_t)DD * DQ, attn_q + DQ, PA, B1, nullptr);

  // layer l=0 on h0 (reuses u) -> vals0 (PA,PB,O); t -> P1 fp32 + B2 bf16
  for (int r = 0; r < 3; ++r)
    mgemm_kernel<0, 0, 1, 0><<<391, 256, 0, stream>>>(
        U[r], fw + (size_t)r * 16384, rsqi + r * NN,
        conv_b + (size_t)r * DD, P1, V[r], nullptr);
  scorecombine_kernel<<<512, 256, 0, stream>>>(
      PA, PB, O, attn_w, attn_q, P1, B2, nullptr);

  // layer l=1 on t: gathers from B2 -> U; gemms (resid = t = P1) -> vals2
  for (int r = 0; r < 3; ++r)
    gatherb_kernel<<<NN * 32 / 256, 256, 0, stream>>>(
        B2, rowptr + r * (NN + 1), col + (size_t)r * NE, rsqo + r * NN, U[r]);
  for (int r = 0; r < 3; ++r)
    mgemm_kernel<0, 0, 1, 0><<<391, 256, 0, stream>>>(
        U[r], fw + (size_t)(3 + r) * 16384, rsqi + r * NN,
        conv_b + (size_t)(3 + r) * DD, P1, V[r], nullptr);
  // h2 -> U0 region (bf16), attn -> out+ND, fp32 dump -> PB
  scorecombine_kernel<<<512, 256, 0, stream>>>(
      PA, PB, O, attn_w + (size_t)DD * DQ, attn_q + DQ, PB, U0, out + ND);

  // y = [h0|h1|h2] @ CW^T -> out (overwrites the O vals plane; reads bf16 only)
  mconcat_kernel<<<196, 512, 0, stream>>>(B0, B1, U0, fw + (size_t)7 * 16384, out);
}

// Round 8
// 686.524 us; speedup vs baseline: 18.9524x; 1.1782x over previous
//
#include <hip/hip_runtime.h>

#define NN 50000
#define NE 800000
#define DD 128
#define DQ 64
#define NB 42          // histogram/fill blocks per (relation, array)
#define SL 19048       // edge slice per block: 42*19048 >= NE
#define NW 25000       // packed uint16 words covering NN counters

typedef __attribute__((ext_vector_type(8))) short short8_t;  // 8 bf16 (4 VGPR)
typedef __attribute__((ext_vector_type(4))) float f32x4;     // MFMA acc

#define FMA4(ACC, S, W_) \
  ACC.x = fmaf((S), (W_).x, ACC.x); ACC.y = fmaf((S), (W_).y, ACC.y); \
  ACC.z = fmaf((S), (W_).z, ACC.z); ACC.w = fmaf((S), (W_).w, ACC.w);

__device__ __forceinline__ int clampi(int v, int lo, int hi) {
  return v < lo ? lo : (v > hi ? hi : v);
}
__device__ __forceinline__ unsigned short f2bf(float f) {  // RNE fp32->bf16
  unsigned int u = __float_as_uint(f);
  return (unsigned short)((u + 0x7FFFu + ((u >> 16) & 1u)) >> 16);
}
__device__ __forceinline__ float bfl(unsigned int u) { return __uint_as_float(u << 16); }
__device__ __forceinline__ float bfh(unsigned int u) { return __uint_as_float(u & 0xFFFF0000u); }

// ---------------- prologue ----------------
__global__ void detect_kernel(const int* __restrict__ e, int* __restrict__ flag) {
  if (threadIdx.x == 0 && blockIdx.x == 0) {
    int f = 1;
    for (int j = 0; j < 32; ++j)
      if (e[2 * j + 1] != 0) f = 0;
    *flag = f;
  }
}

__global__ __launch_bounds__(512) void hist6_kernel(
    const int* __restrict__ e, const int* __restrict__ flag,
    unsigned int* __restrict__ hist) {
  __shared__ unsigned int lds[NW];  // 100 KB
  const int b = blockIdx.x;
  const int c = blockIdx.y;
  const int r = c >> 1;
  const int a = c & 1;  // 0: dst, 1: src
  const int tid = threadIdx.x;
  const int f = *flag;
  for (int i = tid; i < NW; i += 512) lds[i] = 0u;
  __syncthreads();
  const long long abase = (long long)r * 2 * NE + (a ? 0 : NE);
  const int beg = b * SL, end = min(beg + SL, NE);
  for (int i = beg + tid; i < end; i += 512) {
    int v = clampi(e[(abase + i) << f], 0, NN - 1);
    atomicAdd(&lds[v >> 1], 1u << ((v & 1) * 16));
  }
  __syncthreads();
  unsigned int* outp = hist + ((size_t)c * NB + b) * NW;
  for (int i = tid; i < NW; i += 512) outp[i] = lds[i];
}

__global__ __launch_bounds__(256) void sumhist_kernel(
    const unsigned int* __restrict__ hist, int* __restrict__ cnt,
    float* __restrict__ rsqi, float* __restrict__ rsqo) {
  const int c = blockIdx.y;
  const int r = c >> 1;
  const int a = c & 1;
  for (int wl = threadIdx.x; wl < 1000; wl += 256) {
    int w = blockIdx.x * 1000 + wl;
    unsigned int lo = 0, hi = 0;
    const unsigned int* hp = hist + (size_t)c * NB * NW + w;
#pragma unroll 7
    for (int b = 0; b < NB; ++b) {
      unsigned int v = hp[(size_t)b * NW];
      lo += v & 0xFFFFu;
      hi += v >> 16;
    }
    int n0 = 2 * w, n1 = 2 * w + 1;
    if (a == 0) {
      cnt[r * NN + n0] = (int)lo;
      cnt[r * NN + n1] = (int)hi;
      rsqi[r * NN + n0] = rsqrtf(fmaxf((float)lo, 1.0f));
      rsqi[r * NN + n1] = rsqrtf(fmaxf((float)hi, 1.0f));
    } else {
      rsqo[r * NN + n0] = rsqrtf(fmaxf((float)lo, 1.0f));
      rsqo[r * NN + n1] = rsqrtf(fmaxf((float)hi, 1.0f));
    }
  }
}

__global__ __launch_bounds__(1024) void scan_kernel(
    const int* __restrict__ cnt, int* __restrict__ rowptr) {
  __shared__ int part[1024];
  const int r = blockIdx.x;
  const int* c = cnt + r * NN;
  int* rp = rowptr + r * (NN + 1);
  const int t = threadIdx.x;
  const int CH = 49;
  int beg = t * CH, end = min(beg + CH, NN);
  int s = 0;
  for (int i = beg; i < end; ++i) s += c[i];
  part[t] = s;
  __syncthreads();
  for (int off = 1; off < 1024; off <<= 1) {
    int v = (t >= off) ? part[t - off] : 0;
    __syncthreads();
    if (t >= off) part[t] += v;
    __syncthreads();
  }
  int excl = (t == 0) ? 0 : part[t - 1];
  for (int i = beg; i < end; ++i) {
    rp[i] = excl;
    excl += c[i];
  }
  if (t == 1023) rp[NN] = part[1023];
}

__global__ __launch_bounds__(256) void bases_kernel(
    const unsigned int* __restrict__ hist, const int* __restrict__ rowptr,
    int* __restrict__ bases) {
  const int r = blockIdx.y;
  for (int wl = threadIdx.x; wl < 1000; wl += 256) {
    int w = blockIdx.x * 1000 + wl;
    int n0 = 2 * w, n1 = 2 * w + 1;
    int run0 = rowptr[r * (NN + 1) + n0];
    int run1 = rowptr[r * (NN + 1) + n1];
    const unsigned int* hp = hist + (size_t)(r * 2) * NB * NW + w;
    int* bp = bases + (size_t)r * NB * NN;
#pragma unroll 7
    for (int b = 0; b < NB; ++b) {
      unsigned int v = hp[(size_t)b * NW];
      bp[(size_t)b * NN + n0] = run0;
      bp[(size_t)b * NN + n1] = run1;
      run0 += (int)(v & 0xFFFFu);
      run1 += (int)(v >> 16);
    }
  }
}

__global__ __launch_bounds__(512) void fill2_kernel(
    const int* __restrict__ e, const int* __restrict__ flag,
    const int* __restrict__ bases, int* __restrict__ col) {
  __shared__ unsigned int cur[NW];  // 100 KB
  const int b = blockIdx.x;
  const int r = blockIdx.y;
  const int tid = threadIdx.x;
  const int f = *flag;
  for (int i = tid; i < NW; i += 512) cur[i] = 0u;
  __syncthreads();
  const long long sbase = (long long)r * 2 * NE;
  const int beg = b * SL, end = min(beg + SL, NE);
  const int* bp = bases + ((size_t)r * NB + b) * NN;
  for (int i = beg + tid; i < end; i += 512) {
    int s = clampi(e[(sbase + i) << f], 0, NN - 1);
    int d = clampi(e[(sbase + NE + i) << f], 0, NN - 1);
    unsigned int packed = atomicAdd(&cur[d >> 1], 1u << ((d & 1) * 16));
    int local = (int)((packed >> ((d & 1) * 16)) & 0xFFFFu);
    int pos = clampi(bp[d] + local, 0, NE - 1);
    col[(size_t)r * NE + pos] = s;
  }
}

// ---------------- weight fragment prep (10 x 16384 ushort) ----------------
__global__ __launch_bounds__(256) void prepw_kernel(
    const float* __restrict__ conv_w, const float* __restrict__ feat_w,
    const float* __restrict__ concat_w, unsigned short* __restrict__ fw) {
  const int i = blockIdx.x;
  unsigned short* dst = fw + (size_t)i * 16384;
  for (int e = threadIdx.x; e < 2048; e += 256) {
    int nt = e >> 8, ks = (e >> 6) & 3, lane = e & 63;
    int n = (lane & 15) + nt * 16;
    int kb = (lane >> 4) * 8 + ks * 32;
    unsigned int w[4];
#pragma unroll
    for (int jj = 0; jj < 4; ++jj) {
      int k0 = kb + 2 * jj, k1 = k0 + 1;
      float f0, f1;
      if (i < 6) {
        f0 = conv_w[(size_t)i * 16384 + (size_t)k0 * DD + n];
        f1 = conv_w[(size_t)i * 16384 + (size_t)k1 * DD + n];
      } else if (i == 6) {
        f0 = feat_w[(size_t)k0 * DD + n];
        f1 = feat_w[(size_t)k1 * DD + n];
      } else {
        int p = i - 7;
        f0 = concat_w[(size_t)n * 384 + p * DD + k0];
        f1 = concat_w[(size_t)n * 384 + p * DD + k1];
      }
      w[jj] = (unsigned int)f2bf(f0) | ((unsigned int)f2bf(f1) << 16);
    }
    ((uint4*)dst)[e] = make_uint4(w[0], w[1], w[2], w[3]);
  }
}

// ---------------- MFMA GEMM, optionally batched over gridDim.y = relations ----
// C = [tanh](A @ W) [EPI: *rsqi + bias + resid]; WF32 -> fp32 C, WBF -> bf16 Cb.
template <int AFP32, int TANH, int EPI, int WF32, int WBF>
__global__ __launch_bounds__(256) void mgemm_kernel(
    const void* __restrict__ Ap, const unsigned short* __restrict__ fw,
    const float* __restrict__ rsqi, const float* __restrict__ bias,
    const float* __restrict__ resid, float* __restrict__ C,
    unsigned short* __restrict__ Cb) {
  const size_t ND = (size_t)NN * DD;
  const int rel = blockIdx.y;
  const unsigned short* fwp = fw + (size_t)rel * 16384;
  const float* rsqip = EPI ? rsqi + (size_t)rel * NN : nullptr;
  const float* biasp = EPI ? bias + (size_t)rel * DD : nullptr;
  unsigned short* Cbp = WBF ? Cb + (size_t)rel * ND : nullptr;
  __shared__ unsigned short sF[16384];  // 32 KB
  const int tid = threadIdx.x;
  {
    const float4* s = (const float4*)fwp;
    float4* d = (float4*)sF;
#pragma unroll
    for (int i = 0; i < 8; ++i) d[tid + i * 256] = s[tid + i * 256];
  }
  __syncthreads();
  const int w = tid >> 6, l = tid & 63, la = l & 15, gr = l >> 4;
  const int row0 = blockIdx.x * 128 + w * 32;
  if (row0 >= NN) return;  // after barrier: safe
  const bool m1ok = (row0 + 32) <= NN;  // NN % 16 == 0
  short8_t a[2][4];
#pragma unroll
  for (int m = 0; m < 2; ++m) {
    const int r = row0 + m * 16 + la;
    const bool ok = (m == 0) || m1ok;
    if (AFP32) {
      const float* ap = (const float*)Ap + (size_t)r * DD + gr * 8;
#pragma unroll
      for (int ks = 0; ks < 4; ++ks) {
        short8_t v = (short8_t)0;
        if (ok) {
          float4 x0 = *(const float4*)(ap + ks * 32);
          float4 x1 = *(const float4*)(ap + ks * 32 + 4);
          v[0] = (short)f2bf(x0.x); v[1] = (short)f2bf(x0.y);
          v[2] = (short)f2bf(x0.z); v[3] = (short)f2bf(x0.w);
          v[4] = (short)f2bf(x1.x); v[5] = (short)f2bf(x1.y);
          v[6] = (short)f2bf(x1.z); v[7] = (short)f2bf(x1.w);
        }
        a[m][ks] = v;
      }
    } else {
      const unsigned short* ap =
          (const unsigned short*)Ap + (size_t)rel * ND + (size_t)r * DD + gr * 8;
#pragma unroll
      for (int ks = 0; ks < 4; ++ks)
        a[m][ks] = ok ? *(const short8_t*)(ap + ks * 32) : (short8_t)0;
    }
  }
  f32x4 zero = {0.f, 0.f, 0.f, 0.f};
  f32x4 acc[2][8];
#pragma unroll
  for (int m = 0; m < 2; ++m)
#pragma unroll
    for (int nt = 0; nt < 8; ++nt) acc[m][nt] = zero;
#pragma unroll
  for (int nt = 0; nt < 8; ++nt) {
#pragma unroll
    for (int ks = 0; ks < 4; ++ks) {
      short8_t b = *(const short8_t*)(sF + ((nt * 4 + ks) * 64 + l) * 8);
      acc[0][nt] = __builtin_amdgcn_mfma_f32_16x16x32_bf16(a[0][ks], b, acc[0][nt], 0, 0, 0);
      acc[1][nt] = __builtin_amdgcn_mfma_f32_16x16x32_bf16(a[1][ks], b, acc[1][nt], 0, 0, 0);
    }
  }
#pragma unroll
  for (int m = 0; m < 2; ++m) {
    if (m == 1 && !m1ok) break;
#pragma unroll
    for (int rr = 0; rr < 4; ++rr) {
      const int row = row0 + m * 16 + gr * 4 + rr;
      const float sc = EPI ? rsqip[row] : 0.0f;
#pragma unroll
      for (int nt = 0; nt < 8; ++nt) {
        const int c0 = nt * 16 + la;
        float v = acc[m][nt][rr];
        if (TANH) v = tanhf(v);
        if (EPI) v = fmaf(v, sc, biasp[c0] + resid[(size_t)row * DD + c0]);
        if (WF32) C[(size_t)row * DD + c0] = v;
        if (WBF) Cbp[(size_t)row * DD + c0] = f2bf(v);
      }
    }
  }
}

// ---------------- MFMA concat: y = sum_p hb[p] @ Bp (K=384) ----------------
__global__ __launch_bounds__(512) void mconcat_kernel(
    const unsigned short* __restrict__ h0b, const unsigned short* __restrict__ h1b,
    const unsigned short* __restrict__ h2b, const unsigned short* __restrict__ fwc,
    float* __restrict__ Y) {
  __shared__ unsigned short sF[3 * 16384];  // 96 KB
  const int tid = threadIdx.x;
  {
    const float4* s = (const float4*)fwc;
    float4* d = (float4*)sF;
#pragma unroll
    for (int i = 0; i < 12; ++i) d[tid + i * 512] = s[tid + i * 512];
  }
  __syncthreads();
  const int w = tid >> 6, l = tid & 63, la = l & 15, gr = l >> 4;
  const int row0 = blockIdx.x * 256 + w * 32;
  if (row0 >= NN) return;
  const bool m1ok = (row0 + 32) <= NN;
  const unsigned short* hb[3] = {h0b, h1b, h2b};
  f32x4 zero = {0.f, 0.f, 0.f, 0.f};
  f32x4 acc[2][8];
#pragma unroll
  for (int m = 0; m < 2; ++m)
#pragma unroll
    for (int nt = 0; nt < 8; ++nt) acc[m][nt] = zero;
#pragma unroll
  for (int p = 0; p < 3; ++p) {
    short8_t a[2][4];
#pragma unroll
    for (int m = 0; m < 2; ++m) {
      const int r = row0 + m * 16 + la;
      const bool ok = (m == 0) || m1ok;
      const unsigned short* ap = hb[p] + (size_t)r * DD + gr * 8;
#pragma unroll
      for (int ks = 0; ks < 4; ++ks)
        a[m][ks] = ok ? *(const short8_t*)(ap + ks * 32) : (short8_t)0;
    }
    const unsigned short* sfp = sF + p * 16384;
#pragma unroll
    for (int nt = 0; nt < 8; ++nt) {
#pragma unroll
      for (int ks = 0; ks < 4; ++ks) {
        short8_t b = *(const short8_t*)(sfp + ((nt * 4 + ks) * 64 + l) * 8);
        acc[0][nt] = __builtin_amdgcn_mfma_f32_16x16x32_bf16(a[0][ks], b, acc[0][nt], 0, 0, 0);
        acc[1][nt] = __builtin_amdgcn_mfma_f32_16x16x32_bf16(a[1][ks], b, acc[1][nt], 0, 0, 0);
      }
    }
  }
#pragma unroll
  for (int m = 0; m < 2; ++m) {
    if (m == 1 && !m1ok) break;
#pragma unroll
    for (int rr = 0; rr < 4; ++rr) {
      const int row = row0 + m * 16 + gr * 4 + rr;
#pragma unroll
      for (int nt = 0; nt < 8; ++nt)
        Y[(size_t)row * DD + nt * 16 + la] = acc[m][nt][rr];
    }
  }
}

// ---------------- bf16 CSR gather, batched over gridDim.y = relations --------
// 16 lanes/node, uint4 (16B = 8 bf16) per lane; 4-edge unroll.
// grid.x = NN*16/256 = 3125.
#define ACC8(A, V, C) \
  A[0] = fmaf(bfl((V).x), (C), A[0]); A[1] = fmaf(bfh((V).x), (C), A[1]); \
  A[2] = fmaf(bfl((V).y), (C), A[2]); A[3] = fmaf(bfh((V).y), (C), A[3]); \
  A[4] = fmaf(bfl((V).z), (C), A[4]); A[5] = fmaf(bfh((V).z), (C), A[5]); \
  A[6] = fmaf(bfl((V).w), (C), A[6]); A[7] = fmaf(bfh((V).w), (C), A[7]);

__global__ __launch_bounds__(256) void gatherb_kernel(
    const unsigned short* __restrict__ hb, const int* __restrict__ rowptr,
    const int* __restrict__ col, const float* __restrict__ rsqo,
    unsigned short* __restrict__ ub) {
  const size_t ND = (size_t)NN * DD;
  const int rel = blockIdx.y;
  rowptr += (size_t)rel * (NN + 1);
  col += (size_t)rel * NE;
  rsqo += (size_t)rel * NN;
  ub += (size_t)rel * ND;
  int gid = blockIdx.x * 256 + threadIdx.x;
  int n = gid >> 4;
  int lane = gid & 15;
  int e0 = clampi(rowptr[n], 0, NE);
  int e1 = clampi(rowptr[n + 1], e0, NE);
  const uint4* h4 = (const uint4*)hb;  // row = 16 x uint4 (256B)
  float a[8] = {0, 0, 0, 0, 0, 0, 0, 0}, b[8] = {0, 0, 0, 0, 0, 0, 0, 0};
  float c[8] = {0, 0, 0, 0, 0, 0, 0, 0}, d[8] = {0, 0, 0, 0, 0, 0, 0, 0};
  int e = e0;
  for (; e + 3 < e1; e += 4) {
    int s0 = clampi(col[e], 0, NN - 1), s1 = clampi(col[e + 1], 0, NN - 1);
    int s2 = clampi(col[e + 2], 0, NN - 1), s3 = clampi(col[e + 3], 0, NN - 1);
    float c0 = rsqo[s0], c1 = rsqo[s1], c2 = rsqo[s2], c3 = rsqo[s3];
    uint4 v0 = h4[(size_t)s0 * 16 + lane];
    uint4 v1 = h4[(size_t)s1 * 16 + lane];
    uint4 v2 = h4[(size_t)s2 * 16 + lane];
    uint4 v3 = h4[(size_t)s3 * 16 + lane];
    ACC8(a, v0, c0) ACC8(b, v1, c1) ACC8(c, v2, c2) ACC8(d, v3, c3)
  }
  for (; e < e1; ++e) {
    int s0 = clampi(col[e], 0, NN - 1);
    float c0 = rsqo[s0];
    uint4 v0 = h4[(size_t)s0 * 16 + lane];
    ACC8(a, v0, c0)
  }
#pragma unroll
  for (int j = 0; j < 8; ++j) a[j] += b[j] + c[j] + d[j];
  uint4 o;
  o.x = (unsigned int)f2bf(a[0]) | ((unsigned int)f2bf(a[1]) << 16);
  o.y = (unsigned int)f2bf(a[2]) | ((unsigned int)f2bf(a[3]) << 16);
  o.z = (unsigned int)f2bf(a[4]) | ((unsigned int)f2bf(a[5]) << 16);
  o.w = (unsigned int)f2bf(a[6]) | ((unsigned int)f2bf(a[7]) << 16);
  ((uint4*)ub)[gid] = o;
}

// ---------------- fused scores + softmax + combine (bf16 vals in) ------------
// Vb: 3 contiguous bf16 planes. houtf optional fp32 out; houtb bf16 out.
__global__ __launch_bounds__(256) void scorecombine_kernel(
    const unsigned short* __restrict__ Vb, const float* __restrict__ AW,
    const float* __restrict__ AQ, float* __restrict__ houtf,
    unsigned short* __restrict__ houtb, float* __restrict__ attn_out) {
  const size_t NDv = (size_t)NN * DD;
  __shared__ float sW[DD * DQ];  // 32 KB
  __shared__ __align__(16) unsigned short sRowB[3][16][136];  // 12.75 KB, pad 136
  __shared__ float sS[3][16];
  __shared__ float sQ[DQ];
  const int tid = threadIdx.x;
  const int cg = tid & 15;
  const int rs = tid >> 4;
  for (int i = tid; i < DD * DQ; i += 256) sW[i] = AW[i];
  if (tid < DQ) sQ[tid] = AQ[tid];
  const int srow = tid >> 4, sq = tid & 15;  // staging: row, uint4-slot

  for (int base = blockIdx.x * 16; base < NN; base += gridDim.x * 16) {
    __syncthreads();
#pragma unroll
    for (int r = 0; r < 3; ++r) {
      uint4 v = ((const uint4*)(Vb + r * NDv))[(size_t)base * 16 + tid];
      *(uint4*)&sRowB[r][srow][sq * 8] = v;
    }
    __syncthreads();
    const float4* W4 = (const float4*)sW;
#pragma unroll
    for (int r = 0; r < 3; ++r) {
      float4 acc = make_float4(0, 0, 0, 0);
#pragma unroll 8
      for (int k4 = 0; k4 < 32; ++k4) {
        uint2 rv = *(const uint2*)&sRowB[r][rs][k4 * 4];
        float f0 = bfl(rv.x), f1 = bfh(rv.x), f2 = bfl(rv.y), f3 = bfh(rv.y);
        float4 wv;
        wv = W4[(k4 * 4 + 0) * 16 + cg]; FMA4(acc, f0, wv)
        wv = W4[(k4 * 4 + 1) * 16 + cg]; FMA4(acc, f1, wv)
        wv = W4[(k4 * 4 + 2) * 16 + cg]; FMA4(acc, f2, wv)
        wv = W4[(k4 * 4 + 3) * 16 + cg]; FMA4(acc, f3, wv)
      }
      float4 q = ((const float4*)sQ)[cg];
      float p = tanhf(acc.x) * q.x + tanhf(acc.y) * q.y +
                tanhf(acc.z) * q.z + tanhf(acc.w) * q.w;
#pragma unroll
      for (int off = 8; off; off >>= 1) p += __shfl_xor(p, off);
      if (cg == 0) sS[r][rs] = p;
    }
    __syncthreads();
    float s0 = sS[0][rs], s1 = sS[1][rs], s2 = sS[2][rs];
    float mx = fmaxf(s0, fmaxf(s1, s2));
    float e0 = __expf(s0 - mx), e1 = __expf(s1 - mx), e2 = __expf(s2 - mx);
    float inv = 1.0f / (e0 + e1 + e2);
    float a0 = e0 * inv, a1 = e1 * inv, a2 = e2 * inv;
    // combine: row rs, cols cg*8..cg*8+7
    uint4 p0 = *(const uint4*)&sRowB[0][rs][cg * 8];
    uint4 p1 = *(const uint4*)&sRowB[1][rs][cg * 8];
    uint4 p2 = *(const uint4*)&sRowB[2][rs][cg * 8];
    float o[8];
    o[0] = a0 * bfl(p0.x) + a1 * bfl(p1.x) + a2 * bfl(p2.x);
    o[1] = a0 * bfh(p0.x) + a1 * bfh(p1.x) + a2 * bfh(p2.x);
    o[2] = a0 * bfl(p0.y) + a1 * bfl(p1.y) + a2 * bfl(p2.y);
    o[3] = a0 * bfh(p0.y) + a1 * bfh(p1.y) + a2 * bfh(p2.y);
    o[4] = a0 * bfl(p0.z) + a1 * bfl(p1.z) + a2 * bfl(p2.z);
    o[5] = a0 * bfh(p0.z) + a1 * bfh(p1.z) + a2 * bfh(p2.z);
    o[6] = a0 * bfl(p0.w) + a1 * bfl(p1.w) + a2 * bfl(p2.w);
    o[7] = a0 * bfh(p0.w) + a1 * bfh(p1.w) + a2 * bfh(p2.w);
    uint4 ob;
    ob.x = (unsigned int)f2bf(o[0]) | ((unsigned int)f2bf(o[1]) << 16);
    ob.y = (unsigned int)f2bf(o[2]) | ((unsigned int)f2bf(o[3]) << 16);
    ob.z = (unsigned int)f2bf(o[4]) | ((unsigned int)f2bf(o[5]) << 16);
    ob.w = (unsigned int)f2bf(o[6]) | ((unsigned int)f2bf(o[7]) << 16);
    ((uint4*)houtb)[(size_t)(base + rs) * 16 + cg] = ob;
    if (houtf != nullptr) {
      float4* hf = (float4*)houtf + (size_t)(base + rs) * 32 + cg * 2;
      hf[0] = make_float4(o[0], o[1], o[2], o[3]);
      hf[1] = make_float4(o[4], o[5], o[6], o[7]);
    }
    if (attn_out != nullptr && cg == 0) {
      int n = base + rs;
      attn_out[(size_t)n * 3 + 0] = a0;
      attn_out[(size_t)n * 3 + 1] = a1;
      attn_out[(size_t)n * 3 + 2] = a2;
    }
  }
}

extern "C" void kernel_launch(void* const* d_in, const int* in_sizes, int n_in,
                              void* d_out, int out_size, void* d_ws, size_t ws_size,
                              hipStream_t stream) {
  const float* x        = (const float*)d_in[0];
  const int*   edges    = (const int*)d_in[1];
  const float* feat_w   = (const float*)d_in[2];
  const float* conv_w   = (const float*)d_in[3];
  const float* conv_b   = (const float*)d_in[4];
  const float* attn_w   = (const float*)d_in[5];
  const float* attn_q   = (const float*)d_in[6];
  const float* concat_w = (const float*)d_in[7];
  float* out = (float*)d_out;   // [NN*128 y][NN*3 attn]

  float* ws = (float*)d_ws;
  float* rsqo = ws;                   // [3][NN]
  float* rsqi = rsqo + 3 * NN;        // [3][NN]
  int* flag = (int*)(rsqi + 3 * NN);
  int* cnt = flag + 16;               // [3][NN]; fw overlays after scan
  int* rowptr = cnt + 3 * NN;         // [3][NN+1] (+pad)
  int* col = rowptr + 3 * (NN + 1) + 13;  // [3][NE]
  const size_t ND = (size_t)NN * DD;
  float* P1 = (float*)(col + 3 * (size_t)NE);  // h0 fp32, later t fp32
  float* PA = P1 + ND;   // prologue: hist; then Vb[0..1]
  float* PB = PA + ND;   // prologue: bases; then Vb[2] (first half)
  unsigned short* U0 = (unsigned short*)(PB + ND);  // u bf16 x3; later h2b in U0
  unsigned short* U1 = U0 + ND;
  unsigned short* U2 = U1 + ND;
  unsigned short* B0 = U2 + ND;   // h0b
  unsigned short* B1 = B0 + ND;   // h1b
  unsigned short* B2 = B1 + ND;   // tb
  unsigned short* fw = (unsigned short*)cnt;   // 10 x 16384 ushort
  unsigned int* hist = (unsigned int*)PA;      // 6*NB*NW <= ND
  int* bases = (int*)PB;                       // 3*NB*NN <= ND
  unsigned short* Vb = (unsigned short*)PA;    // 3 bf16 vals planes (contig)

  // prologue: degrees + CSR (no global atomics) + weight fragments
  detect_kernel<<<1, 64, 0, stream>>>(edges, flag);
  hist6_kernel<<<dim3(NB, 6), 512, 0, stream>>>(edges, flag, hist);
  sumhist_kernel<<<dim3(25, 6), 256, 0, stream>>>(hist, cnt, rsqi, rsqo);
  scan_kernel<<<3, 1024, 0, stream>>>(cnt, rowptr);
  prepw_kernel<<<10, 256, 0, stream>>>(conv_w, feat_w, concat_w, fw);  // cnt dead
  bases_kernel<<<dim3(25, 3), 256, 0, stream>>>(hist, rowptr, bases);
  fill2_kernel<<<dim3(NB, 3), 512, 0, stream>>>(edges, flag, bases, col);

  // h0 = tanh(x @ feat_w) -> P1 fp32 + B0 bf16
  mgemm_kernel<1, 1, 0, 1, 1><<<dim3(391, 1), 256, 0, stream>>>(
      x, fw + (size_t)6 * 16384, nullptr, nullptr, nullptr, P1, B0);

  // shared u[r] = A_r^T (h0 * rsqo_r) -> U0..U2 (bf16), batched
  gatherb_kernel<<<dim3(3125, 3), 256, 0, stream>>>(B0, rowptr, col, rsqo, U0);

  // layer l=1 on h0 -> Vb bf16 (batched); h1 -> B1 bf16
  mgemm_kernel<0, 0, 1, 0, 1><<<dim3(391, 3), 256, 0, stream>>>(
      U0, fw + (size_t)3 * 16384, rsqi, conv_b + (size_t)3 * DD, P1, nullptr, Vb);
  scorecombine_kernel<<<512, 256, 0, stream>>>(
      Vb, attn_w + (size_t)DD * DQ, attn_q + DQ, nullptr, B1, nullptr);

  // layer l=0 on h0 (reuses u) -> Vb; t -> P1 fp32 (h0 fp32 dead) + B2 bf16
  mgemm_kernel<0, 0, 1, 0, 1><<<dim3(391, 3), 256, 0, stream>>>(
      U0, fw, rsqi, conv_b, P1, nullptr, Vb);
  scorecombine_kernel<<<512, 256, 0, stream>>>(
      Vb, attn_w, attn_q, P1, B2, nullptr);

  // layer l=1 on t: gathers from B2 -> U; convs (resid = t = P1) -> Vb
  gatherb_kernel<<<dim3(3125, 3), 256, 0, stream>>>(B2, rowptr, col, rsqo, U0);
  mgemm_kernel<0, 0, 1, 0, 1><<<dim3(391, 3), 256, 0, stream>>>(
      U0, fw + (size_t)3 * 16384, rsqi, conv_b + (size_t)3 * DD, P1, nullptr, Vb);
  // h2 -> U0 (bf16, U planes dead), attn -> out+ND
  scorecombine_kernel<<<512, 256, 0, stream>>>(
      Vb, attn_w + (size_t)DD * DQ, attn_q + DQ, nullptr, U0, out + ND);

  // y = [h0|h1|h2] @ CW^T -> out
  mconcat_kernel<<<196, 512, 0, stream>>>(B0, B1, U0, fw + (size_t)7 * 16384, out);
}

// Round 9
// 539.933 us; speedup vs baseline: 24.0979x; 1.2715x over previous
//
#include <hip/hip_runtime.h>

#define NN 50000
#define NE 800000
#define DD 128
#define DQ 64
#define NB 42          // histogram/fill blocks per (relation, array)
#define SL 19048       // edge slice per block: 42*19048 >= NE
#define NW 25000       // packed uint16 words covering NN counters

typedef __attribute__((ext_vector_type(8))) short short8_t;  // 8 bf16 (4 VGPR)
typedef __attribute__((ext_vector_type(4))) float f32x4;     // MFMA acc

__device__ __forceinline__ int clampi(int v, int lo, int hi) {
  return v < lo ? lo : (v > hi ? hi : v);
}
__device__ __forceinline__ unsigned short f2bf(float f) {  // RNE fp32->bf16
  unsigned int u = __float_as_uint(f);
  return (unsigned short)((u + 0x7FFFu + ((u >> 16) & 1u)) >> 16);
}
__device__ __forceinline__ float bfl(unsigned int u) { return __uint_as_float(u << 16); }
__device__ __forceinline__ float bfh(unsigned int u) { return __uint_as_float(u & 0xFFFF0000u); }
__device__ __forceinline__ float b2f(short s) {
  return __uint_as_float(((unsigned int)(unsigned short)s) << 16);
}

// ---------------- prologue ----------------
__global__ void detect_kernel(const int* __restrict__ e, int* __restrict__ flag) {
  if (threadIdx.x == 0 && blockIdx.x == 0) {
    int f = 1;
    for (int j = 0; j < 32; ++j)
      if (e[2 * j + 1] != 0) f = 0;
    *flag = f;
  }
}

__global__ __launch_bounds__(512) void hist6_kernel(
    const int* __restrict__ e, const int* __restrict__ flag,
    unsigned int* __restrict__ hist) {
  __shared__ unsigned int lds[NW];  // 100 KB
  const int b = blockIdx.x;
  const int c = blockIdx.y;
  const int r = c >> 1;
  const int a = c & 1;  // 0: dst, 1: src
  const int tid = threadIdx.x;
  const int f = *flag;
  for (int i = tid; i < NW; i += 512) lds[i] = 0u;
  __syncthreads();
  const long long abase = (long long)r * 2 * NE + (a ? 0 : NE);
  const int beg = b * SL, end = min(beg + SL, NE);
  for (int i = beg + tid; i < end; i += 512) {
    int v = clampi(e[(abase + i) << f], 0, NN - 1);
    atomicAdd(&lds[v >> 1], 1u << ((v & 1) * 16));
  }
  __syncthreads();
  unsigned int* outp = hist + ((size_t)c * NB + b) * NW;
  for (int i = tid; i < NW; i += 512) outp[i] = lds[i];
}

__global__ __launch_bounds__(256) void sumhist_kernel(
    const unsigned int* __restrict__ hist, int* __restrict__ cnt,
    float* __restrict__ rsqi, float* __restrict__ rsqo) {
  const int c = blockIdx.y;
  const int r = c >> 1;
  const int a = c & 1;
  for (int wl = threadIdx.x; wl < 1000; wl += 256) {
    int w = blockIdx.x * 1000 + wl;
    unsigned int lo = 0, hi = 0;
    const unsigned int* hp = hist + (size_t)c * NB * NW + w;
#pragma unroll 7
    for (int b = 0; b < NB; ++b) {
      unsigned int v = hp[(size_t)b * NW];
      lo += v & 0xFFFFu;
      hi += v >> 16;
    }
    int n0 = 2 * w, n1 = 2 * w + 1;
    if (a == 0) {
      cnt[r * NN + n0] = (int)lo;
      cnt[r * NN + n1] = (int)hi;
      rsqi[r * NN + n0] = rsqrtf(fmaxf((float)lo, 1.0f));
      rsqi[r * NN + n1] = rsqrtf(fmaxf((float)hi, 1.0f));
    } else {
      rsqo[r * NN + n0] = rsqrtf(fmaxf((float)lo, 1.0f));
      rsqo[r * NN + n1] = rsqrtf(fmaxf((float)hi, 1.0f));
    }
  }
}

__global__ __launch_bounds__(1024) void scan_kernel(
    const int* __restrict__ cnt, int* __restrict__ rowptr) {
  __shared__ int part[1024];
  const int r = blockIdx.x;
  const int* c = cnt + r * NN;
  int* rp = rowptr + r * (NN + 1);
  const int t = threadIdx.x;
  const int CH = 49;
  int beg = t * CH, end = min(beg + CH, NN);
  int s = 0;
  for (int i = beg; i < end; ++i) s += c[i];
  part[t] = s;
  __syncthreads();
  for (int off = 1; off < 1024; off <<= 1) {
    int v = (t >= off) ? part[t - off] : 0;
    __syncthreads();
    if (t >= off) part[t] += v;
    __syncthreads();
  }
  int excl = (t == 0) ? 0 : part[t - 1];
  for (int i = beg; i < end; ++i) {
    rp[i] = excl;
    excl += c[i];
  }
  if (t == 1023) rp[NN] = part[1023];
}

__global__ __launch_bounds__(256) void bases_kernel(
    const unsigned int* __restrict__ hist, const int* __restrict__ rowptr,
    int* __restrict__ bases) {
  const int r = blockIdx.y;
  for (int wl = threadIdx.x; wl < 1000; wl += 256) {
    int w = blockIdx.x * 1000 + wl;
    int n0 = 2 * w, n1 = 2 * w + 1;
    int run0 = rowptr[r * (NN + 1) + n0];
    int run1 = rowptr[r * (NN + 1) + n1];
    const unsigned int* hp = hist + (size_t)(r * 2) * NB * NW + w;
    int* bp = bases + (size_t)r * NB * NN;
#pragma unroll 7
    for (int b = 0; b < NB; ++b) {
      unsigned int v = hp[(size_t)b * NW];
      bp[(size_t)b * NN + n0] = run0;
      bp[(size_t)b * NN + n1] = run1;
      run0 += (int)(v & 0xFFFFu);
      run1 += (int)(v >> 16);
    }
  }
}

__global__ __launch_bounds__(512) void fill2_kernel(
    const int* __restrict__ e, const int* __restrict__ flag,
    const int* __restrict__ bases, int* __restrict__ col) {
  __shared__ unsigned int cur[NW];  // 100 KB
  const int b = blockIdx.x;
  const int r = blockIdx.y;
  const int tid = threadIdx.x;
  const int f = *flag;
  for (int i = tid; i < NW; i += 512) cur[i] = 0u;
  __syncthreads();
  const long long sbase = (long long)r * 2 * NE;
  const int beg = b * SL, end = min(beg + SL, NE);
  const int* bp = bases + ((size_t)r * NB + b) * NN;
  for (int i = beg + tid; i < end; i += 512) {
    int s = clampi(e[(sbase + i) << f], 0, NN - 1);
    int d = clampi(e[(sbase + NE + i) << f], 0, NN - 1);
    unsigned int packed = atomicAdd(&cur[d >> 1], 1u << ((d & 1) * 16));
    int local = (int)((packed >> ((d & 1) * 16)) & 0xFFFFu);
    int pos = clampi(bp[d] + local, 0, NE - 1);
    col[(size_t)r * NE + pos] = s;
  }
}

// ---------------- weight fragment prep ----------------
// i 0..5: conv_w (128x128); 6: feat_w; 7..9: concat part; 10..11: attn_w[l] (128x64).
__global__ __launch_bounds__(256) void prepw_kernel(
    const float* __restrict__ conv_w, const float* __restrict__ feat_w,
    const float* __restrict__ concat_w, const float* __restrict__ attn_w,
    unsigned short* __restrict__ fw) {
  const int i = blockIdx.x;
  if (i < 10) {
    unsigned short* dst = fw + (size_t)i * 16384;
    for (int e = threadIdx.x; e < 2048; e += 256) {
      int nt = e >> 8, ks = (e >> 6) & 3, lane = e & 63;
      int n = (lane & 15) + nt * 16;
      int kb = (lane >> 4) * 8 + ks * 32;
      unsigned int w[4];
#pragma unroll
      for (int jj = 0; jj < 4; ++jj) {
        int k0 = kb + 2 * jj, k1 = k0 + 1;
        float f0, f1;
        if (i < 6) {
          f0 = conv_w[(size_t)i * 16384 + (size_t)k0 * DD + n];
          f1 = conv_w[(size_t)i * 16384 + (size_t)k1 * DD + n];
        } else if (i == 6) {
          f0 = feat_w[(size_t)k0 * DD + n];
          f1 = feat_w[(size_t)k1 * DD + n];
        } else {
          int p = i - 7;
          f0 = concat_w[(size_t)n * 384 + p * DD + k0];
          f1 = concat_w[(size_t)n * 384 + p * DD + k1];
        }
        w[jj] = (unsigned int)f2bf(f0) | ((unsigned int)f2bf(f1) << 16);
      }
      ((uint4*)dst)[e] = make_uint4(w[0], w[1], w[2], w[3]);
    }
  } else {
    const int l = i - 10;
    unsigned short* dst = fw + (size_t)10 * 16384 + (size_t)l * 8192;
    for (int e = threadIdx.x; e < 1024; e += 256) {
      int nt = e >> 8, ks = (e >> 6) & 3, lane = e & 63;  // nt 0..3 (64 cols)
      int n = (lane & 15) + nt * 16;
      int kb = (lane >> 4) * 8 + ks * 32;
      unsigned int w[4];
#pragma unroll
      for (int jj = 0; jj < 4; ++jj) {
        int k0 = kb + 2 * jj, k1 = k0 + 1;
        float f0 = attn_w[((size_t)l * DD + k0) * DQ + n];
        float f1 = attn_w[((size_t)l * DD + k1) * DQ + n];
        w[jj] = (unsigned int)f2bf(f0) | ((unsigned int)f2bf(f1) << 16);
      }
      ((uint4*)dst)[e] = make_uint4(w[0], w[1], w[2], w[3]);
    }
  }
}

// ---------------- MFMA GEMM: Cb = bf16([tanh](A @ W) [*rsqi + bias + residb]) --
// Batched over gridDim.y = relations (fw, rsqi, bias, Cb rel-indexed; residb shared).
template <int AFP32, int TANH, int EPI>
__global__ __launch_bounds__(256) void mgemm_kernel(
    const void* __restrict__ Ap, const unsigned short* __restrict__ fw,
    const float* __restrict__ rsqi, const float* __restrict__ bias,
    const unsigned short* __restrict__ residb, unsigned short* __restrict__ Cb) {
  const size_t ND = (size_t)NN * DD;
  const int rel = blockIdx.y;
  const unsigned short* fwp = fw + (size_t)rel * 16384;
  const float* rsqip = EPI ? rsqi + (size_t)rel * NN : nullptr;
  const float* biasp = EPI ? bias + (size_t)rel * DD : nullptr;
  unsigned short* Cbp = Cb + (size_t)rel * ND;
  __shared__ unsigned short sF[16384];  // 32 KB
  const int tid = threadIdx.x;
  {
    const float4* s = (const float4*)fwp;
    float4* d = (float4*)sF;
#pragma unroll
    for (int i = 0; i < 8; ++i) d[tid + i * 256] = s[tid + i * 256];
  }
  __syncthreads();
  const int w = tid >> 6, l = tid & 63, la = l & 15, gr = l >> 4;
  const int row0 = blockIdx.x * 128 + w * 32;
  if (row0 >= NN) return;  // after barrier: safe
  const bool m1ok = (row0 + 32) <= NN;  // NN % 16 == 0
  short8_t a[2][4];
#pragma unroll
  for (int m = 0; m < 2; ++m) {
    const int r = row0 + m * 16 + la;
    const bool ok = (m == 0) || m1ok;
    if (AFP32) {
      const float* ap = (const float*)Ap + (size_t)r * DD + gr * 8;
#pragma unroll
      for (int ks = 0; ks < 4; ++ks) {
        short8_t v = (short8_t)0;
        if (ok) {
          float4 x0 = *(const float4*)(ap + ks * 32);
          float4 x1 = *(const float4*)(ap + ks * 32 + 4);
          v[0] = (short)f2bf(x0.x); v[1] = (short)f2bf(x0.y);
          v[2] = (short)f2bf(x0.z); v[3] = (short)f2bf(x0.w);
          v[4] = (short)f2bf(x1.x); v[5] = (short)f2bf(x1.y);
          v[6] = (short)f2bf(x1.z); v[7] = (short)f2bf(x1.w);
        }
        a[m][ks] = v;
      }
    } else {
      const unsigned short* ap =
          (const unsigned short*)Ap + (size_t)rel * ND + (size_t)r * DD + gr * 8;
#pragma unroll
      for (int ks = 0; ks < 4; ++ks)
        a[m][ks] = ok ? *(const short8_t*)(ap + ks * 32) : (short8_t)0;
    }
  }
  f32x4 zero = {0.f, 0.f, 0.f, 0.f};
  f32x4 acc[2][8];
#pragma unroll
  for (int m = 0; m < 2; ++m)
#pragma unroll
    for (int nt = 0; nt < 8; ++nt) acc[m][nt] = zero;
#pragma unroll
  for (int nt = 0; nt < 8; ++nt) {
#pragma unroll
    for (int ks = 0; ks < 4; ++ks) {
      short8_t b = *(const short8_t*)(sF + ((nt * 4 + ks) * 64 + l) * 8);
      acc[0][nt] = __builtin_amdgcn_mfma_f32_16x16x32_bf16(a[0][ks], b, acc[0][nt], 0, 0, 0);
      acc[1][nt] = __builtin_amdgcn_mfma_f32_16x16x32_bf16(a[1][ks], b, acc[1][nt], 0, 0, 0);
    }
  }
#pragma unroll
  for (int m = 0; m < 2; ++m) {
    if (m == 1 && !m1ok) break;
#pragma unroll
    for (int rr = 0; rr < 4; ++rr) {
      const int row = row0 + m * 16 + gr * 4 + rr;
      const float sc = EPI ? rsqip[row] : 0.0f;
#pragma unroll
      for (int nt = 0; nt < 8; ++nt) {
        const int c0 = nt * 16 + la;
        float v = acc[m][nt][rr];
        if (TANH) v = tanhf(v);
        if (EPI) {
          float rv = __uint_as_float((unsigned int)residb[(size_t)row * DD + c0] << 16);
          v = fmaf(v, sc, biasp[c0] + rv);
        }
        Cbp[(size_t)row * DD + c0] = f2bf(v);
      }
    }
  }
}

// ---------------- MFMA concat: y = sum_p hb[p] @ Bp (K=384) ----------------
__global__ __launch_bounds__(512) void mconcat_kernel(
    const unsigned short* __restrict__ h0b, const unsigned short* __restrict__ h1b,
    const unsigned short* __restrict__ h2b, const unsigned short* __restrict__ fwc,
    float* __restrict__ Y) {
  __shared__ unsigned short sF[3 * 16384];  // 96 KB
  const int tid = threadIdx.x;
  {
    const float4* s = (const float4*)fwc;
    float4* d = (float4*)sF;
#pragma unroll
    for (int i = 0; i < 12; ++i) d[tid + i * 512] = s[tid + i * 512];
  }
  __syncthreads();
  const int w = tid >> 6, l = tid & 63, la = l & 15, gr = l >> 4;
  const int row0 = blockIdx.x * 256 + w * 32;
  if (row0 >= NN) return;
  const bool m1ok = (row0 + 32) <= NN;
  const unsigned short* hb[3] = {h0b, h1b, h2b};
  f32x4 zero = {0.f, 0.f, 0.f, 0.f};
  f32x4 acc[2][8];
#pragma unroll
  for (int m = 0; m < 2; ++m)
#pragma unroll
    for (int nt = 0; nt < 8; ++nt) acc[m][nt] = zero;
#pragma unroll
  for (int p = 0; p < 3; ++p) {
    short8_t a[2][4];
#pragma unroll
    for (int m = 0; m < 2; ++m) {
      const int r = row0 + m * 16 + la;
      const bool ok = (m == 0) || m1ok;
      const unsigned short* ap = hb[p] + (size_t)r * DD + gr * 8;
#pragma unroll
      for (int ks = 0; ks < 4; ++ks)
        a[m][ks] = ok ? *(const short8_t*)(ap + ks * 32) : (short8_t)0;
    }
    const unsigned short* sfp = sF + p * 16384;
#pragma unroll
    for (int nt = 0; nt < 8; ++nt) {
#pragma unroll
      for (int ks = 0; ks < 4; ++ks) {
        short8_t b = *(const short8_t*)(sfp + ((nt * 4 + ks) * 64 + l) * 8);
        acc[0][nt] = __builtin_amdgcn_mfma_f32_16x16x32_bf16(a[0][ks], b, acc[0][nt], 0, 0, 0);
        acc[1][nt] = __builtin_amdgcn_mfma_f32_16x16x32_bf16(a[1][ks], b, acc[1][nt], 0, 0, 0);
      }
    }
  }
#pragma unroll
  for (int m = 0; m < 2; ++m) {
    if (m == 1 && !m1ok) break;
#pragma unroll
    for (int rr = 0; rr < 4; ++rr) {
      const int row = row0 + m * 16 + gr * 4 + rr;
#pragma unroll
      for (int nt = 0; nt < 8; ++nt)
        Y[(size_t)row * DD + nt * 16 + la] = acc[m][nt][rr];
    }
  }
}

// ---------------- bf16 CSR gather, batched over gridDim.y = relations --------
#define ACC8(A, V, C) \
  A[0] = fmaf(bfl((V).x), (C), A[0]); A[1] = fmaf(bfh((V).x), (C), A[1]); \
  A[2] = fmaf(bfl((V).y), (C), A[2]); A[3] = fmaf(bfh((V).y), (C), A[3]); \
  A[4] = fmaf(bfl((V).z), (C), A[4]); A[5] = fmaf(bfh((V).z), (C), A[5]); \
  A[6] = fmaf(bfl((V).w), (C), A[6]); A[7] = fmaf(bfh((V).w), (C), A[7]);

__global__ __launch_bounds__(256) void gatherb_kernel(
    const unsigned short* __restrict__ hb, const int* __restrict__ rowptr,
    const int* __restrict__ col, const float* __restrict__ rsqo,
    unsigned short* __restrict__ ub) {
  const size_t ND = (size_t)NN * DD;
  const int rel = blockIdx.y;
  rowptr += (size_t)rel * (NN + 1);
  col += (size_t)rel * NE;
  rsqo += (size_t)rel * NN;
  ub += (size_t)rel * ND;
  int gid = blockIdx.x * 256 + threadIdx.x;
  int n = gid >> 4;
  int lane = gid & 15;
  int e0 = clampi(rowptr[n], 0, NE);
  int e1 = clampi(rowptr[n + 1], e0, NE);
  const uint4* h4 = (const uint4*)hb;  // row = 16 x uint4 (256B)
  float a[8] = {0, 0, 0, 0, 0, 0, 0, 0}, b[8] = {0, 0, 0, 0, 0, 0, 0, 0};
  float c[8] = {0, 0, 0, 0, 0, 0, 0, 0}, d[8] = {0, 0, 0, 0, 0, 0, 0, 0};
  int e = e0;
  for (; e + 3 < e1; e += 4) {
    int s0 = clampi(col[e], 0, NN - 1), s1 = clampi(col[e + 1], 0, NN - 1);
    int s2 = clampi(col[e + 2], 0, NN - 1), s3 = clampi(col[e + 3], 0, NN - 1);
    float c0 = rsqo[s0], c1 = rsqo[s1], c2 = rsqo[s2], c3 = rsqo[s3];
    uint4 v0 = h4[(size_t)s0 * 16 + lane];
    uint4 v1 = h4[(size_t)s1 * 16 + lane];
    uint4 v2 = h4[(size_t)s2 * 16 + lane];
    uint4 v3 = h4[(size_t)s3 * 16 + lane];
    ACC8(a, v0, c0) ACC8(b, v1, c1) ACC8(c, v2, c2) ACC8(d, v3, c3)
  }
  for (; e < e1; ++e) {
    int s0 = clampi(col[e], 0, NN - 1);
    float c0 = rsqo[s0];
    uint4 v0 = h4[(size_t)s0 * 16 + lane];
    ACC8(a, v0, c0)
  }
#pragma unroll
  for (int j = 0; j < 8; ++j) a[j] += b[j] + c[j] + d[j];
  uint4 o;
  o.x = (unsigned int)f2bf(a[0]) | ((unsigned int)f2bf(a[1]) << 16);
  o.y = (unsigned int)f2bf(a[2]) | ((unsigned int)f2bf(a[3]) << 16);
  o.z = (unsigned int)f2bf(a[4]) | ((unsigned int)f2bf(a[5]) << 16);
  o.w = (unsigned int)f2bf(a[6]) | ((unsigned int)f2bf(a[7]) << 16);
  ((uint4*)ub)[gid] = o;
}

// ------- fused MFMA scores + softmax + combine (Vb read once, in registers) ---
// Per wave: 32 rows. A-frag lane la holds row row0+m*16+la (cols gr*8+ks*32..+7).
// Scores via MFMA vs attn_w fragments + tanh/AQ epilogue + width-16 reduce;
// realigned through LDS; softmax; combine A-registers; bf16 store.
__global__ __launch_bounds__(256) void mscomb_kernel(
    const unsigned short* __restrict__ Vb, const unsigned short* __restrict__ fa,
    const float* __restrict__ AQ, unsigned short* __restrict__ houtb,
    float* __restrict__ attn_out) {
  const size_t ND = (size_t)NN * DD;
  __shared__ unsigned short sF[8192];  // 16 KB
  __shared__ float sS[4][3][32];
  const int tid = threadIdx.x;
  {
    const float4* s = (const float4*)fa;
    float4* d = (float4*)sF;
#pragma unroll
    for (int i = 0; i < 4; ++i) d[tid + i * 256] = s[tid + i * 256];
  }
  const int w = tid >> 6, l = tid & 63, la = l & 15, gr = l >> 4;
  int row0 = blockIdx.x * 128 + w * 32;
  if (row0 + 32 > NN) row0 = NN - 32;  // clamp (dup rows idempotent), no return
  short8_t a[3][2][4];
#pragma unroll
  for (int r3 = 0; r3 < 3; ++r3) {
#pragma unroll
    for (int m = 0; m < 2; ++m) {
      const unsigned short* rp =
          Vb + (size_t)r3 * ND + (size_t)(row0 + m * 16 + la) * DD + gr * 8;
#pragma unroll
      for (int ks = 0; ks < 4; ++ks)
        a[r3][m][ks] = *(const short8_t*)(rp + ks * 32);
    }
  }
  __syncthreads();  // sF ready
  float q[4];
#pragma unroll
  for (int nt = 0; nt < 4; ++nt) q[nt] = AQ[la + nt * 16];
#pragma unroll
  for (int r3 = 0; r3 < 3; ++r3) {
    f32x4 zero = {0.f, 0.f, 0.f, 0.f};
    f32x4 acc[2][4];
#pragma unroll
    for (int m = 0; m < 2; ++m)
#pragma unroll
      for (int nt = 0; nt < 4; ++nt) acc[m][nt] = zero;
#pragma unroll
    for (int nt = 0; nt < 4; ++nt) {
#pragma unroll
      for (int ks = 0; ks < 4; ++ks) {
        short8_t b = *(const short8_t*)(sF + ((nt * 4 + ks) * 64 + l) * 8);
        acc[0][nt] = __builtin_amdgcn_mfma_f32_16x16x32_bf16(a[r3][0][ks], b, acc[0][nt], 0, 0, 0);
        acc[1][nt] = __builtin_amdgcn_mfma_f32_16x16x32_bf16(a[r3][1][ks], b, acc[1][nt], 0, 0, 0);
      }
    }
#pragma unroll
    for (int m = 0; m < 2; ++m) {
#pragma unroll
      for (int rr = 0; rr < 4; ++rr) {
        float p = tanhf(acc[m][0][rr]) * q[0] + tanhf(acc[m][1][rr]) * q[1] +
                  tanhf(acc[m][2][rr]) * q[2] + tanhf(acc[m][3][rr]) * q[3];
#pragma unroll
        for (int off = 1; off < 16; off <<= 1) p += __shfl_xor(p, off, 16);
        if (la == 0) sS[w][r3][m * 16 + gr * 4 + rr] = p;
      }
    }
  }
  __syncthreads();
#pragma unroll
  for (int m = 0; m < 2; ++m) {
    const int row = row0 + m * 16 + la;
    float s0 = sS[w][0][m * 16 + la];
    float s1 = sS[w][1][m * 16 + la];
    float s2 = sS[w][2][m * 16 + la];
    float mx = fmaxf(s0, fmaxf(s1, s2));
    float e0 = __expf(s0 - mx), e1 = __expf(s1 - mx), e2 = __expf(s2 - mx);
    float inv = 1.0f / (e0 + e1 + e2);
    float a0 = e0 * inv, a1 = e1 * inv, a2 = e2 * inv;
#pragma unroll
    for (int ks = 0; ks < 4; ++ks) {
      unsigned int ow[4];
#pragma unroll
      for (int jj = 0; jj < 4; ++jj) {
        float v0 = a0 * b2f(a[0][m][ks][2 * jj]) + a1 * b2f(a[1][m][ks][2 * jj]) +
                   a2 * b2f(a[2][m][ks][2 * jj]);
        float v1 = a0 * b2f(a[0][m][ks][2 * jj + 1]) + a1 * b2f(a[1][m][ks][2 * jj + 1]) +
                   a2 * b2f(a[2][m][ks][2 * jj + 1]);
        ow[jj] = (unsigned int)f2bf(v0) | ((unsigned int)f2bf(v1) << 16);
      }
      *(uint4*)(houtb + (size_t)row * DD + gr * 8 + ks * 32) =
          make_uint4(ow[0], ow[1], ow[2], ow[3]);
    }
    if (attn_out != nullptr) {
      attn_out[(size_t)row * 3 + 0] = a0;
      attn_out[(size_t)row * 3 + 1] = a1;
      attn_out[(size_t)row * 3 + 2] = a2;
    }
  }
}

extern "C" void kernel_launch(void* const* d_in, const int* in_sizes, int n_in,
                              void* d_out, int out_size, void* d_ws, size_t ws_size,
                              hipStream_t stream) {
  const float* x        = (const float*)d_in[0];
  const int*   edges    = (const int*)d_in[1];
  const float* feat_w   = (const float*)d_in[2];
  const float* conv_w   = (const float*)d_in[3];
  const float* conv_b   = (const float*)d_in[4];
  const float* attn_w   = (const float*)d_in[5];
  const float* attn_q   = (const float*)d_in[6];
  const float* concat_w = (const float*)d_in[7];
  float* out = (float*)d_out;   // [NN*128 y][NN*3 attn]

  float* ws = (float*)d_ws;
  float* rsqo = ws;                   // [3][NN]
  float* rsqi = rsqo + 3 * NN;        // [3][NN]
  int* flag = (int*)(rsqi + 3 * NN);
  int* cnt = flag + 16;               // [3][NN]; fw overlays after scan
  int* rowptr = cnt + 3 * NN;         // [3][NN+1] (+pad)
  int* col = rowptr + 3 * (NN + 1) + 13;  // [3][NE]
  const size_t ND = (size_t)NN * DD;
  float* P1 = (float*)(col + 3 * (size_t)NE);  // spare plane (unused post-R8)
  float* PA = P1 + ND;   // prologue: hist; then Vb planes 0..1
  float* PB = PA + ND;   // prologue: bases; then Vb plane 2 (first half)
  unsigned short* U0 = (unsigned short*)(PB + ND);  // u bf16 x3; later h2b
  unsigned short* U1 = U0 + ND;
  unsigned short* U2 = U1 + ND;
  unsigned short* B0 = U2 + ND;   // h0b
  unsigned short* B1 = B0 + ND;   // h1b
  unsigned short* B2 = B1 + ND;   // tb
  unsigned short* fw = (unsigned short*)cnt;   // 10x16384 + 2x8192 ushort
  unsigned int* hist = (unsigned int*)PA;      // 6*NB*NW <= ND
  int* bases = (int*)PB;                       // 3*NB*NN <= ND
  unsigned short* Vb = (unsigned short*)PA;    // 3 bf16 vals planes (contig)
  unsigned short* fa0 = fw + (size_t)10 * 16384;
  unsigned short* fa1 = fa0 + 8192;

  // prologue: degrees + CSR (no global atomics) + weight fragments
  detect_kernel<<<1, 64, 0, stream>>>(edges, flag);
  hist6_kernel<<<dim3(NB, 6), 512, 0, stream>>>(edges, flag, hist);
  sumhist_kernel<<<dim3(25, 6), 256, 0, stream>>>(hist, cnt, rsqi, rsqo);
  scan_kernel<<<3, 1024, 0, stream>>>(cnt, rowptr);
  prepw_kernel<<<12, 256, 0, stream>>>(conv_w, feat_w, concat_w, attn_w, fw);
  bases_kernel<<<dim3(25, 3), 256, 0, stream>>>(hist, rowptr, bases);
  fill2_kernel<<<dim3(NB, 3), 512, 0, stream>>>(edges, flag, bases, col);

  // h0 = tanh(x @ feat_w) -> B0 bf16
  mgemm_kernel<1, 1, 0><<<dim3(391, 1), 256, 0, stream>>>(
      x, fw + (size_t)6 * 16384, nullptr, nullptr, nullptr, B0);

  // shared u[r] = A_r^T (h0 * rsqo_r) -> U0..U2, batched
  gatherb_kernel<<<dim3(3125, 3), 256, 0, stream>>>(B0, rowptr, col, rsqo, U0);

  // layer l=1 on h0 -> Vb; h1 -> B1
  mgemm_kernel<0, 0, 1><<<dim3(391, 3), 256, 0, stream>>>(
      U0, fw + (size_t)3 * 16384, rsqi, conv_b + (size_t)3 * DD, B0, Vb);
  mscomb_kernel<<<391, 256, 0, stream>>>(Vb, fa1, attn_q + DQ, B1, nullptr);

  // layer l=0 on h0 (reuses u) -> Vb; t -> B2
  mgemm_kernel<0, 0, 1><<<dim3(391, 3), 256, 0, stream>>>(
      U0, fw, rsqi, conv_b, B0, Vb);
  mscomb_kernel<<<391, 256, 0, stream>>>(Vb, fa0, attn_q, B2, nullptr);

  // layer l=1 on t: gathers from B2 -> U; convs (resid = B2) -> Vb
  gatherb_kernel<<<dim3(3125, 3), 256, 0, stream>>>(B2, rowptr, col, rsqo, U0);
  mgemm_kernel<0, 0, 1><<<dim3(391, 3), 256, 0, stream>>>(
      U0, fw + (size_t)3 * 16384, rsqi, conv_b + (size_t)3 * DD, B2, Vb);
  // h2 -> U0 (bf16), attn -> out+ND
  mscomb_kernel<<<391, 256, 0, stream>>>(Vb, fa1, attn_q + DQ, U0, out + ND);

  // y = [h0|h1|h2] @ CW^T -> out
  mconcat_kernel<<<196, 512, 0, stream>>>(B0, B1, U0, fw + (size_t)7 * 16384, out);
}

// Round 10
// 465.083 us; speedup vs baseline: 27.9761x; 1.1609x over previous
//
#include <hip/hip_runtime.h>

#define NN 50000
#define NE 800000
#define DD 128
#define DQ 64
#define NB 42          // histogram/fill blocks per (relation, array)
#define SL 19048       // edge slice per block: 42*19048 >= NE
#define NW 25000       // packed uint16 words covering NN counters

typedef __attribute__((ext_vector_type(8))) short short8_t;  // 8 bf16 (4 VGPR)
typedef __attribute__((ext_vector_type(4))) float f32x4;     // MFMA acc

__device__ __forceinline__ int clampi(int v, int lo, int hi) {
  return v < lo ? lo : (v > hi ? hi : v);
}
__device__ __forceinline__ unsigned short f2bf(float f) {  // RNE fp32->bf16
  unsigned int u = __float_as_uint(f);
  return (unsigned short)((u + 0x7FFFu + ((u >> 16) & 1u)) >> 16);
}
__device__ __forceinline__ float bfl(unsigned int u) { return __uint_as_float(u << 16); }
__device__ __forceinline__ float bfh(unsigned int u) { return __uint_as_float(u & 0xFFFF0000u); }
__device__ __forceinline__ float b2f(short s) {
  return __uint_as_float(((unsigned int)(unsigned short)s) << 16);
}

// ---------------- prologue ----------------
__global__ void detect_kernel(const int* __restrict__ e, int* __restrict__ flag) {
  if (threadIdx.x == 0 && blockIdx.x == 0) {
    int f = 1;
    for (int j = 0; j < 32; ++j)
      if (e[2 * j + 1] != 0) f = 0;
    *flag = f;
  }
}

__global__ __launch_bounds__(512) void hist6_kernel(
    const int* __restrict__ e, const int* __restrict__ flag,
    unsigned int* __restrict__ hist) {
  __shared__ unsigned int lds[NW];  // 100 KB
  const int b = blockIdx.x;
  const int c = blockIdx.y;
  const int r = c >> 1;
  const int a = c & 1;  // 0: dst, 1: src
  const int tid = threadIdx.x;
  const int f = *flag;
  for (int i = tid; i < NW; i += 512) lds[i] = 0u;
  __syncthreads();
  const long long abase = (long long)r * 2 * NE + (a ? 0 : NE);
  const int beg = b * SL, end = min(beg + SL, NE);
  for (int i = beg + tid; i < end; i += 512) {
    int v = clampi(e[(abase + i) << f], 0, NN - 1);
    atomicAdd(&lds[v >> 1], 1u << ((v & 1) * 16));
  }
  __syncthreads();
  unsigned int* outp = hist + ((size_t)c * NB + b) * NW;
  for (int i = tid; i < NW; i += 512) outp[i] = lds[i];
}

__global__ __launch_bounds__(256) void sumhist_kernel(
    const unsigned int* __restrict__ hist, int* __restrict__ cnt,
    float* __restrict__ rsqi, float* __restrict__ rsqo) {
  const int c = blockIdx.y;
  const int r = c >> 1;
  const int a = c & 1;
  for (int wl = threadIdx.x; wl < 1000; wl += 256) {
    int w = blockIdx.x * 1000 + wl;
    unsigned int lo = 0, hi = 0;
    const unsigned int* hp = hist + (size_t)c * NB * NW + w;
#pragma unroll 7
    for (int b = 0; b < NB; ++b) {
      unsigned int v = hp[(size_t)b * NW];
      lo += v & 0xFFFFu;
      hi += v >> 16;
    }
    int n0 = 2 * w, n1 = 2 * w + 1;
    if (a == 0) {
      cnt[r * NN + n0] = (int)lo;
      cnt[r * NN + n1] = (int)hi;
      rsqi[r * NN + n0] = rsqrtf(fmaxf((float)lo, 1.0f));
      rsqi[r * NN + n1] = rsqrtf(fmaxf((float)hi, 1.0f));
    } else {
      rsqo[r * NN + n0] = rsqrtf(fmaxf((float)lo, 1.0f));
      rsqo[r * NN + n1] = rsqrtf(fmaxf((float)hi, 1.0f));
    }
  }
}

// -------- hierarchical scan: p1 per-block local prefix, p2 block offsets, p3 add --
__global__ __launch_bounds__(256) void scanp1_kernel(
    const int* __restrict__ cnt, int* __restrict__ rowptr, int* __restrict__ btot) {
  __shared__ int part[256];
  const int r = blockIdx.y;
  const int b = blockIdx.x;   // 25 blocks x 2000 nodes
  const int t = threadIdx.x;
  const int base = b * 2000;
  const int beg = t * 8;
  int v[8];
  int s = 0;
  if (beg < 2000) {
#pragma unroll
    for (int j = 0; j < 8; ++j) {
      v[j] = cnt[r * NN + base + beg + j];
      s += v[j];
    }
  }
  part[t] = s;
  __syncthreads();
  for (int off = 1; off < 256; off <<= 1) {
    int x = (t >= off) ? part[t - off] : 0;
    __syncthreads();
    part[t] += x;
    __syncthreads();
  }
  if (beg < 2000) {
    int excl = part[t] - s;
#pragma unroll
    for (int j = 0; j < 8; ++j) {
      rowptr[r * (NN + 1) + base + beg + j] = excl;
      excl += v[j];
    }
  }
  if (t == 255) btot[r * 25 + b] = part[255];
}

__global__ __launch_bounds__(64) void scanp2_kernel(
    const int* __restrict__ btot, int* __restrict__ boff, int* __restrict__ rowptr) {
  if (threadIdx.x == 0) {
    for (int r = 0; r < 3; ++r) {
      int run = 0;
      for (int b = 0; b < 25; ++b) {
        boff[r * 25 + b] = run;
        run += btot[r * 25 + b];
      }
      rowptr[r * (NN + 1) + NN] = run;
    }
  }
}

__global__ __launch_bounds__(256) void scanp3_kernel(
    const int* __restrict__ boff, int* __restrict__ rowptr) {
  const int r = blockIdx.y, b = blockIdx.x, t = threadIdx.x;
  const int off = boff[r * 25 + b];
  const int beg = t * 8;
  if (beg < 2000) {
    int* rp = rowptr + r * (NN + 1) + b * 2000 + beg;
#pragma unroll
    for (int j = 0; j < 8; ++j) rp[j] += off;
  }
}

__global__ __launch_bounds__(256) void bases_kernel(
    const unsigned int* __restrict__ hist, const int* __restrict__ rowptr,
    int* __restrict__ bases) {
  const int r = blockIdx.y;
  for (int wl = threadIdx.x; wl < 1000; wl += 256) {
    int w = blockIdx.x * 1000 + wl;
    int n0 = 2 * w, n1 = 2 * w + 1;
    int run0 = rowptr[r * (NN + 1) + n0];
    int run1 = rowptr[r * (NN + 1) + n1];
    const unsigned int* hp = hist + (size_t)(r * 2) * NB * NW + w;
    int* bp = bases + (size_t)r * NB * NN;
#pragma unroll 7
    for (int b = 0; b < NB; ++b) {
      unsigned int v = hp[(size_t)b * NW];
      bp[(size_t)b * NN + n0] = run0;
      bp[(size_t)b * NN + n1] = run1;
      run0 += (int)(v & 0xFFFFu);
      run1 += (int)(v >> 16);
    }
  }
}

__global__ __launch_bounds__(512) void fill2_kernel(
    const int* __restrict__ e, const int* __restrict__ flag,
    const int* __restrict__ bases, int* __restrict__ col) {
  __shared__ unsigned int cur[NW];  // 100 KB
  const int b = blockIdx.x;
  const int r = blockIdx.y;
  const int tid = threadIdx.x;
  const int f = *flag;
  for (int i = tid; i < NW; i += 512) cur[i] = 0u;
  __syncthreads();
  const long long sbase = (long long)r * 2 * NE;
  const int beg = b * SL, end = min(beg + SL, NE);
  const int* bp = bases + ((size_t)r * NB + b) * NN;
  for (int i = beg + tid; i < end; i += 512) {
    int s = clampi(e[(sbase + i) << f], 0, NN - 1);
    int d = clampi(e[(sbase + NE + i) << f], 0, NN - 1);
    unsigned int packed = atomicAdd(&cur[d >> 1], 1u << ((d & 1) * 16));
    int local = (int)((packed >> ((d & 1) * 16)) & 0xFFFFu);
    int pos = clampi(bp[d] + local, 0, NE - 1);
    col[(size_t)r * NE + pos] = s;
  }
}

// ---------------- weight fragment prep ----------------
// i 0..5: conv_w (128x128); 6: feat_w; 7..9: concat part; 10..11: attn_w[l] (128x64).
__global__ __launch_bounds__(256) void prepw_kernel(
    const float* __restrict__ conv_w, const float* __restrict__ feat_w,
    const float* __restrict__ concat_w, const float* __restrict__ attn_w,
    unsigned short* __restrict__ fw) {
  const int i = blockIdx.x;
  if (i < 10) {
    unsigned short* dst = fw + (size_t)i * 16384;
    for (int e = threadIdx.x; e < 2048; e += 256) {
      int nt = e >> 8, ks = (e >> 6) & 3, lane = e & 63;
      int n = (lane & 15) + nt * 16;
      int kb = (lane >> 4) * 8 + ks * 32;
      unsigned int w[4];
#pragma unroll
      for (int jj = 0; jj < 4; ++jj) {
        int k0 = kb + 2 * jj, k1 = k0 + 1;
        float f0, f1;
        if (i < 6) {
          f0 = conv_w[(size_t)i * 16384 + (size_t)k0 * DD + n];
          f1 = conv_w[(size_t)i * 16384 + (size_t)k1 * DD + n];
        } else if (i == 6) {
          f0 = feat_w[(size_t)k0 * DD + n];
          f1 = feat_w[(size_t)k1 * DD + n];
        } else {
          int p = i - 7;
          f0 = concat_w[(size_t)n * 384 + p * DD + k0];
          f1 = concat_w[(size_t)n * 384 + p * DD + k1];
        }
        w[jj] = (unsigned int)f2bf(f0) | ((unsigned int)f2bf(f1) << 16);
      }
      ((uint4*)dst)[e] = make_uint4(w[0], w[1], w[2], w[3]);
    }
  } else {
    const int l = i - 10;
    unsigned short* dst = fw + (size_t)10 * 16384 + (size_t)l * 8192;
    for (int e = threadIdx.x; e < 1024; e += 256) {
      int nt = e >> 8, ks = (e >> 6) & 3, lane = e & 63;  // nt 0..3
      int n = (lane & 15) + nt * 16;
      int kb = (lane >> 4) * 8 + ks * 32;
      unsigned int w[4];
#pragma unroll
      for (int jj = 0; jj < 4; ++jj) {
        int k0 = kb + 2 * jj, k1 = k0 + 1;
        float f0 = attn_w[((size_t)l * DD + k0) * DQ + n];
        float f1 = attn_w[((size_t)l * DD + k1) * DQ + n];
        w[jj] = (unsigned int)f2bf(f0) | ((unsigned int)f2bf(f1) << 16);
      }
      ((uint4*)dst)[e] = make_uint4(w[0], w[1], w[2], w[3]);
    }
  }
}

// ---------------- MFMA GEMM: Cb = bf16([tanh](A @ W) [*rsqi + bias + residb]) --
// SIX=1: gridDim.y=6 covers both h0-fed layers (weights/bias idx (rel+3)%6,
// A plane rel%3, out plane rel). SIX=0: gridDim.y = relations (all idx rel).
template <int AFP32, int TANH, int EPI, int SIX>
__global__ __launch_bounds__(256) void mgemm_kernel(
    const void* __restrict__ Ap, const unsigned short* __restrict__ fw,
    const float* __restrict__ rsqi, const float* __restrict__ bias,
    const unsigned short* __restrict__ residb, unsigned short* __restrict__ Cb) {
  const size_t ND = (size_t)NN * DD;
  const int rel = blockIdx.y;
  const int wsel = SIX ? (rel + 3) % 6 : rel;
  const int arel = SIX ? rel % 3 : rel;
  const unsigned short* fwp = fw + (size_t)wsel * 16384;
  const float* rsqip = EPI ? rsqi + (size_t)arel * NN : nullptr;
  const float* biasp = EPI ? bias + (size_t)wsel * DD : nullptr;
  unsigned short* Cbp = Cb + (size_t)rel * ND;
  __shared__ unsigned short sF[16384];  // 32 KB
  const int tid = threadIdx.x;
  {
    const float4* s = (const float4*)fwp;
    float4* d = (float4*)sF;
#pragma unroll
    for (int i = 0; i < 8; ++i) d[tid + i * 256] = s[tid + i * 256];
  }
  __syncthreads();
  const int w = tid >> 6, l = tid & 63, la = l & 15, gr = l >> 4;
  const int row0 = blockIdx.x * 128 + w * 32;
  if (row0 >= NN) return;  // after barrier: safe
  const bool m1ok = (row0 + 32) <= NN;  // NN % 16 == 0
  short8_t a[2][4];
#pragma unroll
  for (int m = 0; m < 2; ++m) {
    const int r = row0 + m * 16 + la;
    const bool ok = (m == 0) || m1ok;
    if (AFP32) {
      const float* ap = (const float*)Ap + (size_t)r * DD + gr * 8;
#pragma unroll
      for (int ks = 0; ks < 4; ++ks) {
        short8_t v = (short8_t)0;
        if (ok) {
          float4 x0 = *(const float4*)(ap + ks * 32);
          float4 x1 = *(const float4*)(ap + ks * 32 + 4);
          v[0] = (short)f2bf(x0.x); v[1] = (short)f2bf(x0.y);
          v[2] = (short)f2bf(x0.z); v[3] = (short)f2bf(x0.w);
          v[4] = (short)f2bf(x1.x); v[5] = (short)f2bf(x1.y);
          v[6] = (short)f2bf(x1.z); v[7] = (short)f2bf(x1.w);
        }
        a[m][ks] = v;
      }
    } else {
      const unsigned short* ap =
          (const unsigned short*)Ap + (size_t)arel * ND + (size_t)r * DD + gr * 8;
#pragma unroll
      for (int ks = 0; ks < 4; ++ks)
        a[m][ks] = ok ? *(const short8_t*)(ap + ks * 32) : (short8_t)0;
    }
  }
  f32x4 zero = {0.f, 0.f, 0.f, 0.f};
  f32x4 acc[2][8];
#pragma unroll
  for (int m = 0; m < 2; ++m)
#pragma unroll
    for (int nt = 0; nt < 8; ++nt) acc[m][nt] = zero;
#pragma unroll
  for (int nt = 0; nt < 8; ++nt) {
#pragma unroll
    for (int ks = 0; ks < 4; ++ks) {
      short8_t b = *(const short8_t*)(sF + ((nt * 4 + ks) * 64 + l) * 8);
      acc[0][nt] = __builtin_amdgcn_mfma_f32_16x16x32_bf16(a[0][ks], b, acc[0][nt], 0, 0, 0);
      acc[1][nt] = __builtin_amdgcn_mfma_f32_16x16x32_bf16(a[1][ks], b, acc[1][nt], 0, 0, 0);
    }
  }
#pragma unroll
  for (int m = 0; m < 2; ++m) {
    if (m == 1 && !m1ok) break;
#pragma unroll
    for (int rr = 0; rr < 4; ++rr) {
      const int row = row0 + m * 16 + gr * 4 + rr;
      const float sc = EPI ? rsqip[row] : 0.0f;
#pragma unroll
      for (int nt = 0; nt < 8; ++nt) {
        const int c0 = nt * 16 + la;
        float v = acc[m][nt][rr];
        if (TANH) v = tanhf(v);
        if (EPI) {
          float rv = __uint_as_float((unsigned int)residb[(size_t)row * DD + c0] << 16);
          v = fmaf(v, sc, biasp[c0] + rv);
        }
        Cbp[(size_t)row * DD + c0] = f2bf(v);
      }
    }
  }
}

// ---------------- MFMA concat: y = sum_p hb[p] @ Bp (K=384) ----------------
__global__ __launch_bounds__(512) void mconcat_kernel(
    const unsigned short* __restrict__ h0b, const unsigned short* __restrict__ h1b,
    const unsigned short* __restrict__ h2b, const unsigned short* __restrict__ fwc,
    float* __restrict__ Y) {
  __shared__ unsigned short sF[3 * 16384];  // 96 KB
  const int tid = threadIdx.x;
  {
    const float4* s = (const float4*)fwc;
    float4* d = (float4*)sF;
#pragma unroll
    for (int i = 0; i < 12; ++i) d[tid + i * 512] = s[tid + i * 512];
  }
  __syncthreads();
  const int w = tid >> 6, l = tid & 63, la = l & 15, gr = l >> 4;
  const int row0 = blockIdx.x * 256 + w * 32;
  if (row0 >= NN) return;
  const bool m1ok = (row0 + 32) <= NN;
  const unsigned short* hb[3] = {h0b, h1b, h2b};
  f32x4 zero = {0.f, 0.f, 0.f, 0.f};
  f32x4 acc[2][8];
#pragma unroll
  for (int m = 0; m < 2; ++m)
#pragma unroll
    for (int nt = 0; nt < 8; ++nt) acc[m][nt] = zero;
#pragma unroll
  for (int p = 0; p < 3; ++p) {
    short8_t a[2][4];
#pragma unroll
    for (int m = 0; m < 2; ++m) {
      const int r = row0 + m * 16 + la;
      const bool ok = (m == 0) || m1ok;
      const unsigned short* ap = hb[p] + (size_t)r * DD + gr * 8;
#pragma unroll
      for (int ks = 0; ks < 4; ++ks)
        a[m][ks] = ok ? *(const short8_t*)(ap + ks * 32) : (short8_t)0;
    }
    const unsigned short* sfp = sF + p * 16384;
#pragma unroll
    for (int nt = 0; nt < 8; ++nt) {
#pragma unroll
      for (int ks = 0; ks < 4; ++ks) {
        short8_t b = *(const short8_t*)(sfp + ((nt * 4 + ks) * 64 + l) * 8);
        acc[0][nt] = __builtin_amdgcn_mfma_f32_16x16x32_bf16(a[0][ks], b, acc[0][nt], 0, 0, 0);
        acc[1][nt] = __builtin_amdgcn_mfma_f32_16x16x32_bf16(a[1][ks], b, acc[1][nt], 0, 0, 0);
      }
    }
  }
#pragma unroll
  for (int m = 0; m < 2; ++m) {
    if (m == 1 && !m1ok) break;
#pragma unroll
    for (int rr = 0; rr < 4; ++rr) {
      const int row = row0 + m * 16 + gr * 4 + rr;
#pragma unroll
      for (int nt = 0; nt < 8; ++nt)
        Y[(size_t)row * DD + nt * 16 + la] = acc[m][nt][rr];
    }
  }
}

// ---------------- bf16 CSR gather, batched over gridDim.y = relations --------
#define ACC8(A, V, C) \
  A[0] = fmaf(bfl((V).x), (C), A[0]); A[1] = fmaf(bfh((V).x), (C), A[1]); \
  A[2] = fmaf(bfl((V).y), (C), A[2]); A[3] = fmaf(bfh((V).y), (C), A[3]); \
  A[4] = fmaf(bfl((V).z), (C), A[4]); A[5] = fmaf(bfh((V).z), (C), A[5]); \
  A[6] = fmaf(bfl((V).w), (C), A[6]); A[7] = fmaf(bfh((V).w), (C), A[7]);

__global__ __launch_bounds__(256) void gatherb_kernel(
    const unsigned short* __restrict__ hb, const int* __restrict__ rowptr,
    const int* __restrict__ col, const float* __restrict__ rsqo,
    unsigned short* __restrict__ ub) {
  const size_t ND = (size_t)NN * DD;
  const int rel = blockIdx.y;
  rowptr += (size_t)rel * (NN + 1);
  col += (size_t)rel * NE;
  rsqo += (size_t)rel * NN;
  ub += (size_t)rel * ND;
  int gid = blockIdx.x * 256 + threadIdx.x;
  int n = gid >> 4;
  int lane = gid & 15;
  int e0 = clampi(rowptr[n], 0, NE);
  int e1 = clampi(rowptr[n + 1], e0, NE);
  const uint4* h4 = (const uint4*)hb;  // row = 16 x uint4 (256B)
  float a[8] = {0, 0, 0, 0, 0, 0, 0, 0}, b[8] = {0, 0, 0, 0, 0, 0, 0, 0};
  float c[8] = {0, 0, 0, 0, 0, 0, 0, 0}, d[8] = {0, 0, 0, 0, 0, 0, 0, 0};
  int e = e0;
  for (; e + 7 < e1; e += 8) {  // 8 outstanding row loads
    int s0 = clampi(col[e], 0, NN - 1), s1 = clampi(col[e + 1], 0, NN - 1);
    int s2 = clampi(col[e + 2], 0, NN - 1), s3 = clampi(col[e + 3], 0, NN - 1);
    int s4 = clampi(col[e + 4], 0, NN - 1), s5 = clampi(col[e + 5], 0, NN - 1);
    int s6 = clampi(col[e + 6], 0, NN - 1), s7 = clampi(col[e + 7], 0, NN - 1);
    float c0 = rsqo[s0], c1 = rsqo[s1], c2 = rsqo[s2], c3 = rsqo[s3];
    float c4 = rsqo[s4], c5 = rsqo[s5], c6 = rsqo[s6], c7 = rsqo[s7];
    uint4 v0 = h4[(size_t)s0 * 16 + lane];
    uint4 v1 = h4[(size_t)s1 * 16 + lane];
    uint4 v2 = h4[(size_t)s2 * 16 + lane];
    uint4 v3 = h4[(size_t)s3 * 16 + lane];
    uint4 v4 = h4[(size_t)s4 * 16 + lane];
    uint4 v5 = h4[(size_t)s5 * 16 + lane];
    uint4 v6 = h4[(size_t)s6 * 16 + lane];
    uint4 v7 = h4[(size_t)s7 * 16 + lane];
    ACC8(a, v0, c0) ACC8(b, v1, c1) ACC8(c, v2, c2) ACC8(d, v3, c3)
    ACC8(a, v4, c4) ACC8(b, v5, c5) ACC8(c, v6, c6) ACC8(d, v7, c7)
  }
  for (; e + 3 < e1; e += 4) {
    int s0 = clampi(col[e], 0, NN - 1), s1 = clampi(col[e + 1], 0, NN - 1);
    int s2 = clampi(col[e + 2], 0, NN - 1), s3 = clampi(col[e + 3], 0, NN - 1);
    float c0 = rsqo[s0], c1 = rsqo[s1], c2 = rsqo[s2], c3 = rsqo[s3];
    uint4 v0 = h4[(size_t)s0 * 16 + lane];
    uint4 v1 = h4[(size_t)s1 * 16 + lane];
    uint4 v2 = h4[(size_t)s2 * 16 + lane];
    uint4 v3 = h4[(size_t)s3 * 16 + lane];
    ACC8(a, v0, c0) ACC8(b, v1, c1) ACC8(c, v2, c2) ACC8(d, v3, c3)
  }
  for (; e < e1; ++e) {
    int s0 = clampi(col[e], 0, NN - 1);
    float c0 = rsqo[s0];
    uint4 v0 = h4[(size_t)s0 * 16 + lane];
    ACC8(a, v0, c0)
  }
#pragma unroll
  for (int j = 0; j < 8; ++j) a[j] += b[j] + c[j] + d[j];
  uint4 o;
  o.x = (unsigned int)f2bf(a[0]) | ((unsigned int)f2bf(a[1]) << 16);
  o.y = (unsigned int)f2bf(a[2]) | ((unsigned int)f2bf(a[3]) << 16);
  o.z = (unsigned int)f2bf(a[4]) | ((unsigned int)f2bf(a[5]) << 16);
  o.w = (unsigned int)f2bf(a[6]) | ((unsigned int)f2bf(a[7]) << 16);
  ((uint4*)ub)[gid] = o;
}

// ------- fused MFMA scores + softmax + combine (Vb read once, in registers) ---
// TWO=1: gridDim.y=2 → y=0: planes 0-2 (l=1, fa1, AQ1, out hout+0);
//                      y=1: planes 3-5 (l=0, fa0, AQ0, out hout+ND).
template <int TWO>
__global__ __launch_bounds__(256) void mscomb_kernel(
    const unsigned short* __restrict__ Vb, const unsigned short* __restrict__ faB,
    const float* __restrict__ AQB, unsigned short* __restrict__ houtB,
    float* __restrict__ attn_out) {
  const size_t ND = (size_t)NN * DD;
  const int y = TWO ? blockIdx.y : 0;
  const unsigned short* Vp = Vb + (TWO ? (size_t)y * 3 * ND : 0);
  const unsigned short* fa = TWO ? faB + (size_t)(1 - y) * 8192 : faB;
  const float* AQ = TWO ? AQB + (size_t)(1 - y) * DQ : AQB;
  unsigned short* houtb = TWO ? houtB + (size_t)y * ND : houtB;
  __shared__ unsigned short sF[8192];  // 16 KB
  __shared__ float sS[4][3][32];
  const int tid = threadIdx.x;
  {
    const float4* s = (const float4*)fa;
    float4* d = (float4*)sF;
#pragma unroll
    for (int i = 0; i < 4; ++i) d[tid + i * 256] = s[tid + i * 256];
  }
  const int w = tid >> 6, l = tid & 63, la = l & 15, gr = l >> 4;
  int row0 = blockIdx.x * 128 + w * 32;
  if (row0 + 32 > NN) row0 = NN - 32;  // clamp (dup rows idempotent), no return
  short8_t a[3][2][4];
#pragma unroll
  for (int r3 = 0; r3 < 3; ++r3) {
#pragma unroll
    for (int m = 0; m < 2; ++m) {
      const unsigned short* rp =
          Vp + (size_t)r3 * ND + (size_t)(row0 + m * 16 + la) * DD + gr * 8;
#pragma unroll
      for (int ks = 0; ks < 4; ++ks)
        a[r3][m][ks] = *(const short8_t*)(rp + ks * 32);
    }
  }
  __syncthreads();  // sF ready
  float q[4];
#pragma unroll
  for (int nt = 0; nt < 4; ++nt) q[nt] = AQ[la + nt * 16];
#pragma unroll
  for (int r3 = 0; r3 < 3; ++r3) {
    f32x4 zero = {0.f, 0.f, 0.f, 0.f};
    f32x4 acc[2][4];
#pragma unroll
    for (int m = 0; m < 2; ++m)
#pragma unroll
      for (int nt = 0; nt < 4; ++nt) acc[m][nt] = zero;
#pragma unroll
    for (int nt = 0; nt < 4; ++nt) {
#pragma unroll
      for (int ks = 0; ks < 4; ++ks) {
        short8_t b = *(const short8_t*)(sF + ((nt * 4 + ks) * 64 + l) * 8);
        acc[0][nt] = __builtin_amdgcn_mfma_f32_16x16x32_bf16(a[r3][0][ks], b, acc[0][nt], 0, 0, 0);
        acc[1][nt] = __builtin_amdgcn_mfma_f32_16x16x32_bf16(a[r3][1][ks], b, acc[1][nt], 0, 0, 0);
      }
    }
#pragma unroll
    for (int m = 0; m < 2; ++m) {
#pragma unroll
      for (int rr = 0; rr < 4; ++rr) {
        float p = tanhf(acc[m][0][rr]) * q[0] + tanhf(acc[m][1][rr]) * q[1] +
                  tanhf(acc[m][2][rr]) * q[2] + tanhf(acc[m][3][rr]) * q[3];
#pragma unroll
        for (int off = 1; off < 16; off <<= 1) p += __shfl_xor(p, off, 16);
        if (la == 0) sS[w][r3][m * 16 + gr * 4 + rr] = p;
      }
    }
  }
  __syncthreads();
#pragma unroll
  for (int m = 0; m < 2; ++m) {
    const int row = row0 + m * 16 + la;
    float s0 = sS[w][0][m * 16 + la];
    float s1 = sS[w][1][m * 16 + la];
    float s2 = sS[w][2][m * 16 + la];
    float mx = fmaxf(s0, fmaxf(s1, s2));
    float e0 = __expf(s0 - mx), e1 = __expf(s1 - mx), e2 = __expf(s2 - mx);
    float inv = 1.0f / (e0 + e1 + e2);
    float a0 = e0 * inv, a1 = e1 * inv, a2 = e2 * inv;
#pragma unroll
    for (int ks = 0; ks < 4; ++ks) {
      unsigned int ow[4];
#pragma unroll
      for (int jj = 0; jj < 4; ++jj) {
        float v0 = a0 * b2f(a[0][m][ks][2 * jj]) + a1 * b2f(a[1][m][ks][2 * jj]) +
                   a2 * b2f(a[2][m][ks][2 * jj]);
        float v1 = a0 * b2f(a[0][m][ks][2 * jj + 1]) + a1 * b2f(a[1][m][ks][2 * jj + 1]) +
                   a2 * b2f(a[2][m][ks][2 * jj + 1]);
        ow[jj] = (unsigned int)f2bf(v0) | ((unsigned int)f2bf(v1) << 16);
      }
      *(uint4*)(houtb + (size_t)row * DD + gr * 8 + ks * 32) =
          make_uint4(ow[0], ow[1], ow[2], ow[3]);
    }
    if (attn_out != nullptr) {
      attn_out[(size_t)row * 3 + 0] = a0;
      attn_out[(size_t)row * 3 + 1] = a1;
      attn_out[(size_t)row * 3 + 2] = a2;
    }
  }
}

extern "C" void kernel_launch(void* const* d_in, const int* in_sizes, int n_in,
                              void* d_out, int out_size, void* d_ws, size_t ws_size,
                              hipStream_t stream) {
  const float* x        = (const float*)d_in[0];
  const int*   edges    = (const int*)d_in[1];
  const float* feat_w   = (const float*)d_in[2];
  const float* conv_w   = (const float*)d_in[3];
  const float* conv_b   = (const float*)d_in[4];
  const float* attn_w   = (const float*)d_in[5];
  const float* attn_q   = (const float*)d_in[6];
  const float* concat_w = (const float*)d_in[7];
  float* out = (float*)d_out;   // [NN*128 y][NN*3 attn]

  float* ws = (float*)d_ws;
  float* rsqo = ws;                   // [3][NN]
  float* rsqi = rsqo + 3 * NN;        // [3][NN]
  int* flag = (int*)(rsqi + 3 * NN);  // 16 ints
  int* btot = flag + 16;              // 80 ints
  int* boff = btot + 80;              // 80 ints
  int* cnt = boff + 80;               // [3][NN]; fw overlays after scanp1
  int* rowptr = cnt + 3 * NN;         // [3][NN+1] (+pad)
  int* col = rowptr + 3 * (NN + 1) + 13;  // [3][NE]
  const size_t ND = (size_t)NN * DD;
  float* P1 = (float*)(col + 3 * (size_t)NE);  // VbAll planes 0-1
  float* PA = P1 + ND;   // prologue: hist | VbAll planes 2-3
  float* PB = PA + ND;   // prologue: bases | VbAll planes 4-5
  unsigned short* U0 = (unsigned short*)(PB + ND);  // u bf16 x3; later h2b
  unsigned short* B0 = U0 + 3 * ND;   // h0b
  unsigned short* B1 = B0 + ND;       // h1b
  unsigned short* B2 = B1 + ND;       // tb
  unsigned short* fw = (unsigned short*)cnt;   // 10x16384 + 2x8192 ushort
  unsigned int* hist = (unsigned int*)PA;      // 6*NB*NW <= ND
  int* bases = (int*)PB;                       // 3*NB*NN <= ND
  unsigned short* VbAll = (unsigned short*)P1; // 6 bf16 vals planes (contig)
  unsigned short* fa0 = fw + (size_t)10 * 16384;
  unsigned short* fa1 = fa0 + 8192;

  // prologue: degrees + CSR (no global atomics) + weight fragments
  detect_kernel<<<1, 64, 0, stream>>>(edges, flag);
  hist6_kernel<<<dim3(NB, 6), 512, 0, stream>>>(edges, flag, hist);
  sumhist_kernel<<<dim3(25, 6), 256, 0, stream>>>(hist, cnt, rsqi, rsqo);
  scanp1_kernel<<<dim3(25, 3), 256, 0, stream>>>(cnt, rowptr, btot);
  scanp2_kernel<<<1, 64, 0, stream>>>(btot, boff, rowptr);
  scanp3_kernel<<<dim3(25, 3), 256, 0, stream>>>(boff, rowptr);
  prepw_kernel<<<12, 256, 0, stream>>>(conv_w, feat_w, concat_w, attn_w, fw);
  bases_kernel<<<dim3(25, 3), 256, 0, stream>>>(hist, rowptr, bases);
  fill2_kernel<<<dim3(NB, 3), 512, 0, stream>>>(edges, flag, bases, col);

  // h0 = tanh(x @ feat_w) -> B0 bf16
  mgemm_kernel<1, 1, 0, 0><<<dim3(391, 1), 256, 0, stream>>>(
      x, fw + (size_t)6 * 16384, nullptr, nullptr, nullptr, B0);

  // shared u[r] = A_r^T (h0 * rsqo_r) -> U planes, batched
  gatherb_kernel<<<dim3(3125, 3), 256, 0, stream>>>(B0, rowptr, col, rsqo, U0);

  // both h0-fed layers in one launch: planes 0-2 = l1 vals, 3-5 = l0 vals
  mgemm_kernel<0, 0, 1, 1><<<dim3(391, 6), 256, 0, stream>>>(
      U0, fw, rsqi, conv_b, B0, VbAll);
  // both mscombs in one launch: h1 -> B1, t -> B2
  mscomb_kernel<1><<<dim3(391, 2), 256, 0, stream>>>(
      VbAll, fa0, attn_q, B1, nullptr);

  // layer l=1 on t: gathers from B2 -> U; convs (resid = B2) -> planes 0-2
  gatherb_kernel<<<dim3(3125, 3), 256, 0, stream>>>(B2, rowptr, col, rsqo, U0);
  mgemm_kernel<0, 0, 1, 0><<<dim3(391, 3), 256, 0, stream>>>(
      U0, fw + (size_t)3 * 16384, rsqi, conv_b + (size_t)3 * DD, B2, VbAll);
  // h2 -> U0 (bf16), attn -> out+ND
  mscomb_kernel<0><<<dim3(391, 1), 256, 0, stream>>>(
      VbAll, fa1, attn_q + DQ, U0, out + ND);

  // y = [h0|h1|h2] @ CW^T -> out
  mconcat_kernel<<<196, 512, 0, stream>>>(B0, B1, U0, fw + (size_t)7 * 16384, out);
}

// Round 11
// 452.992 us; speedup vs baseline: 28.7229x; 1.0267x over previous
//
#include <hip/hip_runtime.h>

#define NN 50000
#define NE 800000
#define DD 128
#define DQ 64
#define NB 42          // histogram/fill blocks per (relation, array)
#define SL 19048       // edge slice per block: 42*19048 >= NE
#define NW 25000       // packed uint16 words covering NN counters

typedef __attribute__((ext_vector_type(8))) short short8_t;  // 8 bf16 (4 VGPR)
typedef __attribute__((ext_vector_type(4))) float f32x4;     // MFMA acc

__device__ __forceinline__ int clampi(int v, int lo, int hi) {
  return v < lo ? lo : (v > hi ? hi : v);
}
__device__ __forceinline__ unsigned short f2bf(float f) {  // RNE fp32->bf16
  unsigned int u = __float_as_uint(f);
  return (unsigned short)((u + 0x7FFFu + ((u >> 16) & 1u)) >> 16);
}
__device__ __forceinline__ float bfl(unsigned int u) { return __uint_as_float(u << 16); }
__device__ __forceinline__ float bfh(unsigned int u) { return __uint_as_float(u & 0xFFFF0000u); }
__device__ __forceinline__ float b2f(short s) {
  return __uint_as_float(((unsigned int)(unsigned short)s) << 16);
}

// ---------------- prologue (edges are int32 per harness contract) ----------------
// Per-block LDS histograms, packed 2x uint16/word. For dst combos (a=0) also
// emits each edge's LOCAL RANK (the atomicAdd return) -> rank[], which replaces
// fill2's whole second LDS-cursor pass.
__global__ __launch_bounds__(512) void hist6_kernel(
    const int* __restrict__ e, unsigned int* __restrict__ hist,
    unsigned short* __restrict__ rank) {
  __shared__ unsigned int lds[NW];  // 100 KB
  const int b = blockIdx.x;
  const int c = blockIdx.y;
  const int r = c >> 1;
  const int a = c & 1;  // 0: dst (rank emitted), 1: src
  const int tid = threadIdx.x;
  for (int i = tid; i < NW; i += 512) lds[i] = 0u;
  __syncthreads();
  const size_t abase = (size_t)r * 2 * NE + (a ? 0 : NE);
  const int beg = b * SL, end = min(beg + SL, NE);
  if (a == 0) {
    unsigned short* rk = rank + (size_t)r * NE;
    for (int i = beg + tid; i < end; i += 512) {
      int v = clampi(e[abase + i], 0, NN - 1);
      unsigned int sh = (v & 1) * 16;
      unsigned int old = atomicAdd(&lds[v >> 1], 1u << sh);
      rk[i] = (unsigned short)((old >> sh) & 0xFFFFu);
    }
  } else {
    for (int i = beg + tid; i < end; i += 512) {
      int v = clampi(e[abase + i], 0, NN - 1);
      atomicAdd(&lds[v >> 1], 1u << ((v & 1) * 16));
    }
  }
  __syncthreads();
  unsigned int* outp = hist + ((size_t)c * NB + b) * NW;
  for (int i = tid; i < NW; i += 512) outp[i] = lds[i];
}

// Merged sumhist + local scan. grid (25, 6): block (g,c) covers words
// [g*1000, g*1000+1000) = nodes [g*2000, +2000). a=0: cnt sum -> rsqi +
// block-local exclusive prefix into rowptr (local) + btot. a=1: rsqo only.
__global__ __launch_bounds__(256) void sumscan_kernel(
    const unsigned int* __restrict__ hist, int* __restrict__ rowptr,
    int* __restrict__ btot, float* __restrict__ rsqi, float* __restrict__ rsqo) {
  __shared__ int part[256];
  const int g = blockIdx.x;
  const int c = blockIdx.y;
  const int r = c >> 1, a = c & 1;
  const int t = threadIdx.x;
  int cntv[8];
  int s = 0;
  const int w0 = g * 1000 + t * 4;
  if (t < 250) {
#pragma unroll
    for (int j = 0; j < 4; ++j) {
      const unsigned int* hp = hist + (size_t)c * NB * NW + w0 + j;
      unsigned int lo = 0, hi = 0;
#pragma unroll 7
      for (int b = 0; b < NB; ++b) {
        unsigned int v = hp[(size_t)b * NW];
        lo += v & 0xFFFFu;
        hi += v >> 16;
      }
      cntv[2 * j] = (int)lo;
      cntv[2 * j + 1] = (int)hi;
      int n0 = 2 * (w0 + j), n1 = n0 + 1;
      float f0 = rsqrtf(fmaxf((float)lo, 1.0f));
      float f1 = rsqrtf(fmaxf((float)hi, 1.0f));
      if (a == 0) {
        rsqi[r * NN + n0] = f0;
        rsqi[r * NN + n1] = f1;
      } else {
        rsqo[r * NN + n0] = f0;
        rsqo[r * NN + n1] = f1;
      }
      s += (int)(lo + hi);
    }
  }
  if (a == 1) return;  // block-uniform: src combos skip the scan
  part[t] = s;
  __syncthreads();
  for (int off = 1; off < 256; off <<= 1) {
    int x = (t >= off) ? part[t - off] : 0;
    __syncthreads();
    part[t] += x;
    __syncthreads();
  }
  if (t < 250) {
    int excl = part[t] - s;
    int base = g * 2000 + t * 8;
#pragma unroll
    for (int j = 0; j < 8; ++j) {
      rowptr[r * (NN + 1) + base + j] = excl;  // block-LOCAL for now
      excl += cntv[j];
    }
  }
  if (t == 255) btot[r * 25 + g] = part[255];
}

// Tiny: block offsets + totals. Also writes rowptr[NN] (final).
__global__ __launch_bounds__(64) void scanp2_kernel(
    const int* __restrict__ btot, int* __restrict__ boff, int* __restrict__ rowptr) {
  if (threadIdx.x == 0) {
    for (int r = 0; r < 3; ++r) {
      int run = 0;
      for (int b = 0; b < 25; ++b) {
        boff[r * 25 + b] = run;
        run += btot[r * 25 + b];
      }
      rowptr[r * (NN + 1) + NN] = run;
    }
  }
}

// Finalize rowptr IN PLACE (local + boff) and emit per-histblock fill bases.
// grid (25,3) aligned with sumscan's 2000-node blocks.
__global__ __launch_bounds__(256) void bases_kernel(
    const unsigned int* __restrict__ hist, const int* __restrict__ boff,
    int* __restrict__ rowptr, int* __restrict__ bases) {
  const int r = blockIdx.y;
  const int off = boff[r * 25 + blockIdx.x];
  for (int wl = threadIdx.x; wl < 1000; wl += 256) {
    int w = blockIdx.x * 1000 + wl;
    int n0 = 2 * w, n1 = n0 + 1;
    int run0 = rowptr[r * (NN + 1) + n0] + off;
    int run1 = rowptr[r * (NN + 1) + n1] + off;
    rowptr[r * (NN + 1) + n0] = run0;   // finalize
    rowptr[r * (NN + 1) + n1] = run1;
    const unsigned int* hp = hist + (size_t)(r * 2) * NB * NW + w;
    int* bp = bases + (size_t)r * NB * NN;
#pragma unroll 7
    for (int b = 0; b < NB; ++b) {
      unsigned int v = hp[(size_t)b * NW];
      bp[(size_t)b * NN + n0] = run0;
      bp[(size_t)b * NN + n1] = run1;
      run0 += (int)(v & 0xFFFFu);
      run1 += (int)(v >> 16);
    }
  }
}

// Streaming CSR fill: pos = bases[edge's histblock][dst] + rank. No LDS.
// grid (3125, 3): 3125*256 == NE exactly.
__global__ __launch_bounds__(256) void fillr_kernel(
    const int* __restrict__ e, const unsigned short* __restrict__ rank,
    const int* __restrict__ bases, int* __restrict__ col) {
  const int r = blockIdx.y;
  const int i = blockIdx.x * 256 + threadIdx.x;
  const size_t sbase = (size_t)r * 2 * NE;
  int s = clampi(e[sbase + i], 0, NN - 1);
  int d = clampi(e[sbase + NE + i], 0, NN - 1);
  int b = i / SL;
  int pos = clampi(bases[((size_t)r * NB + b) * NN + d] + (int)rank[(size_t)r * NE + i],
                   0, NE - 1);
  col[(size_t)r * NE + pos] = s;
}

// ---------------- weight fragment prep ----------------
// i 0..5: conv_w (128x128); 6: feat_w; 7..9: concat part; 10..11: attn_w[l] (128x64).
__global__ __launch_bounds__(256) void prepw_kernel(
    const float* __restrict__ conv_w, const float* __restrict__ feat_w,
    const float* __restrict__ concat_w, const float* __restrict__ attn_w,
    unsigned short* __restrict__ fw) {
  const int i = blockIdx.x;
  if (i < 10) {
    unsigned short* dst = fw + (size_t)i * 16384;
    for (int e = threadIdx.x; e < 2048; e += 256) {
      int nt = e >> 8, ks = (e >> 6) & 3, lane = e & 63;
      int n = (lane & 15) + nt * 16;
      int kb = (lane >> 4) * 8 + ks * 32;
      unsigned int w[4];
#pragma unroll
      for (int jj = 0; jj < 4; ++jj) {
        int k0 = kb + 2 * jj, k1 = k0 + 1;
        float f0, f1;
        if (i < 6) {
          f0 = conv_w[(size_t)i * 16384 + (size_t)k0 * DD + n];
          f1 = conv_w[(size_t)i * 16384 + (size_t)k1 * DD + n];
        } else if (i == 6) {
          f0 = feat_w[(size_t)k0 * DD + n];
          f1 = feat_w[(size_t)k1 * DD + n];
        } else {
          int p = i - 7;
          f0 = concat_w[(size_t)n * 384 + p * DD + k0];
          f1 = concat_w[(size_t)n * 384 + p * DD + k1];
        }
        w[jj] = (unsigned int)f2bf(f0) | ((unsigned int)f2bf(f1) << 16);
      }
      ((uint4*)dst)[e] = make_uint4(w[0], w[1], w[2], w[3]);
    }
  } else {
    const int l = i - 10;
    unsigned short* dst = fw + (size_t)10 * 16384 + (size_t)l * 8192;
    for (int e = threadIdx.x; e < 1024; e += 256) {
      int nt = e >> 8, ks = (e >> 6) & 3, lane = e & 63;  // nt 0..3
      int n = (lane & 15) + nt * 16;
      int kb = (lane >> 4) * 8 + ks * 32;
      unsigned int w[4];
#pragma unroll
      for (int jj = 0; jj < 4; ++jj) {
        int k0 = kb + 2 * jj, k1 = k0 + 1;
        float f0 = attn_w[((size_t)l * DD + k0) * DQ + n];
        float f1 = attn_w[((size_t)l * DD + k1) * DQ + n];
        w[jj] = (unsigned int)f2bf(f0) | ((unsigned int)f2bf(f1) << 16);
      }
      ((uint4*)dst)[e] = make_uint4(w[0], w[1], w[2], w[3]);
    }
  }
}

// ---------------- MFMA GEMM: Cb = bf16([tanh](A @ W) [*rsqi + bias + residb]) --
// SIX=1: gridDim.y=6 covers both h0-fed layers (weights/bias idx (rel+3)%6,
// A plane rel%3, out plane rel). SIX=0: gridDim.y = relations (all idx rel).
template <int AFP32, int TANH, int EPI, int SIX>
__global__ __launch_bounds__(256) void mgemm_kernel(
    const void* __restrict__ Ap, const unsigned short* __restrict__ fw,
    const float* __restrict__ rsqi, const float* __restrict__ bias,
    const unsigned short* __restrict__ residb, unsigned short* __restrict__ Cb) {
  const size_t ND = (size_t)NN * DD;
  const int rel = blockIdx.y;
  const int wsel = SIX ? (rel + 3) % 6 : rel;
  const int arel = SIX ? rel % 3 : rel;
  const unsigned short* fwp = fw + (size_t)wsel * 16384;
  const float* rsqip = EPI ? rsqi + (size_t)arel * NN : nullptr;
  const float* biasp = EPI ? bias + (size_t)wsel * DD : nullptr;
  unsigned short* Cbp = Cb + (size_t)rel * ND;
  __shared__ unsigned short sF[16384];  // 32 KB
  const int tid = threadIdx.x;
  {
    const float4* s = (const float4*)fwp;
    float4* d = (float4*)sF;
#pragma unroll
    for (int i = 0; i < 8; ++i) d[tid + i * 256] = s[tid + i * 256];
  }
  __syncthreads();
  const int w = tid >> 6, l = tid & 63, la = l & 15, gr = l >> 4;
  const int row0 = blockIdx.x * 128 + w * 32;
  if (row0 >= NN) return;  // after barrier: safe
  const bool m1ok = (row0 + 32) <= NN;  // NN % 16 == 0
  short8_t a[2][4];
#pragma unroll
  for (int m = 0; m < 2; ++m) {
    const int r = row0 + m * 16 + la;
    const bool ok = (m == 0) || m1ok;
    if (AFP32) {
      const float* ap = (const float*)Ap + (size_t)r * DD + gr * 8;
#pragma unroll
      for (int ks = 0; ks < 4; ++ks) {
        short8_t v = (short8_t)0;
        if (ok) {
          float4 x0 = *(const float4*)(ap + ks * 32);
          float4 x1 = *(const float4*)(ap + ks * 32 + 4);
          v[0] = (short)f2bf(x0.x); v[1] = (short)f2bf(x0.y);
          v[2] = (short)f2bf(x0.z); v[3] = (short)f2bf(x0.w);
          v[4] = (short)f2bf(x1.x); v[5] = (short)f2bf(x1.y);
          v[6] = (short)f2bf(x1.z); v[7] = (short)f2bf(x1.w);
        }
        a[m][ks] = v;
      }
    } else {
      const unsigned short* ap =
          (const unsigned short*)Ap + (size_t)arel * ND + (size_t)r * DD + gr * 8;
#pragma unroll
      for (int ks = 0; ks < 4; ++ks)
        a[m][ks] = ok ? *(const short8_t*)(ap + ks * 32) : (short8_t)0;
    }
  }
  f32x4 zero = {0.f, 0.f, 0.f, 0.f};
  f32x4 acc[2][8];
#pragma unroll
  for (int m = 0; m < 2; ++m)
#pragma unroll
    for (int nt = 0; nt < 8; ++nt) acc[m][nt] = zero;
#pragma unroll
  for (int nt = 0; nt < 8; ++nt) {
#pragma unroll
    for (int ks = 0; ks < 4; ++ks) {
      short8_t b = *(const short8_t*)(sF + ((nt * 4 + ks) * 64 + l) * 8);
      acc[0][nt] = __builtin_amdgcn_mfma_f32_16x16x32_bf16(a[0][ks], b, acc[0][nt], 0, 0, 0);
      acc[1][nt] = __builtin_amdgcn_mfma_f32_16x16x32_bf16(a[1][ks], b, acc[1][nt], 0, 0, 0);
    }
  }
#pragma unroll
  for (int m = 0; m < 2; ++m) {
    if (m == 1 && !m1ok) break;
#pragma unroll
    for (int rr = 0; rr < 4; ++rr) {
      const int row = row0 + m * 16 + gr * 4 + rr;
      const float sc = EPI ? rsqip[row] : 0.0f;
#pragma unroll
      for (int nt = 0; nt < 8; ++nt) {
        const int c0 = nt * 16 + la;
        float v = acc[m][nt][rr];
        if (TANH) v = tanhf(v);
        if (EPI) {
          float rv = __uint_as_float((unsigned int)residb[(size_t)row * DD + c0] << 16);
          v = fmaf(v, sc, biasp[c0] + rv);
        }
        Cbp[(size_t)row * DD + c0] = f2bf(v);
      }
    }
  }
}

// ---------------- MFMA concat: y = sum_p hb[p] @ Bp (K=384) ----------------
__global__ __launch_bounds__(512) void mconcat_kernel(
    const unsigned short* __restrict__ h0b, const unsigned short* __restrict__ h1b,
    const unsigned short* __restrict__ h2b, const unsigned short* __restrict__ fwc,
    float* __restrict__ Y) {
  __shared__ unsigned short sF[3 * 16384];  // 96 KB
  const int tid = threadIdx.x;
  {
    const float4* s = (const float4*)fwc;
    float4* d = (float4*)sF;
#pragma unroll
    for (int i = 0; i < 12; ++i) d[tid + i * 512] = s[tid + i * 512];
  }
  __syncthreads();
  const int w = tid >> 6, l = tid & 63, la = l & 15, gr = l >> 4;
  const int row0 = blockIdx.x * 256 + w * 32;
  if (row0 >= NN) return;
  const bool m1ok = (row0 + 32) <= NN;
  const unsigned short* hb[3] = {h0b, h1b, h2b};
  f32x4 zero = {0.f, 0.f, 0.f, 0.f};
  f32x4 acc[2][8];
#pragma unroll
  for (int m = 0; m < 2; ++m)
#pragma unroll
    for (int nt = 0; nt < 8; ++nt) acc[m][nt] = zero;
#pragma unroll
  for (int p = 0; p < 3; ++p) {
    short8_t a[2][4];
#pragma unroll
    for (int m = 0; m < 2; ++m) {
      const int r = row0 + m * 16 + la;
      const bool ok = (m == 0) || m1ok;
      const unsigned short* ap = hb[p] + (size_t)r * DD + gr * 8;
#pragma unroll
      for (int ks = 0; ks < 4; ++ks)
        a[m][ks] = ok ? *(const short8_t*)(ap + ks * 32) : (short8_t)0;
    }
    const unsigned short* sfp = sF + p * 16384;
#pragma unroll
    for (int nt = 0; nt < 8; ++nt) {
#pragma unroll
      for (int ks = 0; ks < 4; ++ks) {
        short8_t b = *(const short8_t*)(sfp + ((nt * 4 + ks) * 64 + l) * 8);
        acc[0][nt] = __builtin_amdgcn_mfma_f32_16x16x32_bf16(a[0][ks], b, acc[0][nt], 0, 0, 0);
        acc[1][nt] = __builtin_amdgcn_mfma_f32_16x16x32_bf16(a[1][ks], b, acc[1][nt], 0, 0, 0);
      }
    }
  }
#pragma unroll
  for (int m = 0; m < 2; ++m) {
    if (m == 1 && !m1ok) break;
#pragma unroll
    for (int rr = 0; rr < 4; ++rr) {
      const int row = row0 + m * 16 + gr * 4 + rr;
#pragma unroll
      for (int nt = 0; nt < 8; ++nt)
        Y[(size_t)row * DD + nt * 16 + la] = acc[m][nt][rr];
    }
  }
}

// ---------------- bf16 CSR gather, batched over gridDim.y = relations --------
#define ACC8(A, V, C) \
  A[0] = fmaf(bfl((V).x), (C), A[0]); A[1] = fmaf(bfh((V).x), (C), A[1]); \
  A[2] = fmaf(bfl((V).y), (C), A[2]); A[3] = fmaf(bfh((V).y), (C), A[3]); \
  A[4] = fmaf(bfl((V).z), (C), A[4]); A[5] = fmaf(bfh((V).z), (C), A[5]); \
  A[6] = fmaf(bfl((V).w), (C), A[6]); A[7] = fmaf(bfh((V).w), (C), A[7]);

__global__ __launch_bounds__(256) void gatherb_kernel(
    const unsigned short* __restrict__ hb, const int* __restrict__ rowptr,
    const int* __restrict__ col, const float* __restrict__ rsqo,
    unsigned short* __restrict__ ub) {
  const size_t ND = (size_t)NN * DD;
  const int rel = blockIdx.y;
  rowptr += (size_t)rel * (NN + 1);
  col += (size_t)rel * NE;
  rsqo += (size_t)rel * NN;
  ub += (size_t)rel * ND;
  int gid = blockIdx.x * 256 + threadIdx.x;
  int n = gid >> 4;
  int lane = gid & 15;
  int e0 = clampi(rowptr[n], 0, NE);
  int e1 = clampi(rowptr[n + 1], e0, NE);
  const uint4* h4 = (const uint4*)hb;  // row = 16 x uint4 (256B)
  float a[8] = {0, 0, 0, 0, 0, 0, 0, 0}, b[8] = {0, 0, 0, 0, 0, 0, 0, 0};
  float c[8] = {0, 0, 0, 0, 0, 0, 0, 0}, d[8] = {0, 0, 0, 0, 0, 0, 0, 0};
  int e = e0;
  for (; e + 7 < e1; e += 8) {  // 8 outstanding row loads
    int s0 = clampi(col[e], 0, NN - 1), s1 = clampi(col[e + 1], 0, NN - 1);
    int s2 = clampi(col[e + 2], 0, NN - 1), s3 = clampi(col[e + 3], 0, NN - 1);
    int s4 = clampi(col[e + 4], 0, NN - 1), s5 = clampi(col[e + 5], 0, NN - 1);
    int s6 = clampi(col[e + 6], 0, NN - 1), s7 = clampi(col[e + 7], 0, NN - 1);
    float c0 = rsqo[s0], c1 = rsqo[s1], c2 = rsqo[s2], c3 = rsqo[s3];
    float c4 = rsqo[s4], c5 = rsqo[s5], c6 = rsqo[s6], c7 = rsqo[s7];
    uint4 v0 = h4[(size_t)s0 * 16 + lane];
    uint4 v1 = h4[(size_t)s1 * 16 + lane];
    uint4 v2 = h4[(size_t)s2 * 16 + lane];
    uint4 v3 = h4[(size_t)s3 * 16 + lane];
    uint4 v4 = h4[(size_t)s4 * 16 + lane];
    uint4 v5 = h4[(size_t)s5 * 16 + lane];
    uint4 v6 = h4[(size_t)s6 * 16 + lane];
    uint4 v7 = h4[(size_t)s7 * 16 + lane];
    ACC8(a, v0, c0) ACC8(b, v1, c1) ACC8(c, v2, c2) ACC8(d, v3, c3)
    ACC8(a, v4, c4) ACC8(b, v5, c5) ACC8(c, v6, c6) ACC8(d, v7, c7)
  }
  for (; e + 3 < e1; e += 4) {
    int s0 = clampi(col[e], 0, NN - 1), s1 = clampi(col[e + 1], 0, NN - 1);
    int s2 = clampi(col[e + 2], 0, NN - 1), s3 = clampi(col[e + 3], 0, NN - 1);
    float c0 = rsqo[s0], c1 = rsqo[s1], c2 = rsqo[s2], c3 = rsqo[s3];
    uint4 v0 = h4[(size_t)s0 * 16 + lane];
    uint4 v1 = h4[(size_t)s1 * 16 + lane];
    uint4 v2 = h4[(size_t)s2 * 16 + lane];
    uint4 v3 = h4[(size_t)s3 * 16 + lane];
    ACC8(a, v0, c0) ACC8(b, v1, c1) ACC8(c, v2, c2) ACC8(d, v3, c3)
  }
  for (; e < e1; ++e) {
    int s0 = clampi(col[e], 0, NN - 1);
    float c0 = rsqo[s0];
    uint4 v0 = h4[(size_t)s0 * 16 + lane];
    ACC8(a, v0, c0)
  }
#pragma unroll
  for (int j = 0; j < 8; ++j) a[j] += b[j] + c[j] + d[j];
  uint4 o;
  o.x = (unsigned int)f2bf(a[0]) | ((unsigned int)f2bf(a[1]) << 16);
  o.y = (unsigned int)f2bf(a[2]) | ((unsigned int)f2bf(a[3]) << 16);
  o.z = (unsigned int)f2bf(a[4]) | ((unsigned int)f2bf(a[5]) << 16);
  o.w = (unsigned int)f2bf(a[6]) | ((unsigned int)f2bf(a[7]) << 16);
  ((uint4*)ub)[gid] = o;
}

// ------- fused MFMA scores + softmax + combine (Vb read once, in registers) ---
// TWO=1: gridDim.y=2 → y=0: planes 0-2 (l=1, fa1, AQ1, out hout+0);
//                      y=1: planes 3-5 (l=0, fa0, AQ0, out hout+ND).
template <int TWO>
__global__ __launch_bounds__(256) void mscomb_kernel(
    const unsigned short* __restrict__ Vb, const unsigned short* __restrict__ faB,
    const float* __restrict__ AQB, unsigned short* __restrict__ houtB,
    float* __restrict__ attn_out) {
  const size_t ND = (size_t)NN * DD;
  const int y = TWO ? blockIdx.y : 0;
  const unsigned short* Vp = Vb + (TWO ? (size_t)y * 3 * ND : 0);
  const unsigned short* fa = TWO ? faB + (size_t)(1 - y) * 8192 : faB;
  const float* AQ = TWO ? AQB + (size_t)(1 - y) * DQ : AQB;
  unsigned short* houtb = TWO ? houtB + (size_t)y * ND : houtB;
  __shared__ unsigned short sF[8192];  // 16 KB
  __shared__ float sS[4][3][32];
  const int tid = threadIdx.x;
  {
    const float4* s = (const float4*)fa;
    float4* d = (float4*)sF;
#pragma unroll
    for (int i = 0; i < 4; ++i) d[tid + i * 256] = s[tid + i * 256];
  }
  const int w = tid >> 6, l = tid & 63, la = l & 15, gr = l >> 4;
  int row0 = blockIdx.x * 128 + w * 32;
  if (row0 + 32 > NN) row0 = NN - 32;  // clamp (dup rows idempotent), no return
  short8_t a[3][2][4];
#pragma unroll
  for (int r3 = 0; r3 < 3; ++r3) {
#pragma unroll
    for (int m = 0; m < 2; ++m) {
      const unsigned short* rp =
          Vp + (size_t)r3 * ND + (size_t)(row0 + m * 16 + la) * DD + gr * 8;
#pragma unroll
      for (int ks = 0; ks < 4; ++ks)
        a[r3][m][ks] = *(const short8_t*)(rp + ks * 32);
    }
  }
  __syncthreads();  // sF ready
  float q[4];
#pragma unroll
  for (int nt = 0; nt < 4; ++nt) q[nt] = AQ[la + nt * 16];
#pragma unroll
  for (int r3 = 0; r3 < 3; ++r3) {
    f32x4 zero = {0.f, 0.f, 0.f, 0.f};
    f32x4 acc[2][4];
#pragma unroll
    for (int m = 0; m < 2; ++m)
#pragma unroll
      for (int nt = 0; nt < 4; ++nt) acc[m][nt] = zero;
#pragma unroll
    for (int nt = 0; nt < 4; ++nt) {
#pragma unroll
      for (int ks = 0; ks < 4; ++ks) {
        short8_t b = *(const short8_t*)(sF + ((nt * 4 + ks) * 64 + l) * 8);
        acc[0][nt] = __builtin_amdgcn_mfma_f32_16x16x32_bf16(a[r3][0][ks], b, acc[0][nt], 0, 0, 0);
        acc[1][nt] = __builtin_amdgcn_mfma_f32_16x16x32_bf16(a[r3][1][ks], b, acc[1][nt], 0, 0, 0);
      }
    }
#pragma unroll
    for (int m = 0; m < 2; ++m) {
#pragma unroll
      for (int rr = 0; rr < 4; ++rr) {
        float p = tanhf(acc[m][0][rr]) * q[0] + tanhf(acc[m][1][rr]) * q[1] +
                  tanhf(acc[m][2][rr]) * q[2] + tanhf(acc[m][3][rr]) * q[3];
#pragma unroll
        for (int off = 1; off < 16; off <<= 1) p += __shfl_xor(p, off, 16);
        if (la == 0) sS[w][r3][m * 16 + gr * 4 + rr] = p;
      }
    }
  }
  __syncthreads();
#pragma unroll
  for (int m = 0; m < 2; ++m) {
    const int row = row0 + m * 16 + la;
    float s0 = sS[w][0][m * 16 + la];
    float s1 = sS[w][1][m * 16 + la];
    float s2 = sS[w][2][m * 16 + la];
    float mx = fmaxf(s0, fmaxf(s1, s2));
    float e0 = __expf(s0 - mx), e1 = __expf(s1 - mx), e2 = __expf(s2 - mx);
    float inv = 1.0f / (e0 + e1 + e2);
    float a0 = e0 * inv, a1 = e1 * inv, a2 = e2 * inv;
#pragma unroll
    for (int ks = 0; ks < 4; ++ks) {
      unsigned int ow[4];
#pragma unroll
      for (int jj = 0; jj < 4; ++jj) {
        float v0 = a0 * b2f(a[0][m][ks][2 * jj]) + a1 * b2f(a[1][m][ks][2 * jj]) +
                   a2 * b2f(a[2][m][ks][2 * jj]);
        float v1 = a0 * b2f(a[0][m][ks][2 * jj + 1]) + a1 * b2f(a[1][m][ks][2 * jj + 1]) +
                   a2 * b2f(a[2][m][ks][2 * jj + 1]);
        ow[jj] = (unsigned int)f2bf(v0) | ((unsigned int)f2bf(v1) << 16);
      }
      *(uint4*)(houtb + (size_t)row * DD + gr * 8 + ks * 32) =
          make_uint4(ow[0], ow[1], ow[2], ow[3]);
    }
    if (attn_out != nullptr) {
      attn_out[(size_t)row * 3 + 0] = a0;
      attn_out[(size_t)row * 3 + 1] = a1;
      attn_out[(size_t)row * 3 + 2] = a2;
    }
  }
}

extern "C" void kernel_launch(void* const* d_in, const int* in_sizes, int n_in,
                              void* d_out, int out_size, void* d_ws, size_t ws_size,
                              hipStream_t stream) {
  const float* x        = (const float*)d_in[0];
  const int*   edges    = (const int*)d_in[1];
  const float* feat_w   = (const float*)d_in[2];
  const float* conv_w   = (const float*)d_in[3];
  const float* conv_b   = (const float*)d_in[4];
  const float* attn_w   = (const float*)d_in[5];
  const float* attn_q   = (const float*)d_in[6];
  const float* concat_w = (const float*)d_in[7];
  float* out = (float*)d_out;   // [NN*128 y][NN*3 attn]

  float* ws = (float*)d_ws;
  float* rsqo = ws;                   // [3][NN]
  float* rsqi = rsqo + 3 * NN;        // [3][NN]
  int* btot = (int*)(rsqi + 3 * NN);  // 80 ints
  int* boff = btot + 80;              // 80 ints
  int* cnt = boff + 96;               // (spare region; fw overlays here)
  int* rowptr = cnt + 3 * NN;         // [3][NN+1] (+pad)
  int* col = rowptr + 3 * (NN + 1) + 13;  // [3][NE]
  const size_t ND = (size_t)NN * DD;
  float* P1 = (float*)(col + 3 * (size_t)NE);  // prologue: rank | VbAll 0-1
  float* PA = P1 + ND;   // prologue: hist | VbAll planes 2-3
  float* PB = PA + ND;   // prologue: bases | VbAll planes 4-5
  unsigned short* U0 = (unsigned short*)(PB + ND);  // u bf16 x3; later h2b
  unsigned short* B0 = U0 + 3 * ND;   // h0b
  unsigned short* B1 = B0 + ND;       // h1b
  unsigned short* B2 = B1 + ND;       // tb
  unsigned short* fw = (unsigned short*)cnt;   // 10x16384 + 2x8192 ushort
  unsigned int* hist = (unsigned int*)PA;      // 6*NB*NW <= ND
  int* bases = (int*)PB;                       // 3*NB*NN <= ND
  unsigned short* rank = (unsigned short*)P1;  // 3*NE ushort = 4.8 MB <= plane
  unsigned short* VbAll = (unsigned short*)P1; // 6 bf16 vals planes (contig)
  unsigned short* fa0 = fw + (size_t)10 * 16384;
  unsigned short* fa1 = fa0 + 8192;

  // prologue: degrees + CSR (no global atomics, no LDS fill pass)
  hist6_kernel<<<dim3(NB, 6), 512, 0, stream>>>(edges, hist, rank);
  sumscan_kernel<<<dim3(25, 6), 256, 0, stream>>>(hist, rowptr, btot, rsqi, rsqo);
  scanp2_kernel<<<1, 64, 0, stream>>>(btot, boff, rowptr);
  prepw_kernel<<<12, 256, 0, stream>>>(conv_w, feat_w, concat_w, attn_w, fw);
  bases_kernel<<<dim3(25, 3), 256, 0, stream>>>(hist, boff, rowptr, bases);
  fillr_kernel<<<dim3(3125, 3), 256, 0, stream>>>(edges, rank, bases, col);

  // h0 = tanh(x @ feat_w) -> B0 bf16
  mgemm_kernel<1, 1, 0, 0><<<dim3(391, 1), 256, 0, stream>>>(
      x, fw + (size_t)6 * 16384, nullptr, nullptr, nullptr, B0);

  // shared u[r] = A_r^T (h0 * rsqo_r) -> U planes, batched
  gatherb_kernel<<<dim3(3125, 3), 256, 0, stream>>>(B0, rowptr, col, rsqo, U0);

  // both h0-fed layers in one launch: planes 0-2 = l1 vals, 3-5 = l0 vals
  mgemm_kernel<0, 0, 1, 1><<<dim3(391, 6), 256, 0, stream>>>(
      U0, fw, rsqi, conv_b, B0, VbAll);
  // both mscombs in one launch: h1 -> B1, t -> B2
  mscomb_kernel<1><<<dim3(391, 2), 256, 0, stream>>>(
      VbAll, fa0, attn_q, B1, nullptr);

  // layer l=1 on t: gathers from B2 -> U; convs (resid = B2) -> planes 0-2
  gatherb_kernel<<<dim3(3125, 3), 256, 0, stream>>>(B2, rowptr, col, rsqo, U0);
  mgemm_kernel<0, 0, 1, 0><<<dim3(391, 3), 256, 0, stream>>>(
      U0, fw + (size_t)3 * 16384, rsqi, conv_b + (size_t)3 * DD, B2, VbAll);
  // h2 -> U0 (bf16), attn -> out+ND
  mscomb_kernel<0><<<dim3(391, 1), 256, 0, stream>>>(
      VbAll, fa1, attn_q + DQ, U0, out + ND);

  // y = [h0|h1|h2] @ CW^T -> out
  mconcat_kernel<<<196, 512, 0, stream>>>(B0, B1, U0, fw + (size_t)7 * 16384, out);
}